// Round 1
// baseline (1989.094 us; speedup 1.0000x reference)
//
#include <hip/hip_runtime.h>
#include <math.h>

#define BB 4
#define NN 4995
#define CC 128
#define IMG 224
#define IMGP (IMG*IMG)
#define ALPHA_F 100.0f
#define SPLITS 8
#define COLS_PER_SPLIT 625   // ceil(4995/8)
#define RBLK 79              // row blocks of 64 per batch

// ws layout in float units
#define OFF_V12    0            // B*N*3 = 59940
#define OFF_FN2    60000        // 19980
#define OFF_VN2    80000        // 19980
#define OFF_VN1    100000       // 19980
#define OFF_PART   120000       // 19980*8*5 = 799200
#define OFF_IMG1   920000       // 200704
#define OFF_IMG2   1120704      // 200704
#define OFF_ACC    1321408      // 3 doubles (byte off 5285632, 8-aligned); reserve 32 floats
#define OFF_STATS  1321440      // 2*4*16 = 128 floats
#define ZERO_START OFF_IMG1
#define ZERO_FLOATS (OFF_STATS + 128 - OFF_IMG1)

__device__ __forceinline__ float wave_min(float v){
#pragma unroll
  for (int off=32; off; off>>=1) v = fminf(v, __shfl_xor(v, off));
  return v;
}
__device__ __forceinline__ float wave_sum(float v){
#pragma unroll
  for (int off=32; off; off>>=1) v += __shfl_xor(v, off);
  return v;
}

// ---------------- norms: vnorm1, vnorm2, fnorm2 ----------------
__global__ void k_norms(const float* __restrict__ verts1, const float* __restrict__ verts2,
                        const float* __restrict__ feat2, float* __restrict__ ws) {
  int i = blockIdx.x*blockDim.x + threadIdx.x;
  if (i >= BB*NN) return;
  float x=verts1[(size_t)i*3], y=verts1[(size_t)i*3+1], z=verts1[(size_t)i*3+2];
  ws[OFF_VN1+i] = x*x + y*y + z*z;
  x=verts2[(size_t)i*3]; y=verts2[(size_t)i*3+1]; z=verts2[(size_t)i*3+2];
  ws[OFF_VN2+i] = x*x + y*y + z*z;
  const float4* f = (const float4*)(feat2 + (size_t)i*CC);
  float s0=0.f,s1=0.f,s2=0.f,s3=0.f;
#pragma unroll
  for (int k=0;k<CC/4;k++){ float4 t=f[k];
    s0=fmaf(t.x,t.x,s0); s1=fmaf(t.y,t.y,s1); s2=fmaf(t.z,t.z,s2); s3=fmaf(t.w,t.w,s3); }
  ws[OFF_FN2+i] = (s0+s1)+(s2+s3);
}

// ---------------- stage A: fused cdist + softmax + Pi@verts2 (partials) ----------------
__global__ __launch_bounds__(64,2) void k_stageA(const float* __restrict__ feat1,
      const float* __restrict__ feat2, const float* __restrict__ verts2,
      float* __restrict__ ws) {
  int rb = blockIdx.x; int split = blockIdx.y;
  int b = rb / RBLK; int rblk = rb - b*RBLK;
  int n = rblk*64 + threadIdx.x;
  bool active = (n < NN);
  int nc = active ? n : (NN-1);
  int row = b*NN + nc;
  const float4* f1 = (const float4*)(feat1 + (size_t)row*CC);
  float a[CC];
  float s0=0.f,s1=0.f,s2=0.f,s3=0.f;
#pragma unroll
  for (int k=0;k<CC/4;k++){ float4 t = f1[k];
    a[4*k]=t.x; a[4*k+1]=t.y; a[4*k+2]=t.z; a[4*k+3]=t.w;
    s0=fmaf(t.x,t.x,s0); s1=fmaf(t.y,t.y,s1); s2=fmaf(t.z,t.z,s2); s3=fmaf(t.w,t.w,s3); }
  float sn = (s0+s1)+(s2+s3);

  const float* fn2 = ws + OFF_FN2 + (size_t)b*NN;
  const float* v2b = verts2 + (size_t)b*NN*3;
  const float* f2b = feat2 + (size_t)b*NN*CC;

  int m0 = split*COLS_PER_SPLIT; int m1 = m0 + COLS_PER_SPLIT; if (m1 > NN) m1 = NN;
  float mm = -INFINITY, S=0.f, Vx=0.f, Vy=0.f, Vz=0.f;
  for (int m=m0; m<m1; ++m) {
    const float4* f2 = (const float4*)(f2b + (size_t)m*CC);
    float sb = fn2[m];
    float wx = v2b[(size_t)m*3], wy = v2b[(size_t)m*3+1], wz = v2b[(size_t)m*3+2];
    float g0=0.f,g1=0.f,g2=0.f,g3=0.f;
#pragma unroll
    for (int k=0;k<CC/4;k++){ float4 t = f2[k];
      g0=fmaf(a[4*k]  ,t.x,g0); g1=fmaf(a[4*k+1],t.y,g1);
      g2=fmaf(a[4*k+2],t.z,g2); g3=fmaf(a[4*k+3],t.w,g3); }
    float g = (g0+g1)+(g2+g3);
    float d2 = (sn - 2.0f*g) + sb;
    float d = sqrtf(fmaxf(d2, 1e-12f));
    float l = -ALPHA_F*d;
    float mn = fmaxf(mm, l);
    float sc = __expf(mm - mn);
    float e  = __expf(l - mn);
    S  = fmaf(S, sc, e);
    Vx = fmaf(Vx, sc, e*wx);
    Vy = fmaf(Vy, sc, e*wy);
    Vz = fmaf(Vz, sc, e*wz);
    mm = mn;
  }
  if (active) {
    float* p = ws + OFF_PART + ((size_t)(b*NN+n)*SPLITS + split)*5;
    p[0]=mm; p[1]=S; p[2]=Vx; p[3]=Vy; p[4]=Vz;
  }
}

// ---------------- combine partials -> verts12 ----------------
__global__ void k_combine(float* __restrict__ ws) {
  int row = blockIdx.x*blockDim.x + threadIdx.x;
  if (row >= BB*NN) return;
  const float* p = ws + OFF_PART + (size_t)row*SPLITS*5;
  float mm = -INFINITY;
#pragma unroll
  for (int s=0;s<SPLITS;s++) mm = fmaxf(mm, p[s*5]);
  float S=0.f,Vx=0.f,Vy=0.f,Vz=0.f;
#pragma unroll
  for (int s=0;s<SPLITS;s++){
    float sc = expf(p[s*5]-mm);
    S  += p[s*5+1]*sc; Vx += p[s*5+2]*sc; Vy += p[s*5+3]*sc; Vz += p[s*5+4]*sc;
  }
  ws[OFF_V12+(size_t)row*3+0]=Vx/S;
  ws[OFF_V12+(size_t)row*3+1]=Vy/S;
  ws[OFF_V12+(size_t)row*3+2]=Vz/S;
}

// ---------------- self-rec: mean over rows of min_m sqdist(verts12, verts2) ----------------
__global__ void k_selfrec(const float* __restrict__ verts2, float* __restrict__ ws) {
  int row = blockIdx.x*4 + (threadIdx.x>>6);
  int lane = threadIdx.x & 63;
  if (row >= BB*NN) return;
  int b = row / NN;
  const float* v12 = ws + OFF_V12 + (size_t)row*3;
  float x=v12[0], y=v12[1], z=v12[2];
  float sa = x*x + y*y + z*z;
  const float* vn2 = ws + OFF_VN2 + (size_t)b*NN;
  const float* v2 = verts2 + (size_t)b*NN*3;
  float mn = INFINITY;
  for (int m=lane; m<NN; m+=64) {
    float wx=v2[(size_t)m*3], wy=v2[(size_t)m*3+1], wz=v2[(size_t)m*3+2];
    float d2 = (sa - 2.0f*(x*wx + y*wy + z*wz)) + vn2[m];
    mn = fminf(mn, d2);
  }
  mn = wave_min(mn);
  if (lane==0) atomicAdd((double*)(ws+OFF_ACC)+0, (double)mn);
}

// ---------------- top-k (k<=16) of sqdist(verts1,verts1) + deform feat MSE ----------------
__global__ __launch_bounds__(64) void k_topk(const float* __restrict__ verts1,
        const float* __restrict__ feat1, const int* __restrict__ kptr,
        float* __restrict__ ws) {
  __shared__ float sv[64*16];
  __shared__ int   si[64*16];
  __shared__ int   sel[16];
  int row = blockIdx.x;
  int lane = threadIdx.x;
  int b = row / NN; int n = row - b*NN;
  int kk = *kptr; if (kk > 16) kk = 16; if (kk < 1) kk = 1;
  const float* v1 = verts1 + (size_t)row*3;
  float x=v1[0], y=v1[1], z=v1[2];
  const float* vn1 = ws + OFF_VN1 + (size_t)b*NN;
  float sa = vn1[n];
  const float* vb = verts1 + (size_t)b*NN*3;
  float tv[16]; int ti[16];
#pragma unroll
  for (int j=0;j<16;j++){ tv[j]=INFINITY; ti[j]=0x7fffffff; }
  for (int m=lane; m<NN; m+=64) {
    float wx=vb[(size_t)m*3], wy=vb[(size_t)m*3+1], wz=vb[(size_t)m*3+2];
    float d2 = (sa - 2.0f*(x*wx+y*wy+z*wz)) + vn1[m];
    if (d2 < tv[15] || (d2 == tv[15] && m < ti[15])) {
      float cv=d2; int ci=m;
#pragma unroll
      for (int j=0;j<16;j++){
        bool lt = (cv<tv[j]) || (cv==tv[j] && ci<ti[j]);
        float nv = lt?cv:tv[j]; int ni = lt?ci:ti[j];
        float ov = lt?tv[j]:cv; int oi = lt?ti[j]:ci;
        tv[j]=nv; ti[j]=ni; cv=ov; ci=oi;
      }
    }
  }
#pragma unroll
  for (int j=0;j<16;j++){ sv[lane*16+j]=tv[j]; si[lane*16+j]=ti[j]; }
  __syncthreads();
  int p = 0;
  for (int r=0;r<kk;r++){
    float cv = (p<16) ? sv[lane*16+p] : INFINITY;
    int   ci = (p<16) ? si[lane*16+p] : 0x7fffffff;
    int   cl = lane;
#pragma unroll
    for (int off=32; off; off>>=1){
      float ov = __shfl_xor(cv, off);
      int   oi = __shfl_xor(ci, off);
      int   ol = __shfl_xor(cl, off);
      bool take = (ov<cv) || (ov==cv && oi<ci);
      if (take){ cv=ov; ci=oi; cl=ol; }
    }
    if (lane==cl) p++;
    if (lane==0) sel[r]=ci;
  }
  __syncthreads();
  const float* f1n = feat1 + (size_t)row*CC;
  float e0 = f1n[lane], e1 = f1n[64+lane];
  float acc = 0.f;
  for (int r=0;r<kk;r++){
    const float* g = feat1 + ((size_t)b*NN + sel[r])*CC;
    float d0 = g[lane]-e0, d1 = g[64+lane]-e1;
    acc = fmaf(d0,d0,acc); acc = fmaf(d1,d1,acc);
  }
  acc = wave_sum(acc);
  if (lane==0) atomicAdd((double*)(ws+OFF_ACC)+2, (double)acc);
}

// ---------------- proj2img stats: min/max, grid size, center offsets ----------------
__global__ void k_imgstats(const float* __restrict__ verts2, const float* __restrict__ imgoff,
                           float* __restrict__ ws) {
  __shared__ float r0[4], r1[4], r2[4], r3[4];
  __shared__ float sgs, smnx, smny;
  int img = blockIdx.x >> 2, b = blockIdx.x & 3;
  const float* pc = (img==0) ? (ws + OFF_V12 + (size_t)b*NN*3) : (verts2 + (size_t)b*NN*3);
  int lane = threadIdx.x & 63, wid = threadIdx.x >> 6;
  float mnx=INFINITY, mxx=-INFINITY, mny=INFINITY, mxy=-INFINITY;
  for (int n = threadIdx.x; n < NN; n += 256) {
    float x = pc[(size_t)n*3], y = pc[(size_t)n*3+1];
    mnx=fminf(mnx,x); mxx=fmaxf(mxx,x); mny=fminf(mny,y); mxy=fmaxf(mxy,y);
  }
#pragma unroll
  for (int off=32; off; off>>=1) {
    mnx=fminf(mnx,__shfl_xor(mnx,off)); mxx=fmaxf(mxx,__shfl_xor(mxx,off));
    mny=fminf(mny,__shfl_xor(mny,off)); mxy=fmaxf(mxy,__shfl_xor(mxy,off));
  }
  if (lane==0){ r0[wid]=mnx; r1[wid]=mxx; r2[wid]=mny; r3[wid]=mxy; }
  __syncthreads();
  float* st = ws + OFF_STATS + (size_t)(img*4+b)*16;
  if (threadIdx.x==0){
    mnx=fminf(fminf(r0[0],r0[1]),fminf(r0[2],r0[3]));
    mxx=fmaxf(fmaxf(r1[0],r1[1]),fmaxf(r1[2],r1[3]));
    mny=fminf(fminf(r2[0],r2[1]),fminf(r2[2],r2[3]));
    mxy=fmaxf(fmaxf(r3[0],r3[1]),fmaxf(r3[2],r3[3]));
    float gs = fmaxf(mxx-mnx, mxy-mny) / 221.0f;
    sgs=gs; smnx=mnx; smny=mny;
    st[0]=mnx; st[1]=mxx; st[2]=mny; st[3]=mxy; st[4]=gs;
  }
  __syncthreads();
  float gs=sgs, bx=smnx, by=smny;
  float fmnx=INFINITY, fmxx=-INFINITY, fmny=INFINITY, fmxy=-INFINITY;
  for (int n = threadIdx.x; n < NN; n += 256) {
    float fx = floorf((pc[(size_t)n*3]-bx)/gs);
    float fy = floorf((pc[(size_t)n*3+1]-by)/gs);
    fmnx=fminf(fmnx,fx); fmxx=fmaxf(fmxx,fx); fmny=fminf(fmny,fy); fmxy=fmaxf(fmxy,fy);
  }
#pragma unroll
  for (int off=32; off; off>>=1) {
    fmnx=fminf(fmnx,__shfl_xor(fmnx,off)); fmxx=fmaxf(fmxx,__shfl_xor(fmxx,off));
    fmny=fminf(fmny,__shfl_xor(fmny,off)); fmxy=fmaxf(fmxy,__shfl_xor(fmxy,off));
  }
  __syncthreads();  // r arrays reuse
  if (lane==0){ r0[wid]=fmnx; r1[wid]=fmxx; r2[wid]=fmny; r3[wid]=fmxy; }
  __syncthreads();
  if (threadIdx.x==0){
    fmnx=fminf(fminf(r0[0],r0[1]),fminf(r0[2],r0[3]));
    fmxx=fmaxf(fmaxf(r1[0],r1[1]),fmaxf(r1[2],r1[3]));
    fmny=fminf(fminf(r2[0],r2[1]),fminf(r2[2],r2[3]));
    fmxy=fmaxf(fmaxf(r3[0],r3[1]),fmaxf(r3[2],r3[3]));
    float omnx=INFINITY, omxx=-INFINITY, omny=INFINITY, omxy=-INFINITY;
    for (int l=0;l<25;l++){
      float ox=imgoff[l*2], oy=imgoff[l*2+1];
      omnx=fminf(omnx,ox); omxx=fmaxf(omxx,ox); omny=fminf(omny,oy); omxy=fmaxf(omxy,oy);
    }
    float cx = floorf(((fmxx+omxx+1.0f)+(fmnx+omnx+1.0f))*0.5f);
    float cy = floorf(((fmxy+omxy+1.0f)+(fmny+omny+1.0f))*0.5f);
    st[5] = (112.0f - cx) - 1.0f;
    st[6] = (112.0f - cy) - 1.0f;
  }
}

// ---------------- scatter z into both images ----------------
__global__ void k_scatter(const float* __restrict__ verts2, const float* __restrict__ imgoff,
                          float* __restrict__ ws) {
  int t = blockIdx.x*blockDim.x + threadIdx.x;
  if (t >= 2*BB*NN) return;
  int img = t / (BB*NN); int r = t - img*(BB*NN); int b = r / NN;
  const float* pc = (img==0) ? (ws + OFF_V12) : verts2;
  float x = pc[(size_t)r*3], y = pc[(size_t)r*3+1], z = pc[(size_t)r*3+2];
  const float* st = ws + OFF_STATS + (size_t)(img*4+b)*16;
  float mnx=st[0], mny=st[2], gs=st[4], offx=st[5], offy=st[6];
  float bx = floorf((x-mnx)/gs) + 1.0f + offx;
  float by = floorf((y-mny)/gs) + 1.0f + offy;
  float* im = ws + (img==0?OFF_IMG1:OFF_IMG2) + (size_t)b*IMGP;
#pragma unroll
  for (int l=0;l<25;l++){
    float vx = bx + imgoff[l*2], vy = by + imgoff[l*2+1];
    vx += (vx<0.f?1.f:0.f) - (vx>223.f?1.f:0.f);
    vy += (vy<0.f?1.f:0.f) - (vy>223.f?1.f:0.f);
    vx = fminf(fmaxf(vx,0.f),223.f); vy = fminf(fmaxf(vy,0.f),223.f);
    int flat = (int)(vx*224.f + vy);
    atomicAdd(im + flat, z);
  }
}

// ---------------- image loss ----------------
__global__ void k_imgloss(float* __restrict__ ws) {
  int i = blockIdx.x*blockDim.x + threadIdx.x;
  float v = 0.f;
  if (i < BB*IMGP) {
    float a = ws[OFF_IMG1+i], c = ws[OFF_IMG2+i];
    float sa = 1.f/(1.f+expf(-a)), sc = 1.f/(1.f+expf(-c));
    float d = sa - sc; v = d*d;
  }
  v = wave_sum(v);
  if ((threadIdx.x&63)==0) atomicAdd((double*)(ws+OFF_ACC)+1, (double)v);
}

// ---------------- finalize ----------------
__global__ void k_final(const int* __restrict__ kptr, const float* __restrict__ ws, float* __restrict__ out) {
  const double* acc = (const double*)(ws+OFF_ACC);
  int kk = *kptr; if (kk > 16) kk = 16; if (kk < 1) kk = 1;
  double srl = acc[0] / (double)(BB*NN);
  double img = acc[1] / ((double)BB*IMGP);
  double df  = acc[2] / ((double)BB*NN*kk*CC);
  out[0] = (float)(srl + img + df);
}

extern "C" void kernel_launch(void* const* d_in, const int* in_sizes, int n_in,
                              void* d_out, int out_size, void* d_ws, size_t ws_size,
                              hipStream_t stream) {
  (void)in_sizes; (void)n_in; (void)out_size; (void)ws_size;
  const float* verts1 = (const float*)d_in[0];
  const float* verts2 = (const float*)d_in[1];
  const float* feat1  = (const float*)d_in[2];
  const float* feat2  = (const float*)d_in[3];
  const float* imgoff = (const float*)d_in[4];
  const int*   kptr   = (const int*)d_in[5];
  float* ws  = (float*)d_ws;
  float* out = (float*)d_out;

  hipMemsetAsync(ws + ZERO_START, 0, (size_t)ZERO_FLOATS*sizeof(float), stream);

  k_norms<<<(BB*NN+255)/256, 256, 0, stream>>>(verts1, verts2, feat2, ws);

  dim3 gA(BB*RBLK, SPLITS);
  k_stageA<<<gA, 64, 0, stream>>>(feat1, feat2, verts2, ws);
  k_combine<<<(BB*NN+255)/256, 256, 0, stream>>>(ws);

  k_selfrec<<<(BB*NN+3)/4, 256, 0, stream>>>(verts2, ws);
  k_topk<<<BB*NN, 64, 0, stream>>>(verts1, feat1, kptr, ws);

  k_imgstats<<<8, 256, 0, stream>>>(verts2, imgoff, ws);
  k_scatter<<<(2*BB*NN+255)/256, 256, 0, stream>>>(verts2, imgoff, ws);
  k_imgloss<<<(BB*IMGP+255)/256, 256, 0, stream>>>(ws);

  k_final<<<1,1,0,stream>>>(kptr, ws, out);
}

// Round 2
// 1550.399 us; speedup vs baseline: 1.2830x; 1.2830x over previous
//
#include <hip/hip_runtime.h>
#include <math.h>

#define BB 4
#define NN 4995
#define CC 128
#define IMG 224
#define IMGP (IMG*IMG)
#define ALPHA_F 100.0f
#define SPLITS 8
#define COLS_PER_SPLIT 625   // ceil(4995/8)
#define RBLK 79              // row blocks of 64 per batch
#define TK 32                // K tile
#define TM 64                // rows per block
#define TNC 64               // cols per tile

// ws layout in float units
#define OFF_V12    0            // B*N*3 = 59940
#define OFF_FN2    60000        // 19980
#define OFF_VN2    80000        // 19980
#define OFF_VN1    100000       // 19980
#define OFF_FN1    120000       // 19980
#define OFF_PART   140000       // 19980*8*5 = 799200 -> ends 939200
#define OFF_IMG1   940000       // 200704
#define OFF_IMG2   1140704      // 200704
#define OFF_ACC    1341408      // 3 doubles (byte off 5365632, 8-aligned); reserve 32 floats
#define OFF_STATS  1341440      // 2*4*16 = 128 floats
#define ZERO_START OFF_IMG1
#define ZERO_FLOATS (OFF_STATS + 128 - OFF_IMG1)

__device__ __forceinline__ float wave_min(float v){
#pragma unroll
  for (int off=32; off; off>>=1) v = fminf(v, __shfl_xor(v, off));
  return v;
}
__device__ __forceinline__ float wave_sum(float v){
#pragma unroll
  for (int off=32; off; off>>=1) v += __shfl_xor(v, off);
  return v;
}

// ---------------- norms: vnorm1, vnorm2, fnorm1, fnorm2 ----------------
__global__ void k_norms(const float* __restrict__ verts1, const float* __restrict__ verts2,
                        const float* __restrict__ feat1, const float* __restrict__ feat2,
                        float* __restrict__ ws) {
  int i = blockIdx.x*blockDim.x + threadIdx.x;
  if (i >= BB*NN) return;
  float x=verts1[(size_t)i*3], y=verts1[(size_t)i*3+1], z=verts1[(size_t)i*3+2];
  ws[OFF_VN1+i] = x*x + y*y + z*z;
  x=verts2[(size_t)i*3]; y=verts2[(size_t)i*3+1]; z=verts2[(size_t)i*3+2];
  ws[OFF_VN2+i] = x*x + y*y + z*z;
  {
    const float4* f = (const float4*)(feat2 + (size_t)i*CC);
    float s0=0.f,s1=0.f,s2=0.f,s3=0.f;
#pragma unroll
    for (int k=0;k<CC/4;k++){ float4 t=f[k];
      s0=fmaf(t.x,t.x,s0); s1=fmaf(t.y,t.y,s1); s2=fmaf(t.z,t.z,s2); s3=fmaf(t.w,t.w,s3); }
    ws[OFF_FN2+i] = (s0+s1)+(s2+s3);
  }
  {
    const float4* f = (const float4*)(feat1 + (size_t)i*CC);
    float s0=0.f,s1=0.f,s2=0.f,s3=0.f;
#pragma unroll
    for (int k=0;k<CC/4;k++){ float4 t=f[k];
      s0=fmaf(t.x,t.x,s0); s1=fmaf(t.y,t.y,s1); s2=fmaf(t.z,t.z,s2); s3=fmaf(t.w,t.w,s3); }
    ws[OFF_FN1+i] = (s0+s1)+(s2+s3);
  }
}

// ---------------- stage A: tiled fp32 GEMM + online softmax + Pi@verts2 (partials) ----------------
// grid (RBLK, SPLITS, BB), block 256. Thread grid 16x16: tx=col group (4 cols), ty=row group (4 rows).
__global__ __launch_bounds__(256) void k_stageA(const float* __restrict__ feat1,
      const float* __restrict__ feat2, const float* __restrict__ verts2,
      float* __restrict__ ws) {
  __shared__ __align__(16) float As[TK][TM];   // [k][row]
  __shared__ __align__(16) float Bs[TK][TNC];  // [k][col]
  int rblk  = blockIdx.x;
  int split = blockIdx.y;
  int b     = blockIdx.z;
  int rowBase = rblk*TM;
  int colBase = split*COLS_PER_SPLIT;
  int colEnd  = colBase + COLS_PER_SPLIT; if (colEnd > NN) colEnd = NN;
  int t  = threadIdx.x;
  int tx = t & 15, ty = t >> 4;

  const float* f1b = feat1 + (size_t)b*NN*CC;
  const float* f2b = feat2 + (size_t)b*NN*CC;
  const float* v2b = verts2 + (size_t)b*NN*3;
  const float* fn1 = ws + OFF_FN1 + (size_t)b*NN;
  const float* fn2 = ws + OFF_FN2 + (size_t)b*NN;

  int r0 = rowBase + 4*ty;
  float sn[4];
#pragma unroll
  for (int i=0;i<4;i++){ int r = r0+i; if (r > NN-1) r = NN-1; sn[i] = fn1[r]; }

  float mm[4], S[4], Vx[4], Vy[4], Vz[4];
#pragma unroll
  for (int i=0;i<4;i++){ mm[i]=-INFINITY; S[i]=0.f; Vx[i]=0.f; Vy[i]=0.f; Vz[i]=0.f; }

  for (int ct = colBase; ct < colEnd; ct += TNC) {
    float acc[4][4];
#pragma unroll
    for (int i=0;i<4;i++)
#pragma unroll
      for (int j=0;j<4;j++) acc[i][j]=0.f;

#pragma unroll 1
    for (int kt = 0; kt < CC; kt += TK) {
      __syncthreads();
#pragma unroll
      for (int h=0; h<2; h++){
        int fi = t*2 + h;          // 0..511
        int rr = fi >> 3;          // 0..63
        int q  = fi & 7;           // 0..7
        int grow = rowBase + rr; if (grow > NN-1) grow = NN-1;
        float4 v = *(const float4*)(f1b + (size_t)grow*CC + kt + 4*q);
        As[4*q+0][rr]=v.x; As[4*q+1][rr]=v.y; As[4*q+2][rr]=v.z; As[4*q+3][rr]=v.w;
        int gcol = ct + rr; if (gcol > NN-1) gcol = NN-1;
        float4 w = *(const float4*)(f2b + (size_t)gcol*CC + kt + 4*q);
        Bs[4*q+0][rr]=w.x; Bs[4*q+1][rr]=w.y; Bs[4*q+2][rr]=w.z; Bs[4*q+3][rr]=w.w;
      }
      __syncthreads();
#pragma unroll
      for (int kk=0; kk<TK; kk++){
        float4 a4 = *(const float4*)&As[kk][4*ty];
        float4 b4 = *(const float4*)&Bs[kk][4*tx];
        acc[0][0]=fmaf(a4.x,b4.x,acc[0][0]); acc[0][1]=fmaf(a4.x,b4.y,acc[0][1]);
        acc[0][2]=fmaf(a4.x,b4.z,acc[0][2]); acc[0][3]=fmaf(a4.x,b4.w,acc[0][3]);
        acc[1][0]=fmaf(a4.y,b4.x,acc[1][0]); acc[1][1]=fmaf(a4.y,b4.y,acc[1][1]);
        acc[1][2]=fmaf(a4.y,b4.z,acc[1][2]); acc[1][3]=fmaf(a4.y,b4.w,acc[1][3]);
        acc[2][0]=fmaf(a4.z,b4.x,acc[2][0]); acc[2][1]=fmaf(a4.z,b4.y,acc[2][1]);
        acc[2][2]=fmaf(a4.z,b4.z,acc[2][2]); acc[2][3]=fmaf(a4.z,b4.w,acc[2][3]);
        acc[3][0]=fmaf(a4.w,b4.x,acc[3][0]); acc[3][1]=fmaf(a4.w,b4.y,acc[3][1]);
        acc[3][2]=fmaf(a4.w,b4.z,acc[3][2]); acc[3][3]=fmaf(a4.w,b4.w,acc[3][3]);
      }
    }

    // epilogue: online softmax update for the 64x64 tile
    int c0 = ct + 4*tx;
    float fnc[4], wx[4], wy[4], wz[4]; bool valid[4];
#pragma unroll
    for (int j=0;j<4;j++){
      int c = c0+j;
      valid[j] = (c < colEnd);
      int cc2 = c; if (cc2 > NN-1) cc2 = NN-1;
      fnc[j] = fn2[cc2];
      wx[j]=v2b[(size_t)cc2*3]; wy[j]=v2b[(size_t)cc2*3+1]; wz[j]=v2b[(size_t)cc2*3+2];
    }
#pragma unroll
    for (int i=0;i<4;i++){
      float l[4];
#pragma unroll
      for (int j=0;j<4;j++){
        float d2 = fmaf(-2.f, acc[i][j], sn[i]) + fnc[j];
        float d = sqrtf(fmaxf(d2, 1e-12f));
        l[j] = valid[j] ? (-ALPHA_F*d) : -INFINITY;
      }
      float Mt = fmaxf(fmaxf(l[0],l[1]), fmaxf(l[2],l[3]));
#pragma unroll
      for (int off=1; off<16; off<<=1) Mt = fmaxf(Mt, __shfl_xor(Mt, off));
      float mn = fmaxf(mm[i], Mt);
      float sc = __expf(mm[i]-mn);
      float e0=__expf(l[0]-mn), e1=__expf(l[1]-mn), e2=__expf(l[2]-mn), e3=__expf(l[3]-mn);
      float se = (e0+e1)+(e2+e3);
      float sx = e0*wx[0]+e1*wx[1]+e2*wx[2]+e3*wx[3];
      float sy = e0*wy[0]+e1*wy[1]+e2*wy[2]+e3*wy[3];
      float sz = e0*wz[0]+e1*wz[1]+e2*wz[2]+e3*wz[3];
#pragma unroll
      for (int off=1; off<16; off<<=1){
        se += __shfl_xor(se,off); sx += __shfl_xor(sx,off);
        sy += __shfl_xor(sy,off); sz += __shfl_xor(sz,off);
      }
      S[i]  = fmaf(S[i], sc, se);
      Vx[i] = fmaf(Vx[i],sc, sx);
      Vy[i] = fmaf(Vy[i],sc, sy);
      Vz[i] = fmaf(Vz[i],sc, sz);
      mm[i] = mn;
    }
  }

  if (tx==0){
#pragma unroll
    for (int i=0;i<4;i++){
      int n = r0 + i;
      if (n < NN){
        float* p = ws + OFF_PART + ((size_t)(b*NN+n)*SPLITS + split)*5;
        p[0]=mm[i]; p[1]=S[i]; p[2]=Vx[i]; p[3]=Vy[i]; p[4]=Vz[i];
      }
    }
  }
}

// ---------------- combine partials -> verts12 ----------------
__global__ void k_combine(float* __restrict__ ws) {
  int row = blockIdx.x*blockDim.x + threadIdx.x;
  if (row >= BB*NN) return;
  const float* p = ws + OFF_PART + (size_t)row*SPLITS*5;
  float mm = -INFINITY;
#pragma unroll
  for (int s=0;s<SPLITS;s++) mm = fmaxf(mm, p[s*5]);
  float S=0.f,Vx=0.f,Vy=0.f,Vz=0.f;
#pragma unroll
  for (int s=0;s<SPLITS;s++){
    float sc = expf(p[s*5]-mm);
    S  += p[s*5+1]*sc; Vx += p[s*5+2]*sc; Vy += p[s*5+3]*sc; Vz += p[s*5+4]*sc;
  }
  ws[OFF_V12+(size_t)row*3+0]=Vx/S;
  ws[OFF_V12+(size_t)row*3+1]=Vy/S;
  ws[OFF_V12+(size_t)row*3+2]=Vz/S;
}

// ---------------- self-rec: mean over rows of min_m sqdist(verts12, verts2) ----------------
__global__ void k_selfrec(const float* __restrict__ verts2, float* __restrict__ ws) {
  int row = blockIdx.x*4 + (threadIdx.x>>6);
  int lane = threadIdx.x & 63;
  if (row >= BB*NN) return;
  int b = row / NN;
  const float* v12 = ws + OFF_V12 + (size_t)row*3;
  float x=v12[0], y=v12[1], z=v12[2];
  float sa = x*x + y*y + z*z;
  const float* vn2 = ws + OFF_VN2 + (size_t)b*NN;
  const float* v2 = verts2 + (size_t)b*NN*3;
  float mn = INFINITY;
  for (int m=lane; m<NN; m+=64) {
    float wx=v2[(size_t)m*3], wy=v2[(size_t)m*3+1], wz=v2[(size_t)m*3+2];
    float d2 = (sa - 2.0f*(x*wx + y*wy + z*wz)) + vn2[m];
    mn = fminf(mn, d2);
  }
  mn = wave_min(mn);
  if (lane==0) atomicAdd((double*)(ws+OFF_ACC)+0, (double)mn);
}

// ---------------- top-k (k<=16) of sqdist(verts1,verts1) + deform feat MSE ----------------
__global__ __launch_bounds__(64) void k_topk(const float* __restrict__ verts1,
        const float* __restrict__ feat1, const int* __restrict__ kptr,
        float* __restrict__ ws) {
  __shared__ float sv[64*16];
  __shared__ int   si[64*16];
  __shared__ int   sel[16];
  int row = blockIdx.x;
  int lane = threadIdx.x;
  int b = row / NN; int n = row - b*NN;
  int kk = *kptr; if (kk > 16) kk = 16; if (kk < 1) kk = 1;
  const float* v1 = verts1 + (size_t)row*3;
  float x=v1[0], y=v1[1], z=v1[2];
  const float* vn1 = ws + OFF_VN1 + (size_t)b*NN;
  float sa = vn1[n];
  const float* vb = verts1 + (size_t)b*NN*3;
  float tv[16]; int ti[16];
#pragma unroll
  for (int j=0;j<16;j++){ tv[j]=INFINITY; ti[j]=0x7fffffff; }
  for (int m=lane; m<NN; m+=64) {
    float wx=vb[(size_t)m*3], wy=vb[(size_t)m*3+1], wz=vb[(size_t)m*3+2];
    float d2 = (sa - 2.0f*(x*wx+y*wy+z*wz)) + vn1[m];
    if (d2 < tv[15] || (d2 == tv[15] && m < ti[15])) {
      float cv=d2; int ci=m;
#pragma unroll
      for (int j=0;j<16;j++){
        bool lt = (cv<tv[j]) || (cv==tv[j] && ci<ti[j]);
        float nv = lt?cv:tv[j]; int ni = lt?ci:ti[j];
        float ov = lt?tv[j]:cv; int oi = lt?ti[j]:ci;
        tv[j]=nv; ti[j]=ni; cv=ov; ci=oi;
      }
    }
  }
#pragma unroll
  for (int j=0;j<16;j++){ sv[lane*16+j]=tv[j]; si[lane*16+j]=ti[j]; }
  __syncthreads();
  int p = 0;
  for (int r=0;r<kk;r++){
    float cv = (p<16) ? sv[lane*16+p] : INFINITY;
    int   ci = (p<16) ? si[lane*16+p] : 0x7fffffff;
    int   cl = lane;
#pragma unroll
    for (int off=32; off; off>>=1){
      float ov = __shfl_xor(cv, off);
      int   oi = __shfl_xor(ci, off);
      int   ol = __shfl_xor(cl, off);
      bool take = (ov<cv) || (ov==cv && oi<ci);
      if (take){ cv=ov; ci=oi; cl=ol; }
    }
    if (lane==cl) p++;
    if (lane==0) sel[r]=ci;
  }
  __syncthreads();
  const float* f1n = feat1 + (size_t)row*CC;
  float e0 = f1n[lane], e1 = f1n[64+lane];
  float acc = 0.f;
  for (int r=0;r<kk;r++){
    const float* g = feat1 + ((size_t)b*NN + sel[r])*CC;
    float d0 = g[lane]-e0, d1 = g[64+lane]-e1;
    acc = fmaf(d0,d0,acc); acc = fmaf(d1,d1,acc);
  }
  acc = wave_sum(acc);
  if (lane==0) atomicAdd((double*)(ws+OFF_ACC)+2, (double)acc);
}

// ---------------- proj2img stats: min/max, grid size, center offsets ----------------
__global__ void k_imgstats(const float* __restrict__ verts2, const float* __restrict__ imgoff,
                           float* __restrict__ ws) {
  __shared__ float r0[4], r1[4], r2[4], r3[4];
  __shared__ float sgs, smnx, smny;
  int img = blockIdx.x >> 2, b = blockIdx.x & 3;
  const float* pc = (img==0) ? (ws + OFF_V12 + (size_t)b*NN*3) : (verts2 + (size_t)b*NN*3);
  int lane = threadIdx.x & 63, wid = threadIdx.x >> 6;
  float mnx=INFINITY, mxx=-INFINITY, mny=INFINITY, mxy=-INFINITY;
  for (int n = threadIdx.x; n < NN; n += 256) {
    float x = pc[(size_t)n*3], y = pc[(size_t)n*3+1];
    mnx=fminf(mnx,x); mxx=fmaxf(mxx,x); mny=fminf(mny,y); mxy=fmaxf(mxy,y);
  }
#pragma unroll
  for (int off=32; off; off>>=1) {
    mnx=fminf(mnx,__shfl_xor(mnx,off)); mxx=fmaxf(mxx,__shfl_xor(mxx,off));
    mny=fminf(mny,__shfl_xor(mny,off)); mxy=fmaxf(mxy,__shfl_xor(mxy,off));
  }
  if (lane==0){ r0[wid]=mnx; r1[wid]=mxx; r2[wid]=mny; r3[wid]=mxy; }
  __syncthreads();
  float* st = ws + OFF_STATS + (size_t)(img*4+b)*16;
  if (threadIdx.x==0){
    mnx=fminf(fminf(r0[0],r0[1]),fminf(r0[2],r0[3]));
    mxx=fmaxf(fmaxf(r1[0],r1[1]),fmaxf(r1[2],r1[3]));
    mny=fminf(fminf(r2[0],r2[1]),fminf(r2[2],r2[3]));
    mxy=fmaxf(fmaxf(r3[0],r3[1]),fmaxf(r3[2],r3[3]));
    float gs = fmaxf(mxx-mnx, mxy-mny) / 221.0f;
    sgs=gs; smnx=mnx; smny=mny;
    st[0]=mnx; st[1]=mxx; st[2]=mny; st[3]=mxy; st[4]=gs;
  }
  __syncthreads();
  float gs=sgs, bx=smnx, by=smny;
  float fmnx=INFINITY, fmxx=-INFINITY, fmny=INFINITY, fmxy=-INFINITY;
  for (int n = threadIdx.x; n < NN; n += 256) {
    float fx = floorf((pc[(size_t)n*3]-bx)/gs);
    float fy = floorf((pc[(size_t)n*3+1]-by)/gs);
    fmnx=fminf(fmnx,fx); fmxx=fmaxf(fmxx,fx); fmny=fminf(fmny,fy); fmxy=fmaxf(fmxy,fy);
  }
#pragma unroll
  for (int off=32; off; off>>=1) {
    fmnx=fminf(fmnx,__shfl_xor(fmnx,off)); fmxx=fmaxf(fmxx,__shfl_xor(fmxx,off));
    fmny=fminf(fmny,__shfl_xor(fmny,off)); fmxy=fmaxf(fmxy,__shfl_xor(fmxy,off));
  }
  __syncthreads();  // r arrays reuse
  if (lane==0){ r0[wid]=fmnx; r1[wid]=fmxx; r2[wid]=fmny; r3[wid]=fmxy; }
  __syncthreads();
  if (threadIdx.x==0){
    fmnx=fminf(fminf(r0[0],r0[1]),fminf(r0[2],r0[3]));
    fmxx=fmaxf(fmaxf(r1[0],r1[1]),fmaxf(r1[2],r1[3]));
    fmny=fminf(fminf(r2[0],r2[1]),fminf(r2[2],r2[3]));
    fmxy=fmaxf(fmaxf(r3[0],r3[1]),fmaxf(r3[2],r3[3]));
    float omnx=INFINITY, omxx=-INFINITY, omny=INFINITY, omxy=-INFINITY;
    for (int l=0;l<25;l++){
      float ox=imgoff[l*2], oy=imgoff[l*2+1];
      omnx=fminf(omnx,ox); omxx=fmaxf(omxx,ox); omny=fminf(omny,oy); omxy=fmaxf(omxy,oy);
    }
    float cx = floorf(((fmxx+omxx+1.0f)+(fmnx+omnx+1.0f))*0.5f);
    float cy = floorf(((fmxy+omxy+1.0f)+(fmny+omny+1.0f))*0.5f);
    st[5] = (112.0f - cx) - 1.0f;
    st[6] = (112.0f - cy) - 1.0f;
  }
}

// ---------------- scatter z into both images ----------------
__global__ void k_scatter(const float* __restrict__ verts2, const float* __restrict__ imgoff,
                          float* __restrict__ ws) {
  int t = blockIdx.x*blockDim.x + threadIdx.x;
  if (t >= 2*BB*NN) return;
  int img = t / (BB*NN); int r = t - img*(BB*NN); int b = r / NN;
  const float* pc = (img==0) ? (ws + OFF_V12) : verts2;
  float x = pc[(size_t)r*3], y = pc[(size_t)r*3+1], z = pc[(size_t)r*3+2];
  const float* st = ws + OFF_STATS + (size_t)(img*4+b)*16;
  float mnx=st[0], mny=st[2], gs=st[4], offx=st[5], offy=st[6];
  float bx = floorf((x-mnx)/gs) + 1.0f + offx;
  float by = floorf((y-mny)/gs) + 1.0f + offy;
  float* im = ws + (img==0?OFF_IMG1:OFF_IMG2) + (size_t)b*IMGP;
#pragma unroll
  for (int l=0;l<25;l++){
    float vx = bx + imgoff[l*2], vy = by + imgoff[l*2+1];
    vx += (vx<0.f?1.f:0.f) - (vx>223.f?1.f:0.f);
    vy += (vy<0.f?1.f:0.f) - (vy>223.f?1.f:0.f);
    vx = fminf(fmaxf(vx,0.f),223.f); vy = fminf(fmaxf(vy,0.f),223.f);
    int flat = (int)(vx*224.f + vy);
    atomicAdd(im + flat, z);
  }
}

// ---------------- image loss ----------------
__global__ void k_imgloss(float* __restrict__ ws) {
  int i = blockIdx.x*blockDim.x + threadIdx.x;
  float v = 0.f;
  if (i < BB*IMGP) {
    float a = ws[OFF_IMG1+i], c = ws[OFF_IMG2+i];
    float sa = 1.f/(1.f+expf(-a)), sc = 1.f/(1.f+expf(-c));
    float d = sa - sc; v = d*d;
  }
  v = wave_sum(v);
  if ((threadIdx.x&63)==0) atomicAdd((double*)(ws+OFF_ACC)+1, (double)v);
}

// ---------------- finalize ----------------
__global__ void k_final(const int* __restrict__ kptr, const float* __restrict__ ws, float* __restrict__ out) {
  const double* acc = (const double*)(ws+OFF_ACC);
  int kk = *kptr; if (kk > 16) kk = 16; if (kk < 1) kk = 1;
  double srl = acc[0] / (double)(BB*NN);
  double img = acc[1] / ((double)BB*IMGP);
  double df  = acc[2] / ((double)BB*NN*kk*CC);
  out[0] = (float)(srl + img + df);
}

extern "C" void kernel_launch(void* const* d_in, const int* in_sizes, int n_in,
                              void* d_out, int out_size, void* d_ws, size_t ws_size,
                              hipStream_t stream) {
  (void)in_sizes; (void)n_in; (void)out_size; (void)ws_size;
  const float* verts1 = (const float*)d_in[0];
  const float* verts2 = (const float*)d_in[1];
  const float* feat1  = (const float*)d_in[2];
  const float* feat2  = (const float*)d_in[3];
  const float* imgoff = (const float*)d_in[4];
  const int*   kptr   = (const int*)d_in[5];
  float* ws  = (float*)d_ws;
  float* out = (float*)d_out;

  hipMemsetAsync(ws + ZERO_START, 0, (size_t)ZERO_FLOATS*sizeof(float), stream);

  k_norms<<<(BB*NN+255)/256, 256, 0, stream>>>(verts1, verts2, feat1, feat2, ws);

  dim3 gA(RBLK, SPLITS, BB);
  k_stageA<<<gA, 256, 0, stream>>>(feat1, feat2, verts2, ws);
  k_combine<<<(BB*NN+255)/256, 256, 0, stream>>>(ws);

  k_selfrec<<<(BB*NN+3)/4, 256, 0, stream>>>(verts2, ws);
  k_topk<<<BB*NN, 64, 0, stream>>>(verts1, feat1, kptr, ws);

  k_imgstats<<<8, 256, 0, stream>>>(verts2, imgoff, ws);
  k_scatter<<<(2*BB*NN+255)/256, 256, 0, stream>>>(verts2, imgoff, ws);
  k_imgloss<<<(BB*IMGP+255)/256, 256, 0, stream>>>(ws);

  k_final<<<1,1,0,stream>>>(kptr, ws, out);
}

// Round 3
// 1161.784 us; speedup vs baseline: 1.7121x; 1.3345x over previous
//
#include <hip/hip_runtime.h>
#include <math.h>

#define BB 4
#define NN 4995
#define CC 128
#define IMG 224
#define IMGP (IMG*IMG)
#define ALPHA_F 100.0f
#define SPLITS 8
#define COLS_PER_SPLIT 625   // ceil(4995/8)
#define RBLK 40              // ceil(4995/128): 128-row blocks for MFMA stageA
#define ASTR 40              // LDS row stride in bf16 elems (32 k + 8 pad)

// ws layout in float units
#define OFF_V12    0            // B*N*3 = 59940
#define OFF_FN2    60000        // 19980
#define OFF_VN2    80000        // 19980
#define OFF_VN1    100000       // 19980
#define OFF_FN1    120000       // 19980
#define OFF_PART   140000       // 19980*8*5 = 799200 -> ends 939200
#define OFF_IMG1   940000       // 200704
#define OFF_IMG2   1140704      // 200704
#define OFF_ACC    1341408      // 3*64 f64 buckets = 384 floats (byte off 5365632, 8-aligned)
#define OFF_STATS  1341792      // 2*4*16 = 128 floats
#define ZERO_START OFF_IMG1
#define ZERO_FLOATS (OFF_STATS + 128 - OFF_IMG1)

typedef short v8s  __attribute__((ext_vector_type(8)));
typedef float v16f __attribute__((ext_vector_type(16)));

__device__ __forceinline__ float wave_min(float v){
#pragma unroll
  for (int off=32; off; off>>=1) v = fminf(v, __shfl_xor(v, off));
  return v;
}
__device__ __forceinline__ float wave_sum(float v){
#pragma unroll
  for (int off=32; off; off>>=1) v += __shfl_xor(v, off);
  return v;
}

// pack top-16 bits (bf16 truncation) of two floats: (hi16(b)<<16)|hi16(a)
__device__ __forceinline__ int pack_bf_hi(float a, float b){
  return (int)__builtin_amdgcn_perm(__float_as_uint(b), __float_as_uint(a), 0x07060302u);
}

// ---------------- norms: vnorm1, vnorm2, fnorm1, fnorm2 ----------------
__global__ void k_norms(const float* __restrict__ verts1, const float* __restrict__ verts2,
                        const float* __restrict__ feat1, const float* __restrict__ feat2,
                        float* __restrict__ ws) {
  int i = blockIdx.x*blockDim.x + threadIdx.x;
  if (i >= BB*NN) return;
  float x=verts1[(size_t)i*3], y=verts1[(size_t)i*3+1], z=verts1[(size_t)i*3+2];
  ws[OFF_VN1+i] = x*x + y*y + z*z;
  x=verts2[(size_t)i*3]; y=verts2[(size_t)i*3+1]; z=verts2[(size_t)i*3+2];
  ws[OFF_VN2+i] = x*x + y*y + z*z;
  {
    const float4* f = (const float4*)(feat2 + (size_t)i*CC);
    float s0=0.f,s1=0.f,s2=0.f,s3=0.f;
#pragma unroll
    for (int k=0;k<CC/4;k++){ float4 t=f[k];
      s0=fmaf(t.x,t.x,s0); s1=fmaf(t.y,t.y,s1); s2=fmaf(t.z,t.z,s2); s3=fmaf(t.w,t.w,s3); }
    ws[OFF_FN2+i] = (s0+s1)+(s2+s3);
  }
  {
    const float4* f = (const float4*)(feat1 + (size_t)i*CC);
    float s0=0.f,s1=0.f,s2=0.f,s3=0.f;
#pragma unroll
    for (int k=0;k<CC/4;k++){ float4 t=f[k];
      s0=fmaf(t.x,t.x,s0); s1=fmaf(t.y,t.y,s1); s2=fmaf(t.z,t.z,s2); s3=fmaf(t.w,t.w,s3); }
    ws[OFF_FN1+i] = (s0+s1)+(s2+s3);
  }
}

// ---------------- stage A: bf16 hi/lo split MFMA GEMM + online softmax ----------------
// grid (RBLK, SPLITS, BB), block 256 = 4 waves x 32 rows. Tile: M=128, N=64, K-step 32.
// v_mfma_f32_32x32x16_bf16: A[m=lane&31][k=(lane>>5)*8+j]; C/D col=lane&31,
// row=(reg&3)+8*(reg>>2)+4*(lane>>5). Softmax state sharded: lane owns row (reg=lane&15, half=lane>>5).
__global__ __launch_bounds__(256) void k_stageA(const float* __restrict__ feat1,
      const float* __restrict__ feat2, const float* __restrict__ verts2,
      float* __restrict__ ws) {
  __shared__ __align__(16) short Ah[128*ASTR];
  __shared__ __align__(16) short Al[128*ASTR];
  __shared__ __align__(16) short Bh[64*ASTR];
  __shared__ __align__(16) short Bl[64*ASTR];

  int rblk  = blockIdx.x;
  int split = blockIdx.y;
  int b     = blockIdx.z;
  int rowBase = rblk*128;
  int colBase = split*COLS_PER_SPLIT;
  int colEnd  = colBase + COLS_PER_SPLIT; if (colEnd > NN) colEnd = NN;
  int nct = (colEnd - colBase + 63) >> 6;

  int t    = threadIdx.x;
  int w    = t >> 6;        // wave id 0..3
  int lane = t & 63;
  int half = lane >> 5;     // 0/1
  int m32  = lane & 31;

  const float* f1b = feat1 + (size_t)b*NN*CC;
  const float* f2b = feat2 + (size_t)b*NN*CC;
  const float* v2b = verts2 + (size_t)b*NN*3;
  const float* fn1 = ws + OFF_FN1 + (size_t)b*NN;
  const float* fn2 = ws + OFF_FN2 + (size_t)b*NN;

  // per-lane row norms for the 16 C-regs (rows of this wave's 32-row strip)
  float snr[16];
#pragma unroll
  for (int reg=0; reg<16; reg++){
    int rIdx = (reg&3) + 8*(reg>>2) + 4*half;
    int grow = rowBase + w*32 + rIdx; if (grow > NN-1) grow = NN-1;
    snr[reg] = fn1[grow];
  }

  // sharded online-softmax state: this lane owns row (reg = lane&15, half)
  float mm = -INFINITY, S = 0.f, Vx = 0.f, Vy = 0.f, Vz = 0.f;

  int arow = w*32 + m32;    // A row this lane reads fragments for

  for (int ci = 0; ci < nct; ci++){
    int ctBase = colBase + ci*64;
    v16f acc0, acc1;
#pragma unroll
    for (int i=0;i<16;i++){ acc0[i]=0.f; acc1[i]=0.f; }

#pragma unroll 1
    for (int kt = 0; kt < 4; kt++){
      int k0 = kt*32;
      __syncthreads();
      // stage A: 128 rows x 32 k (fp32 -> bf16 hi/lo, truncation split)
#pragma unroll
      for (int h=0; h<4; h++){
        int fi = t + 256*h;
        int r = fi>>3, kq = fi&7;
        int grow = rowBase + r; if (grow > NN-1) grow = NN-1;
        float4 v = *(const float4*)(f1b + (size_t)grow*CC + k0 + 4*kq);
        float hx=__uint_as_float(__float_as_uint(v.x)&0xffff0000u);
        float hy=__uint_as_float(__float_as_uint(v.y)&0xffff0000u);
        float hz=__uint_as_float(__float_as_uint(v.z)&0xffff0000u);
        float hw=__uint_as_float(__float_as_uint(v.w)&0xffff0000u);
        int ph01 = pack_bf_hi(v.x, v.y), ph23 = pack_bf_hi(v.z, v.w);
        int pl01 = pack_bf_hi(v.x-hx, v.y-hy), pl23 = pack_bf_hi(v.z-hz, v.w-hw);
        *(int2*)&Ah[r*ASTR + 4*kq] = make_int2(ph01, ph23);
        *(int2*)&Al[r*ASTR + 4*kq] = make_int2(pl01, pl23);
      }
      // stage B: 64 cols x 32 k
#pragma unroll
      for (int h=0; h<2; h++){
        int fi = t + 256*h;
        int c = fi>>3, kq = fi&7;
        int gcol = ctBase + c; if (gcol > NN-1) gcol = NN-1;
        float4 v = *(const float4*)(f2b + (size_t)gcol*CC + k0 + 4*kq);
        float hx=__uint_as_float(__float_as_uint(v.x)&0xffff0000u);
        float hy=__uint_as_float(__float_as_uint(v.y)&0xffff0000u);
        float hz=__uint_as_float(__float_as_uint(v.z)&0xffff0000u);
        float hw=__uint_as_float(__float_as_uint(v.w)&0xffff0000u);
        int ph01 = pack_bf_hi(v.x, v.y), ph23 = pack_bf_hi(v.z, v.w);
        int pl01 = pack_bf_hi(v.x-hx, v.y-hy), pl23 = pack_bf_hi(v.z-hz, v.w-hw);
        *(int2*)&Bh[c*ASTR + 4*kq] = make_int2(ph01, ph23);
        *(int2*)&Bl[c*ASTR + 4*kq] = make_int2(pl01, pl23);
      }
      __syncthreads();

#pragma unroll
      for (int kh=0; kh<2; kh++){
        int ka = kh*16 + half*8;
        v8s a_h = *(const v8s*)&Ah[arow*ASTR + ka];
        v8s a_l = *(const v8s*)&Al[arow*ASTR + ka];
        {
          v8s b_h = *(const v8s*)&Bh[m32*ASTR + ka];
          v8s b_l = *(const v8s*)&Bl[m32*ASTR + ka];
          acc0 = __builtin_amdgcn_mfma_f32_32x32x16_bf16(a_h, b_h, acc0, 0,0,0);
          acc0 = __builtin_amdgcn_mfma_f32_32x32x16_bf16(a_h, b_l, acc0, 0,0,0);
          acc0 = __builtin_amdgcn_mfma_f32_32x32x16_bf16(a_l, b_h, acc0, 0,0,0);
        }
        {
          v8s b_h = *(const v8s*)&Bh[(32+m32)*ASTR + ka];
          v8s b_l = *(const v8s*)&Bl[(32+m32)*ASTR + ka];
          acc1 = __builtin_amdgcn_mfma_f32_32x32x16_bf16(a_h, b_h, acc1, 0,0,0);
          acc1 = __builtin_amdgcn_mfma_f32_32x32x16_bf16(a_h, b_l, acc1, 0,0,0);
          acc1 = __builtin_amdgcn_mfma_f32_32x32x16_bf16(a_l, b_h, acc1, 0,0,0);
        }
      }
    }

    // ---- epilogue: online softmax over this 128x64 tile ----
    int c0 = ctBase + m32, c1 = c0 + 32;
    bool valid0 = (c0 < colEnd), valid1 = (c1 < colEnd);
    int cc0 = c0 > NN-1 ? NN-1 : c0, cc1 = c1 > NN-1 ? NN-1 : c1;
    float fnc0 = fn2[cc0], fnc1 = fn2[cc1];
    float wx0 = v2b[(size_t)cc0*3], wy0 = v2b[(size_t)cc0*3+1], wz0 = v2b[(size_t)cc0*3+2];
    float wx1 = v2b[(size_t)cc1*3], wy1 = v2b[(size_t)cc1*3+1], wz1 = v2b[(size_t)cc1*3+2];

#pragma unroll
    for (int reg=0; reg<16; reg++){
      float d20 = fmaf(-2.f, acc0[reg], snr[reg]) + fnc0;
      float d21 = fmaf(-2.f, acc1[reg], snr[reg]) + fnc1;
      float l0 = valid0 ? (-ALPHA_F * sqrtf(fmaxf(d20, 1e-12f))) : -INFINITY;
      float l1 = valid1 ? (-ALPHA_F * sqrtf(fmaxf(d21, 1e-12f))) : -INFINITY;
      float Mt = fmaxf(l0, l1);
#pragma unroll
      for (int off=1; off<32; off<<=1) Mt = fmaxf(Mt, __shfl_xor(Mt, off));
      float mnA = fmaxf(mm, Mt);                 // valid on owner lanes
      float mnb = __shfl(mnA, (lane & 32) + reg); // broadcast owner's new max
      float e0 = __expf(l0 - mnb), e1 = __expf(l1 - mnb);
      float se = e0 + e1;
      float sx = fmaf(e0, wx0, e1*wx1);
      float sy = fmaf(e0, wy0, e1*wy1);
      float sz = fmaf(e0, wz0, e1*wz1);
#pragma unroll
      for (int off=1; off<32; off<<=1){
        se += __shfl_xor(se, off); sx += __shfl_xor(sx, off);
        sy += __shfl_xor(sy, off); sz += __shfl_xor(sz, off);
      }
      bool own = ((lane & 15) == reg);
      float sc = __expf(mm - mnb);
      S  = own ? fmaf(S,  sc, se) : S;
      Vx = own ? fmaf(Vx, sc, sx) : Vx;
      Vy = own ? fmaf(Vy, sc, sy) : Vy;
      Vz = own ? fmaf(Vz, sc, sz) : Vz;
      mm = own ? mnb : mm;
    }
  }

  // write partials: one writer per (reg, half)
  {
    int reg = lane & 15;
    int rIdx = (reg&3) + 8*(reg>>2) + 4*half;
    int n = rowBase + w*32 + rIdx;
    if (((lane & 16) == 0) && n < NN){
      float* p = ws + OFF_PART + ((size_t)(b*NN+n)*SPLITS + split)*5;
      p[0]=mm; p[1]=S; p[2]=Vx; p[3]=Vy; p[4]=Vz;
    }
  }
}

// ---------------- combine partials -> verts12 ----------------
__global__ void k_combine(float* __restrict__ ws) {
  int row = blockIdx.x*blockDim.x + threadIdx.x;
  if (row >= BB*NN) return;
  const float* p = ws + OFF_PART + (size_t)row*SPLITS*5;
  float mm = -INFINITY;
#pragma unroll
  for (int s=0;s<SPLITS;s++) mm = fmaxf(mm, p[s*5]);
  float S=0.f,Vx=0.f,Vy=0.f,Vz=0.f;
#pragma unroll
  for (int s=0;s<SPLITS;s++){
    float sc = expf(p[s*5]-mm);
    S  += p[s*5+1]*sc; Vx += p[s*5+2]*sc; Vy += p[s*5+3]*sc; Vz += p[s*5+4]*sc;
  }
  ws[OFF_V12+(size_t)row*3+0]=Vx/S;
  ws[OFF_V12+(size_t)row*3+1]=Vy/S;
  ws[OFF_V12+(size_t)row*3+2]=Vz/S;
}

// ---------------- self-rec: mean over rows of min_m sqdist(verts12, verts2) ----------------
__global__ void k_selfrec(const float* __restrict__ verts2, float* __restrict__ ws) {
  int wid = threadIdx.x >> 6;
  int row = blockIdx.x*4 + wid;
  int lane = threadIdx.x & 63;
  if (row >= BB*NN) return;
  int b = row / NN;
  const float* v12 = ws + OFF_V12 + (size_t)row*3;
  float x=v12[0], y=v12[1], z=v12[2];
  float sa = x*x + y*y + z*z;
  const float* vn2 = ws + OFF_VN2 + (size_t)b*NN;
  const float* v2 = verts2 + (size_t)b*NN*3;
  float mn = INFINITY;
  for (int m=lane; m<NN; m+=64) {
    float wx=v2[(size_t)m*3], wy=v2[(size_t)m*3+1], wz=v2[(size_t)m*3+2];
    float d2 = (sa - 2.0f*(x*wx + y*wy + z*wz)) + vn2[m];
    mn = fminf(mn, d2);
  }
  mn = wave_min(mn);
  if (lane==0)
    atomicAdd(((double*)(ws+OFF_ACC)) + (((blockIdx.x & 15)<<2) | wid), (double)mn);
}

// ---------------- top-k (k<=16) of sqdist(verts1,verts1) + deform feat MSE ----------------
__global__ __launch_bounds__(64) void k_topk(const float* __restrict__ verts1,
        const float* __restrict__ feat1, const int* __restrict__ kptr,
        float* __restrict__ ws) {
  __shared__ float sv[64*16];
  __shared__ int   si[64*16];
  __shared__ int   sel[16];
  int row = blockIdx.x;
  int lane = threadIdx.x;
  int b = row / NN; int n = row - b*NN;
  int kk = *kptr; if (kk > 16) kk = 16; if (kk < 1) kk = 1;
  const float* v1 = verts1 + (size_t)row*3;
  float x=v1[0], y=v1[1], z=v1[2];
  const float* vn1 = ws + OFF_VN1 + (size_t)b*NN;
  float sa = vn1[n];
  const float* vb = verts1 + (size_t)b*NN*3;
  float tv[16]; int ti[16];
#pragma unroll
  for (int j=0;j<16;j++){ tv[j]=INFINITY; ti[j]=0x7fffffff; }
  for (int m=lane; m<NN; m+=64) {
    float wx=vb[(size_t)m*3], wy=vb[(size_t)m*3+1], wz=vb[(size_t)m*3+2];
    float d2 = (sa - 2.0f*(x*wx+y*wy+z*wz)) + vn1[m];
    if (d2 < tv[15] || (d2 == tv[15] && m < ti[15])) {
      float cv=d2; int ci=m;
#pragma unroll
      for (int j=0;j<16;j++){
        bool lt = (cv<tv[j]) || (cv==tv[j] && ci<ti[j]);
        float nv = lt?cv:tv[j]; int ni = lt?ci:ti[j];
        float ov = lt?tv[j]:cv; int oi = lt?ti[j]:ci;
        tv[j]=nv; ti[j]=ni; cv=ov; ci=oi;
      }
    }
  }
#pragma unroll
  for (int j=0;j<16;j++){ sv[lane*16+j]=tv[j]; si[lane*16+j]=ti[j]; }
  __syncthreads();
  int p = 0;
  for (int r=0;r<kk;r++){
    float cv = (p<16) ? sv[lane*16+p] : INFINITY;
    int   ci = (p<16) ? si[lane*16+p] : 0x7fffffff;
    int   cl = lane;
#pragma unroll
    for (int off=32; off; off>>=1){
      float ov = __shfl_xor(cv, off);
      int   oi = __shfl_xor(ci, off);
      int   ol = __shfl_xor(cl, off);
      bool take = (ov<cv) || (ov==cv && oi<ci);
      if (take){ cv=ov; ci=oi; cl=ol; }
    }
    if (lane==cl) p++;
    if (lane==0) sel[r]=ci;
  }
  __syncthreads();
  const float* f1n = feat1 + (size_t)row*CC;
  float e0 = f1n[lane], e1 = f1n[64+lane];
  float acc = 0.f;
  for (int r=0;r<kk;r++){
    const float* g = feat1 + ((size_t)b*NN + sel[r])*CC;
    float d0 = g[lane]-e0, d1 = g[64+lane]-e1;
    acc = fmaf(d0,d0,acc); acc = fmaf(d1,d1,acc);
  }
  acc = wave_sum(acc);
  if (lane==0)
    atomicAdd(((double*)(ws+OFF_ACC)) + 128 + (blockIdx.x & 63), (double)acc);
}

// ---------------- proj2img stats ----------------
__global__ void k_imgstats(const float* __restrict__ verts2, const float* __restrict__ imgoff,
                           float* __restrict__ ws) {
  __shared__ float r0[4], r1[4], r2[4], r3[4];
  __shared__ float sgs, smnx, smny;
  int img = blockIdx.x >> 2, b = blockIdx.x & 3;
  const float* pc = (img==0) ? (ws + OFF_V12 + (size_t)b*NN*3) : (verts2 + (size_t)b*NN*3);
  int lane = threadIdx.x & 63, wid = threadIdx.x >> 6;
  float mnx=INFINITY, mxx=-INFINITY, mny=INFINITY, mxy=-INFINITY;
  for (int n = threadIdx.x; n < NN; n += 256) {
    float x = pc[(size_t)n*3], y = pc[(size_t)n*3+1];
    mnx=fminf(mnx,x); mxx=fmaxf(mxx,x); mny=fminf(mny,y); mxy=fmaxf(mxy,y);
  }
#pragma unroll
  for (int off=32; off; off>>=1) {
    mnx=fminf(mnx,__shfl_xor(mnx,off)); mxx=fmaxf(mxx,__shfl_xor(mxx,off));
    mny=fminf(mny,__shfl_xor(mny,off)); mxy=fmaxf(mxy,__shfl_xor(mxy,off));
  }
  if (lane==0){ r0[wid]=mnx; r1[wid]=mxx; r2[wid]=mny; r3[wid]=mxy; }
  __syncthreads();
  float* st = ws + OFF_STATS + (size_t)(img*4+b)*16;
  if (threadIdx.x==0){
    mnx=fminf(fminf(r0[0],r0[1]),fminf(r0[2],r0[3]));
    mxx=fmaxf(fmaxf(r1[0],r1[1]),fmaxf(r1[2],r1[3]));
    mny=fminf(fminf(r2[0],r2[1]),fminf(r2[2],r2[3]));
    mxy=fmaxf(fmaxf(r3[0],r3[1]),fmaxf(r3[2],r3[3]));
    float gs = fmaxf(mxx-mnx, mxy-mny) / 221.0f;
    sgs=gs; smnx=mnx; smny=mny;
    st[0]=mnx; st[1]=mxx; st[2]=mny; st[3]=mxy; st[4]=gs;
  }
  __syncthreads();
  float gs=sgs, bx=smnx, by=smny;
  float fmnx=INFINITY, fmxx=-INFINITY, fmny=INFINITY, fmxy=-INFINITY;
  for (int n = threadIdx.x; n < NN; n += 256) {
    float fx = floorf((pc[(size_t)n*3]-bx)/gs);
    float fy = floorf((pc[(size_t)n*3+1]-by)/gs);
    fmnx=fminf(fmnx,fx); fmxx=fmaxf(fmxx,fx); fmny=fminf(fmny,fy); fmxy=fmaxf(fmxy,fy);
  }
#pragma unroll
  for (int off=32; off; off>>=1) {
    fmnx=fminf(fmnx,__shfl_xor(fmnx,off)); fmxx=fmaxf(fmxx,__shfl_xor(fmxx,off));
    fmny=fminf(fmny,__shfl_xor(fmny,off)); fmxy=fmaxf(fmxy,__shfl_xor(fmxy,off));
  }
  __syncthreads();
  if (lane==0){ r0[wid]=fmnx; r1[wid]=fmxx; r2[wid]=fmny; r3[wid]=fmxy; }
  __syncthreads();
  if (threadIdx.x==0){
    fmnx=fminf(fminf(r0[0],r0[1]),fminf(r0[2],r0[3]));
    fmxx=fmaxf(fmaxf(r1[0],r1[1]),fmaxf(r1[2],r1[3]));
    fmny=fminf(fminf(r2[0],r2[1]),fminf(r2[2],r2[3]));
    fmxy=fmaxf(fmaxf(r3[0],r3[1]),fmaxf(r3[2],r3[3]));
    float omnx=INFINITY, omxx=-INFINITY, omny=INFINITY, omxy=-INFINITY;
    for (int l=0;l<25;l++){
      float ox=imgoff[l*2], oy=imgoff[l*2+1];
      omnx=fminf(omnx,ox); omxx=fmaxf(omxx,ox); omny=fminf(omny,oy); omxy=fmaxf(omxy,oy);
    }
    float cx = floorf(((fmxx+omxx+1.0f)+(fmnx+omnx+1.0f))*0.5f);
    float cy = floorf(((fmxy+omxy+1.0f)+(fmny+omny+1.0f))*0.5f);
    st[5] = (112.0f - cx) - 1.0f;
    st[6] = (112.0f - cy) - 1.0f;
  }
}

// ---------------- scatter z into both images ----------------
__global__ void k_scatter(const float* __restrict__ verts2, const float* __restrict__ imgoff,
                          float* __restrict__ ws) {
  int t = blockIdx.x*blockDim.x + threadIdx.x;
  if (t >= 2*BB*NN) return;
  int img = t / (BB*NN); int r = t - img*(BB*NN); int b = r / NN;
  const float* pc = (img==0) ? (ws + OFF_V12) : verts2;
  float x = pc[(size_t)r*3], y = pc[(size_t)r*3+1], z = pc[(size_t)r*3+2];
  const float* st = ws + OFF_STATS + (size_t)(img*4+b)*16;
  float mnx=st[0], mny=st[2], gs=st[4], offx=st[5], offy=st[6];
  float bx = floorf((x-mnx)/gs) + 1.0f + offx;
  float by = floorf((y-mny)/gs) + 1.0f + offy;
  float* im = ws + (img==0?OFF_IMG1:OFF_IMG2) + (size_t)b*IMGP;
#pragma unroll
  for (int l=0;l<25;l++){
    float vx = bx + imgoff[l*2], vy = by + imgoff[l*2+1];
    vx += (vx<0.f?1.f:0.f) - (vx>223.f?1.f:0.f);
    vy += (vy<0.f?1.f:0.f) - (vy>223.f?1.f:0.f);
    vx = fminf(fmaxf(vx,0.f),223.f); vy = fminf(fmaxf(vy,0.f),223.f);
    int flat = (int)(vx*224.f + vy);
    atomicAdd(im + flat, z);
  }
}

// ---------------- image loss ----------------
__global__ void k_imgloss(float* __restrict__ ws) {
  int i = blockIdx.x*blockDim.x + threadIdx.x;
  float v = 0.f;
  if (i < BB*IMGP) {
    float a = ws[OFF_IMG1+i], c = ws[OFF_IMG2+i];
    float sa = 1.f/(1.f+expf(-a)), sc = 1.f/(1.f+expf(-c));
    float d = sa - sc; v = d*d;
  }
  v = wave_sum(v);
  if ((threadIdx.x&63)==0)
    atomicAdd(((double*)(ws+OFF_ACC)) + 64 + (blockIdx.x & 63), (double)v);
}

// ---------------- finalize ----------------
__global__ void k_final(const int* __restrict__ kptr, const float* __restrict__ ws, float* __restrict__ out) {
  const double* acc = (const double*)(ws+OFF_ACC);
  int kk = *kptr; if (kk > 16) kk = 16; if (kk < 1) kk = 1;
  double a0=0.0, a1=0.0, a2=0.0;
  for (int j=0;j<64;j++){ a0 += acc[j]; a1 += acc[64+j]; a2 += acc[128+j]; }
  double srl = a0 / (double)(BB*NN);
  double img = a1 / ((double)BB*IMGP);
  double df  = a2 / ((double)BB*NN*kk*CC);
  out[0] = (float)(srl + img + df);
}

extern "C" void kernel_launch(void* const* d_in, const int* in_sizes, int n_in,
                              void* d_out, int out_size, void* d_ws, size_t ws_size,
                              hipStream_t stream) {
  (void)in_sizes; (void)n_in; (void)out_size; (void)ws_size;
  const float* verts1 = (const float*)d_in[0];
  const float* verts2 = (const float*)d_in[1];
  const float* feat1  = (const float*)d_in[2];
  const float* feat2  = (const float*)d_in[3];
  const float* imgoff = (const float*)d_in[4];
  const int*   kptr   = (const int*)d_in[5];
  float* ws  = (float*)d_ws;
  float* out = (float*)d_out;

  hipMemsetAsync(ws + ZERO_START, 0, (size_t)ZERO_FLOATS*sizeof(float), stream);

  k_norms<<<(BB*NN+255)/256, 256, 0, stream>>>(verts1, verts2, feat1, feat2, ws);

  dim3 gA(RBLK, SPLITS, BB);
  k_stageA<<<gA, 256, 0, stream>>>(feat1, feat2, verts2, ws);
  k_combine<<<(BB*NN+255)/256, 256, 0, stream>>>(ws);

  k_selfrec<<<(BB*NN+3)/4, 256, 0, stream>>>(verts2, ws);
  k_topk<<<BB*NN, 64, 0, stream>>>(verts1, feat1, kptr, ws);

  k_imgstats<<<8, 256, 0, stream>>>(verts2, imgoff, ws);
  k_scatter<<<(2*BB*NN+255)/256, 256, 0, stream>>>(verts2, imgoff, ws);
  k_imgloss<<<(BB*IMGP+255)/256, 256, 0, stream>>>(ws);

  k_final<<<1,1,0,stream>>>(kptr, ws, out);
}

// Round 4
// 919.518 us; speedup vs baseline: 2.1632x; 1.2635x over previous
//
#include <hip/hip_runtime.h>
#include <math.h>

#define BB 4
#define NN 4995
#define CC 128
#define IMG 224
#define IMGP (IMG*IMG)
#define ALPHA_F 100.0f
#define SPLITS 8
#define COLS_PER_SPLIT 625   // ceil(4995/8)
#define RBLK 40              // ceil(4995/128): 128-row blocks for MFMA stageA
#define ASTR 40              // LDS row stride in bf16 elems (32 k + 8 pad)

// ws layout in float units
#define OFF_V12    0            // B*N*3 = 59940
#define OFF_FN2    60000        // 19980
#define OFF_VN2    80000        // 19980
#define OFF_VN1    100000       // 19980
#define OFF_FN1    120000       // 19980
#define OFF_PART   140000       // 19980*8*5 = 799200 -> ends 939200
#define OFF_IMG1   940000       // 200704
#define OFF_IMG2   1140704      // 200704
#define OFF_ACC    1341408      // 3*64 f64 buckets = 384 floats (byte off 5365632, 8-aligned)
#define OFF_STATS  1341792      // 2*4*16 = 128 floats
#define ZERO_START OFF_IMG1
#define ZERO_FLOATS (OFF_STATS + 128 - OFF_IMG1)

typedef short v8s  __attribute__((ext_vector_type(8)));
typedef float v16f __attribute__((ext_vector_type(16)));

__device__ __forceinline__ float wave_min(float v){
#pragma unroll
  for (int off=32; off; off>>=1) v = fminf(v, __shfl_xor(v, off));
  return v;
}
__device__ __forceinline__ float wave_sum(float v){
#pragma unroll
  for (int off=32; off; off>>=1) v += __shfl_xor(v, off);
  return v;
}

// pack top-16 bits (bf16 truncation) of two floats: (hi16(b)<<16)|hi16(a)
__device__ __forceinline__ int pack_bf_hi(float a, float b){
  return (int)__builtin_amdgcn_perm(__float_as_uint(b), __float_as_uint(a), 0x07060302u);
}

// ---------------- norms: vnorm1, vnorm2, fnorm1, fnorm2 ----------------
__global__ void k_norms(const float* __restrict__ verts1, const float* __restrict__ verts2,
                        const float* __restrict__ feat1, const float* __restrict__ feat2,
                        float* __restrict__ ws) {
  int i = blockIdx.x*blockDim.x + threadIdx.x;
  if (i >= BB*NN) return;
  float x=verts1[(size_t)i*3], y=verts1[(size_t)i*3+1], z=verts1[(size_t)i*3+2];
  ws[OFF_VN1+i] = x*x + y*y + z*z;
  x=verts2[(size_t)i*3]; y=verts2[(size_t)i*3+1]; z=verts2[(size_t)i*3+2];
  ws[OFF_VN2+i] = x*x + y*y + z*z;
  {
    const float4* f = (const float4*)(feat2 + (size_t)i*CC);
    float s0=0.f,s1=0.f,s2=0.f,s3=0.f;
#pragma unroll
    for (int k=0;k<CC/4;k++){ float4 t=f[k];
      s0=fmaf(t.x,t.x,s0); s1=fmaf(t.y,t.y,s1); s2=fmaf(t.z,t.z,s2); s3=fmaf(t.w,t.w,s3); }
    ws[OFF_FN2+i] = (s0+s1)+(s2+s3);
  }
  {
    const float4* f = (const float4*)(feat1 + (size_t)i*CC);
    float s0=0.f,s1=0.f,s2=0.f,s3=0.f;
#pragma unroll
    for (int k=0;k<CC/4;k++){ float4 t=f[k];
      s0=fmaf(t.x,t.x,s0); s1=fmaf(t.y,t.y,s1); s2=fmaf(t.z,t.z,s2); s3=fmaf(t.w,t.w,s3); }
    ws[OFF_FN1+i] = (s0+s1)+(s2+s3);
  }
}

// ---------------- stage A: bf16 hi/lo split MFMA GEMM + online softmax ----------------
__global__ __launch_bounds__(256) void k_stageA(const float* __restrict__ feat1,
      const float* __restrict__ feat2, const float* __restrict__ verts2,
      float* __restrict__ ws) {
  __shared__ __align__(16) short Ah[128*ASTR];
  __shared__ __align__(16) short Al[128*ASTR];
  __shared__ __align__(16) short Bh[64*ASTR];
  __shared__ __align__(16) short Bl[64*ASTR];

  int rblk  = blockIdx.x;
  int split = blockIdx.y;
  int b     = blockIdx.z;
  int rowBase = rblk*128;
  int colBase = split*COLS_PER_SPLIT;
  int colEnd  = colBase + COLS_PER_SPLIT; if (colEnd > NN) colEnd = NN;
  int nct = (colEnd - colBase + 63) >> 6;

  int t    = threadIdx.x;
  int w    = t >> 6;        // wave id 0..3
  int lane = t & 63;
  int half = lane >> 5;     // 0/1
  int m32  = lane & 31;

  const float* f1b = feat1 + (size_t)b*NN*CC;
  const float* f2b = feat2 + (size_t)b*NN*CC;
  const float* v2b = verts2 + (size_t)b*NN*3;
  const float* fn1 = ws + OFF_FN1 + (size_t)b*NN;
  const float* fn2 = ws + OFF_FN2 + (size_t)b*NN;

  float snr[16];
#pragma unroll
  for (int reg=0; reg<16; reg++){
    int rIdx = (reg&3) + 8*(reg>>2) + 4*half;
    int grow = rowBase + w*32 + rIdx; if (grow > NN-1) grow = NN-1;
    snr[reg] = fn1[grow];
  }

  float mm = -INFINITY, S = 0.f, Vx = 0.f, Vy = 0.f, Vz = 0.f;
  int arow = w*32 + m32;

  for (int ci = 0; ci < nct; ci++){
    int ctBase = colBase + ci*64;
    v16f acc0, acc1;
#pragma unroll
    for (int i=0;i<16;i++){ acc0[i]=0.f; acc1[i]=0.f; }

#pragma unroll 1
    for (int kt = 0; kt < 4; kt++){
      int k0 = kt*32;
      __syncthreads();
#pragma unroll
      for (int h=0; h<4; h++){
        int fi = t + 256*h;
        int r = fi>>3, kq = fi&7;
        int grow = rowBase + r; if (grow > NN-1) grow = NN-1;
        float4 v = *(const float4*)(f1b + (size_t)grow*CC + k0 + 4*kq);
        float hx=__uint_as_float(__float_as_uint(v.x)&0xffff0000u);
        float hy=__uint_as_float(__float_as_uint(v.y)&0xffff0000u);
        float hz=__uint_as_float(__float_as_uint(v.z)&0xffff0000u);
        float hw=__uint_as_float(__float_as_uint(v.w)&0xffff0000u);
        int ph01 = pack_bf_hi(v.x, v.y), ph23 = pack_bf_hi(v.z, v.w);
        int pl01 = pack_bf_hi(v.x-hx, v.y-hy), pl23 = pack_bf_hi(v.z-hz, v.w-hw);
        *(int2*)&Ah[r*ASTR + 4*kq] = make_int2(ph01, ph23);
        *(int2*)&Al[r*ASTR + 4*kq] = make_int2(pl01, pl23);
      }
#pragma unroll
      for (int h=0; h<2; h++){
        int fi = t + 256*h;
        int c = fi>>3, kq = fi&7;
        int gcol = ctBase + c; if (gcol > NN-1) gcol = NN-1;
        float4 v = *(const float4*)(f2b + (size_t)gcol*CC + k0 + 4*kq);
        float hx=__uint_as_float(__float_as_uint(v.x)&0xffff0000u);
        float hy=__uint_as_float(__float_as_uint(v.y)&0xffff0000u);
        float hz=__uint_as_float(__float_as_uint(v.z)&0xffff0000u);
        float hw=__uint_as_float(__float_as_uint(v.w)&0xffff0000u);
        int ph01 = pack_bf_hi(v.x, v.y), ph23 = pack_bf_hi(v.z, v.w);
        int pl01 = pack_bf_hi(v.x-hx, v.y-hy), pl23 = pack_bf_hi(v.z-hz, v.w-hw);
        *(int2*)&Bh[c*ASTR + 4*kq] = make_int2(ph01, ph23);
        *(int2*)&Bl[c*ASTR + 4*kq] = make_int2(pl01, pl23);
      }
      __syncthreads();

#pragma unroll
      for (int kh=0; kh<2; kh++){
        int ka = kh*16 + half*8;
        v8s a_h = *(const v8s*)&Ah[arow*ASTR + ka];
        v8s a_l = *(const v8s*)&Al[arow*ASTR + ka];
        {
          v8s b_h = *(const v8s*)&Bh[m32*ASTR + ka];
          v8s b_l = *(const v8s*)&Bl[m32*ASTR + ka];
          acc0 = __builtin_amdgcn_mfma_f32_32x32x16_bf16(a_h, b_h, acc0, 0,0,0);
          acc0 = __builtin_amdgcn_mfma_f32_32x32x16_bf16(a_h, b_l, acc0, 0,0,0);
          acc0 = __builtin_amdgcn_mfma_f32_32x32x16_bf16(a_l, b_h, acc0, 0,0,0);
        }
        {
          v8s b_h = *(const v8s*)&Bh[(32+m32)*ASTR + ka];
          v8s b_l = *(const v8s*)&Bl[(32+m32)*ASTR + ka];
          acc1 = __builtin_amdgcn_mfma_f32_32x32x16_bf16(a_h, b_h, acc1, 0,0,0);
          acc1 = __builtin_amdgcn_mfma_f32_32x32x16_bf16(a_h, b_l, acc1, 0,0,0);
          acc1 = __builtin_amdgcn_mfma_f32_32x32x16_bf16(a_l, b_h, acc1, 0,0,0);
        }
      }
    }

    // ---- epilogue: online softmax over this 128x64 tile ----
    int c0 = ctBase + m32, c1 = c0 + 32;
    bool valid0 = (c0 < colEnd), valid1 = (c1 < colEnd);
    int cc0 = c0 > NN-1 ? NN-1 : c0, cc1 = c1 > NN-1 ? NN-1 : c1;
    float fnc0 = fn2[cc0], fnc1 = fn2[cc1];
    float wx0 = v2b[(size_t)cc0*3], wy0 = v2b[(size_t)cc0*3+1], wz0 = v2b[(size_t)cc0*3+2];
    float wx1 = v2b[(size_t)cc1*3], wy1 = v2b[(size_t)cc1*3+1], wz1 = v2b[(size_t)cc1*3+2];

#pragma unroll
    for (int reg=0; reg<16; reg++){
      float d20 = fmaf(-2.f, acc0[reg], snr[reg]) + fnc0;
      float d21 = fmaf(-2.f, acc1[reg], snr[reg]) + fnc1;
      float l0 = valid0 ? (-ALPHA_F * sqrtf(fmaxf(d20, 1e-12f))) : -INFINITY;
      float l1 = valid1 ? (-ALPHA_F * sqrtf(fmaxf(d21, 1e-12f))) : -INFINITY;
      float Mt = fmaxf(l0, l1);
#pragma unroll
      for (int off=1; off<32; off<<=1) Mt = fmaxf(Mt, __shfl_xor(Mt, off));
      float mnA = fmaxf(mm, Mt);
      float mnb = __shfl(mnA, (lane & 32) + reg);
      float e0 = __expf(l0 - mnb), e1 = __expf(l1 - mnb);
      float se = e0 + e1;
      float sx = fmaf(e0, wx0, e1*wx1);
      float sy = fmaf(e0, wy0, e1*wy1);
      float sz = fmaf(e0, wz0, e1*wz1);
#pragma unroll
      for (int off=1; off<32; off<<=1){
        se += __shfl_xor(se, off); sx += __shfl_xor(sx, off);
        sy += __shfl_xor(sy, off); sz += __shfl_xor(sz, off);
      }
      bool own = ((lane & 15) == reg);
      float sc = __expf(mm - mnb);
      S  = own ? fmaf(S,  sc, se) : S;
      Vx = own ? fmaf(Vx, sc, sx) : Vx;
      Vy = own ? fmaf(Vy, sc, sy) : Vy;
      Vz = own ? fmaf(Vz, sc, sz) : Vz;
      mm = own ? mnb : mm;
    }
  }

  {
    int reg = lane & 15;
    int rIdx = (reg&3) + 8*(reg>>2) + 4*half;
    int n = rowBase + w*32 + rIdx;
    if (((lane & 16) == 0) && n < NN){
      float* p = ws + OFF_PART + ((size_t)(b*NN+n)*SPLITS + split)*5;
      p[0]=mm; p[1]=S; p[2]=Vx; p[3]=Vy; p[4]=Vz;
    }
  }
}

// ---------------- combine partials -> verts12 ----------------
__global__ void k_combine(float* __restrict__ ws) {
  int row = blockIdx.x*blockDim.x + threadIdx.x;
  if (row >= BB*NN) return;
  const float* p = ws + OFF_PART + (size_t)row*SPLITS*5;
  float mm = -INFINITY;
#pragma unroll
  for (int s=0;s<SPLITS;s++) mm = fmaxf(mm, p[s*5]);
  float S=0.f,Vx=0.f,Vy=0.f,Vz=0.f;
#pragma unroll
  for (int s=0;s<SPLITS;s++){
    float sc = expf(p[s*5]-mm);
    S  += p[s*5+1]*sc; Vx += p[s*5+2]*sc; Vy += p[s*5+3]*sc; Vz += p[s*5+4]*sc;
  }
  ws[OFF_V12+(size_t)row*3+0]=Vx/S;
  ws[OFF_V12+(size_t)row*3+1]=Vy/S;
  ws[OFF_V12+(size_t)row*3+2]=Vz/S;
}

// ---------------- self-rec: mean over rows of min_m sqdist(verts12, verts2) ----------------
__global__ void k_selfrec(const float* __restrict__ verts2, float* __restrict__ ws) {
  int wid = threadIdx.x >> 6;
  int row = blockIdx.x*4 + wid;
  int lane = threadIdx.x & 63;
  if (row >= BB*NN) return;
  int b = row / NN;
  const float* v12 = ws + OFF_V12 + (size_t)row*3;
  float x=v12[0], y=v12[1], z=v12[2];
  float sa = x*x + y*y + z*z;
  const float* vn2 = ws + OFF_VN2 + (size_t)b*NN;
  const float* v2 = verts2 + (size_t)b*NN*3;
  float mn = INFINITY;
  for (int m=lane; m<NN; m+=64) {
    float wx=v2[(size_t)m*3], wy=v2[(size_t)m*3+1], wz=v2[(size_t)m*3+2];
    float d2 = (sa - 2.0f*(x*wx + y*wy + z*wz)) + vn2[m];
    mn = fminf(mn, d2);
  }
  mn = wave_min(mn);
  if (lane==0)
    atomicAdd(((double*)(ws+OFF_ACC)) + (((blockIdx.x & 15)<<2) | wid), (double)mn);
}

// ---------------- top-k via LDS key table + kk rounds of block-argmin ----------------
// block = 256 threads per row. keys: monotonic-u32(d2); kv = (key<<13)|idx for exact
// lowest-index tie-break. Winner slots overwritten with 0xFFFFFFFF (unreachable by finite d2).
__global__ __launch_bounds__(256) void k_topk(const float* __restrict__ verts1,
        const float* __restrict__ feat1, const int* __restrict__ kptr,
        float* __restrict__ ws) {
  __shared__ unsigned int keys[NN];
  __shared__ unsigned long long red[4];
  __shared__ float rs[4];
  __shared__ int sel[16];
  int row = blockIdx.x;
  int t = threadIdx.x;
  int lane = t & 63, wid = t >> 6;
  int b = row / NN; int n = row - b*NN;
  int kk = *kptr; if (kk > 16) kk = 16; if (kk < 1) kk = 1;

  const float* v1 = verts1 + (size_t)row*3;
  float x=v1[0], y=v1[1], z=v1[2];
  const float* vn1 = ws + OFF_VN1 + (size_t)b*NN;
  float sa = vn1[n];
  const float* vb = verts1 + (size_t)b*NN*3;

  // phase 1: build keys
  for (int m=t; m<NN; m+=256) {
    float wx=vb[(size_t)m*3], wy=vb[(size_t)m*3+1], wz=vb[(size_t)m*3+2];
    float d2 = (sa - 2.0f*(x*wx+y*wy+z*wz)) + vn1[m];
    unsigned int u = __float_as_uint(d2);
    u = ((int)u < 0) ? ~u : (u ^ 0x80000000u);
    keys[m] = u;
  }
  __syncthreads();

  // phase 2: kk rounds of argmin-extract
  for (int r=0; r<kk; r++){
    unsigned long long best = ~0ull;
    for (int i=t; i<NN; i+=256) {
      unsigned long long kv = ((unsigned long long)keys[i] << 13) | (unsigned int)i;
      best = (kv < best) ? kv : best;
    }
#pragma unroll
    for (int off=32; off; off>>=1){
      unsigned long long o = __shfl_xor(best, off);
      best = (o < best) ? o : best;
    }
    if (lane==0) red[wid] = best;
    __syncthreads();
    if (t==0){
      unsigned long long b0 = red[0] < red[1] ? red[0] : red[1];
      unsigned long long b1 = red[2] < red[3] ? red[2] : red[3];
      unsigned long long bw = b0 < b1 ? b0 : b1;
      int idx = (int)(bw & 8191ull);
      sel[r] = idx;
      keys[idx] = 0xFFFFFFFFu;
    }
    __syncthreads();
  }

  // phase 3: deform feat MSE over selected neighbors
  int c = t & 127;
  int rh = t >> 7;  // 0/1
  const float* f1n = feat1 + (size_t)row*CC;
  float e = f1n[c];
  float acc = 0.f;
  for (int r=rh; r<kk; r+=2){
    const float* g = feat1 + ((size_t)b*NN + sel[r])*CC;
    float d = g[c]-e;
    acc = fmaf(d,d,acc);
  }
  acc = wave_sum(acc);
  if (lane==0) rs[wid] = acc;
  __syncthreads();
  if (t==0){
    float s = (rs[0]+rs[1])+(rs[2]+rs[3]);
    atomicAdd(((double*)(ws+OFF_ACC)) + 128 + (blockIdx.x & 63), (double)s);
  }
}

// ---------------- proj2img stats ----------------
__global__ void k_imgstats(const float* __restrict__ verts2, const float* __restrict__ imgoff,
                           float* __restrict__ ws) {
  __shared__ float r0[4], r1[4], r2[4], r3[4];
  __shared__ float sgs, smnx, smny;
  int img = blockIdx.x >> 2, b = blockIdx.x & 3;
  const float* pc = (img==0) ? (ws + OFF_V12 + (size_t)b*NN*3) : (verts2 + (size_t)b*NN*3);
  int lane = threadIdx.x & 63, wid = threadIdx.x >> 6;
  float mnx=INFINITY, mxx=-INFINITY, mny=INFINITY, mxy=-INFINITY;
  for (int n = threadIdx.x; n < NN; n += 256) {
    float x = pc[(size_t)n*3], y = pc[(size_t)n*3+1];
    mnx=fminf(mnx,x); mxx=fmaxf(mxx,x); mny=fminf(mny,y); mxy=fmaxf(mxy,y);
  }
#pragma unroll
  for (int off=32; off; off>>=1) {
    mnx=fminf(mnx,__shfl_xor(mnx,off)); mxx=fmaxf(mxx,__shfl_xor(mxx,off));
    mny=fminf(mny,__shfl_xor(mny,off)); mxy=fmaxf(mxy,__shfl_xor(mxy,off));
  }
  if (lane==0){ r0[wid]=mnx; r1[wid]=mxx; r2[wid]=mny; r3[wid]=mxy; }
  __syncthreads();
  float* st = ws + OFF_STATS + (size_t)(img*4+b)*16;
  if (threadIdx.x==0){
    mnx=fminf(fminf(r0[0],r0[1]),fminf(r0[2],r0[3]));
    mxx=fmaxf(fmaxf(r1[0],r1[1]),fmaxf(r1[2],r1[3]));
    mny=fminf(fminf(r2[0],r2[1]),fminf(r2[2],r2[3]));
    mxy=fmaxf(fmaxf(r3[0],r3[1]),fmaxf(r3[2],r3[3]));
    float gs = fmaxf(mxx-mnx, mxy-mny) / 221.0f;
    sgs=gs; smnx=mnx; smny=mny;
    st[0]=mnx; st[1]=mxx; st[2]=mny; st[3]=mxy; st[4]=gs;
  }
  __syncthreads();
  float gs=sgs, bx=smnx, by=smny;
  float fmnx=INFINITY, fmxx=-INFINITY, fmny=INFINITY, fmxy=-INFINITY;
  for (int n = threadIdx.x; n < NN; n += 256) {
    float fx = floorf((pc[(size_t)n*3]-bx)/gs);
    float fy = floorf((pc[(size_t)n*3+1]-by)/gs);
    fmnx=fminf(fmnx,fx); fmxx=fmaxf(fmxx,fx); fmny=fminf(fmny,fy); fmxy=fmaxf(fmxy,fy);
  }
#pragma unroll
  for (int off=32; off; off>>=1) {
    fmnx=fminf(fmnx,__shfl_xor(fmnx,off)); fmxx=fmaxf(fmxx,__shfl_xor(fmxx,off));
    fmny=fminf(fmny,__shfl_xor(fmny,off)); fmxy=fmaxf(fmxy,__shfl_xor(fmxy,off));
  }
  __syncthreads();
  if (lane==0){ r0[wid]=fmnx; r1[wid]=fmxx; r2[wid]=fmny; r3[wid]=fmxy; }
  __syncthreads();
  if (threadIdx.x==0){
    fmnx=fminf(fminf(r0[0],r0[1]),fminf(r0[2],r0[3]));
    fmxx=fmaxf(fmaxf(r1[0],r1[1]),fmaxf(r1[2],r1[3]));
    fmny=fminf(fminf(r2[0],r2[1]),fminf(r2[2],r2[3]));
    fmxy=fmaxf(fmaxf(r3[0],r3[1]),fmaxf(r3[2],r3[3]));
    float omnx=INFINITY, omxx=-INFINITY, omny=INFINITY, omxy=-INFINITY;
    for (int l=0;l<25;l++){
      float ox=imgoff[l*2], oy=imgoff[l*2+1];
      omnx=fminf(omnx,ox); omxx=fmaxf(omxx,ox); omny=fminf(omny,oy); omxy=fmaxf(omxy,oy);
    }
    float cx = floorf(((fmxx+omxx+1.0f)+(fmnx+omnx+1.0f))*0.5f);
    float cy = floorf(((fmxy+omxy+1.0f)+(fmny+omny+1.0f))*0.5f);
    st[5] = (112.0f - cx) - 1.0f;
    st[6] = (112.0f - cy) - 1.0f;
  }
}

// ---------------- scatter z into both images ----------------
__global__ void k_scatter(const float* __restrict__ verts2, const float* __restrict__ imgoff,
                          float* __restrict__ ws) {
  int t = blockIdx.x*blockDim.x + threadIdx.x;
  if (t >= 2*BB*NN) return;
  int img = t / (BB*NN); int r = t - img*(BB*NN); int b = r / NN;
  const float* pc = (img==0) ? (ws + OFF_V12) : verts2;
  float x = pc[(size_t)r*3], y = pc[(size_t)r*3+1], z = pc[(size_t)r*3+2];
  const float* st = ws + OFF_STATS + (size_t)(img*4+b)*16;
  float mnx=st[0], mny=st[2], gs=st[4], offx=st[5], offy=st[6];
  float bx = floorf((x-mnx)/gs) + 1.0f + offx;
  float by = floorf((y-mny)/gs) + 1.0f + offy;
  float* im = ws + (img==0?OFF_IMG1:OFF_IMG2) + (size_t)b*IMGP;
#pragma unroll
  for (int l=0;l<25;l++){
    float vx = bx + imgoff[l*2], vy = by + imgoff[l*2+1];
    vx += (vx<0.f?1.f:0.f) - (vx>223.f?1.f:0.f);
    vy += (vy<0.f?1.f:0.f) - (vy>223.f?1.f:0.f);
    vx = fminf(fmaxf(vx,0.f),223.f); vy = fminf(fmaxf(vy,0.f),223.f);
    int flat = (int)(vx*224.f + vy);
    atomicAdd(im + flat, z);
  }
}

// ---------------- image loss ----------------
__global__ void k_imgloss(float* __restrict__ ws) {
  int i = blockIdx.x*blockDim.x + threadIdx.x;
  float v = 0.f;
  if (i < BB*IMGP) {
    float a = ws[OFF_IMG1+i], c = ws[OFF_IMG2+i];
    float sa = 1.f/(1.f+expf(-a)), sc = 1.f/(1.f+expf(-c));
    float d = sa - sc; v = d*d;
  }
  v = wave_sum(v);
  if ((threadIdx.x&63)==0)
    atomicAdd(((double*)(ws+OFF_ACC)) + 64 + (blockIdx.x & 63), (double)v);
}

// ---------------- finalize ----------------
__global__ void k_final(const int* __restrict__ kptr, const float* __restrict__ ws, float* __restrict__ out) {
  const double* acc = (const double*)(ws+OFF_ACC);
  int kk = *kptr; if (kk > 16) kk = 16; if (kk < 1) kk = 1;
  double a0=0.0, a1=0.0, a2=0.0;
  for (int j=0;j<64;j++){ a0 += acc[j]; a1 += acc[64+j]; a2 += acc[128+j]; }
  double srl = a0 / (double)(BB*NN);
  double img = a1 / ((double)BB*IMGP);
  double df  = a2 / ((double)BB*NN*kk*CC);
  out[0] = (float)(srl + img + df);
}

extern "C" void kernel_launch(void* const* d_in, const int* in_sizes, int n_in,
                              void* d_out, int out_size, void* d_ws, size_t ws_size,
                              hipStream_t stream) {
  (void)in_sizes; (void)n_in; (void)out_size; (void)ws_size;
  const float* verts1 = (const float*)d_in[0];
  const float* verts2 = (const float*)d_in[1];
  const float* feat1  = (const float*)d_in[2];
  const float* feat2  = (const float*)d_in[3];
  const float* imgoff = (const float*)d_in[4];
  const int*   kptr   = (const int*)d_in[5];
  float* ws  = (float*)d_ws;
  float* out = (float*)d_out;

  hipMemsetAsync(ws + ZERO_START, 0, (size_t)ZERO_FLOATS*sizeof(float), stream);

  k_norms<<<(BB*NN+255)/256, 256, 0, stream>>>(verts1, verts2, feat1, feat2, ws);

  dim3 gA(RBLK, SPLITS, BB);
  k_stageA<<<gA, 256, 0, stream>>>(feat1, feat2, verts2, ws);
  k_combine<<<(BB*NN+255)/256, 256, 0, stream>>>(ws);

  k_selfrec<<<(BB*NN+3)/4, 256, 0, stream>>>(verts2, ws);
  k_topk<<<BB*NN, 256, 0, stream>>>(verts1, feat1, kptr, ws);

  k_imgstats<<<8, 256, 0, stream>>>(verts2, imgoff, ws);
  k_scatter<<<(2*BB*NN+255)/256, 256, 0, stream>>>(verts2, imgoff, ws);
  k_imgloss<<<(BB*IMGP+255)/256, 256, 0, stream>>>(ws);

  k_final<<<1,1,0,stream>>>(kptr, ws, out);
}

// Round 5
// 745.670 us; speedup vs baseline: 2.6675x; 1.2331x over previous
//
#include <hip/hip_runtime.h>
#include <math.h>

#define BB 4
#define NN 4995
#define CC 128
#define IMG 224
#define IMGP (IMG*IMG)
#define ALPHA_F 100.0f
#define SPLITS 8
#define COLS_PER_SPLIT 640   // 32-aligned; 8*640=5120 >= 4995
#define RBLK 40              // ceil(4995/128)
#define NG 158               // col groups of 32 (incl. 1 pad group)

// ws layout in float units
#define OFF_V12    0            // 59940
#define OFF_FN1    60000        // 19980
#define OFF_V1Q    81000        // 79920 {x,y,z,|v1|^2}
#define OFF_V2Q    161000       // 79920 {x,y,z,|v2|^2}
#define OFF_C2Q    241000       // 79920 {x,y,z,|f2|^2}
#define OFF_PART   321000       // 19980*8*5 = 799200 -> ends 1120200
#define OFF_IMG1   1121000      // 200704
#define OFF_IMG2   1321704      // 200704 -> ends 1522408
#define OFF_ACC    1522408      // 3*64 f64 = 384 floats (byte 6089632, 8-aligned)
#define OFF_STATS  1522792      // 128 -> ends 1522920
#define OFF_F2H    1523000      // 4*158*4096 shorts = 1294336 floats
#define OFF_F2L    2818000      // 1294336 floats -> ends 4112336 (16.45MB)
#define ZERO_START OFF_IMG1
#define ZERO_FLOATS (1522920 - OFF_IMG1)

typedef short v8s  __attribute__((ext_vector_type(8)));
typedef float v16f __attribute__((ext_vector_type(16)));

__device__ __forceinline__ float wave_min(float v){
#pragma unroll
  for (int off=32; off; off>>=1) v = fminf(v, __shfl_xor(v, off));
  return v;
}
__device__ __forceinline__ float wave_sum(float v){
#pragma unroll
  for (int off=32; off; off>>=1) v += __shfl_xor(v, off);
  return v;
}

// pack top-16 bits (bf16 truncation) of two floats: (hi16(b)<<16)|hi16(a)
__device__ __forceinline__ int pack_bf_hi(float a, float b){
  return (int)__builtin_amdgcn_perm(__float_as_uint(b), __float_as_uint(a), 0x07060302u);
}

// ---------------- norms + packed quads ----------------
__global__ void k_norms(const float* __restrict__ verts1, const float* __restrict__ verts2,
                        const float* __restrict__ feat1, const float* __restrict__ feat2,
                        float* __restrict__ ws) {
  int i = blockIdx.x*blockDim.x + threadIdx.x;
  if (i >= BB*NN) return;
  float x=verts1[(size_t)i*3], y=verts1[(size_t)i*3+1], z=verts1[(size_t)i*3+2];
  ((float4*)(ws+OFF_V1Q))[i] = make_float4(x,y,z, x*x+y*y+z*z);
  float x2=verts2[(size_t)i*3], y2=verts2[(size_t)i*3+1], z2=verts2[(size_t)i*3+2];
  ((float4*)(ws+OFF_V2Q))[i] = make_float4(x2,y2,z2, x2*x2+y2*y2+z2*z2);
  {
    const float4* f = (const float4*)(feat2 + (size_t)i*CC);
    float s0=0.f,s1=0.f,s2=0.f,s3=0.f;
#pragma unroll
    for (int k=0;k<CC/4;k++){ float4 t=f[k];
      s0=fmaf(t.x,t.x,s0); s1=fmaf(t.y,t.y,s1); s2=fmaf(t.z,t.z,s2); s3=fmaf(t.w,t.w,s3); }
    ((float4*)(ws+OFF_C2Q))[i] = make_float4(x2,y2,z2, (s0+s1)+(s2+s3));
  }
  {
    const float4* f = (const float4*)(feat1 + (size_t)i*CC);
    float s0=0.f,s1=0.f,s2=0.f,s3=0.f;
#pragma unroll
    for (int k=0;k<CC/4;k++){ float4 t=f[k];
      s0=fmaf(t.x,t.x,s0); s1=fmaf(t.y,t.y,s1); s2=fmaf(t.z,t.z,s2); s3=fmaf(t.w,t.w,s3); }
    ws[OFF_FN1+i] = (s0+s1)+(s2+s3);
  }
}

// ---------------- pre-convert feat2 -> tiled bf16 hi/lo ----------------
// layout [b][g][kt4][kh2][half2][c32][j8], strides (shorts): j=1,c32=8,half=256,kh=512,kt=1024,g=4096
__global__ __launch_bounds__(256) void k_conv(const float* __restrict__ feat2, float* __restrict__ ws) {
  int g = blockIdx.x, b = blockIdx.y;
  int t = threadIdx.x;
  int q = t >> 5, c32 = t & 31;
  int col = g*32 + c32; if (col > NN-1) col = NN-1;
  const float4* src = (const float4*)(feat2 + ((size_t)(b*NN + col))*CC) + q*4;
  float4 v0 = src[0], v1 = src[1], v2 = src[2], v3 = src[3];
  short* f2h = (short*)(ws + OFF_F2H);
  short* f2l = (short*)(ws + OFF_F2L);
  size_t base = ((size_t)(b*NG + g))*4096 + (size_t)q*512 + c32*8;  // kt*1024+kh*512 = q*512
#pragma unroll
  for (int h=0; h<2; h++){
    float4 a = h ? v2 : v0;
    float4 c = h ? v3 : v1;
    float hx=__uint_as_float(__float_as_uint(a.x)&0xffff0000u);
    float hy=__uint_as_float(__float_as_uint(a.y)&0xffff0000u);
    float hz=__uint_as_float(__float_as_uint(a.z)&0xffff0000u);
    float hw=__uint_as_float(__float_as_uint(a.w)&0xffff0000u);
    float gx=__uint_as_float(__float_as_uint(c.x)&0xffff0000u);
    float gy=__uint_as_float(__float_as_uint(c.y)&0xffff0000u);
    float gz=__uint_as_float(__float_as_uint(c.z)&0xffff0000u);
    float gw=__uint_as_float(__float_as_uint(c.w)&0xffff0000u);
    int4 hi = make_int4(pack_bf_hi(a.x,a.y), pack_bf_hi(a.z,a.w),
                        pack_bf_hi(c.x,c.y), pack_bf_hi(c.z,c.w));
    int4 lo = make_int4(pack_bf_hi(a.x-hx,a.y-hy), pack_bf_hi(a.z-hz,a.w-hw),
                        pack_bf_hi(c.x-gx,c.y-gy), pack_bf_hi(c.z-gz,c.w-gw));
    *(int4*)&f2h[base + h*256] = hi;
    *(int4*)&f2l[base + h*256] = lo;
  }
}

// ---------------- stage A: swapped-operand MFMA GEMM + in-lane online softmax ----------------
// D = A(feat2)·B(feat1): lane&31 = feat1 row (within wave's 32-row strip), regs+half = feat2 col.
// Each lane owns ONE row and 32 in-lane columns per 64-col tile -> no shuffles in softmax.
__global__ __launch_bounds__(256) void k_stageA(const float* __restrict__ feat1,
      float* __restrict__ ws) {
  __shared__ __align__(16) short Ah[4096], Al[4096];   // feat1: [gg4][kh2][half2][r32][j8]
  __shared__ __align__(16) short Bh[2048], Bl[2048];   // feat2: [cg2][kh2][half2][c32][j8]
  __shared__ __align__(16) float colq[64*4];           // {x,y,z,fn2} per col

  int rblk  = blockIdx.x;
  int split = blockIdx.y;
  int b     = blockIdx.z;
  int rowBase = rblk*128;
  int colBase = split*COLS_PER_SPLIT;
  int colEnd  = colBase + COLS_PER_SPLIT; if (colEnd > NN) colEnd = NN;
  int nct = (colEnd - colBase + 63) >> 6;

  int t    = threadIdx.x;
  int w    = t >> 6;
  int lane = t & 63;
  int half = lane >> 5;
  int m32  = lane & 31;

  const float* f1b = feat1 + (size_t)b*NN*CC;
  const short* f2h = (const short*)(ws + OFF_F2H);
  const short* f2l = (const short*)(ws + OFF_F2L);
  const float4* c2q = (const float4*)(ws + OFF_C2Q) + (size_t)b*NN;

  int nrow = rowBase + w*32 + m32;
  int nclamp = nrow > NN-1 ? NN-1 : nrow;
  float sn = ws[OFF_FN1 + (size_t)b*NN + nclamp];

  // A(feat1) staging assignment: thread -> (row=t>>1, kh=t&1), 16 consecutive k
  int sr = t >> 1, skh = t & 1;
  int srow = rowBase + sr; if (srow > NN-1) srow = NN-1;
  int sgg = sr >> 5, sr32 = sr & 31;
  const float4* aSrcBase = (const float4*)(f1b + (size_t)srow*CC);
  size_t aDst = (size_t)sgg*1024 + (size_t)skh*512 + sr32*8;

  // B(feat2) staging assignment: thread -> 16B chunk (cg = t>>7)
  int scg = t >> 7;
  size_t bDstOff = (size_t)scg*1024 + (t & 127)*8;

  float mm = -INFINITY, S = 0.f, Vx = 0.f, Vy = 0.f, Vz = 0.f;

  for (int ci = 0; ci < nct; ci++){
    int ctBase = colBase + ci*64;
    int g0 = ctBase >> 5;
    __syncthreads();                    // prior epilogue done before colq rewrite
    if (t < 64){
      int c = ctBase + t; if (c > NN-1) c = NN-1;
      *(float4*)&colq[t*4] = c2q[c];
    }
    v16f acc0, acc1;
#pragma unroll
    for (int i=0;i<16;i++){ acc0[i]=0.f; acc1[i]=0.f; }

#pragma unroll 1
    for (int kt = 0; kt < 4; kt++){
      __syncthreads();
      // ---- stage B (pre-converted): 2 x (b128 load + ds_write_b128) ----
      {
        size_t gsrc = ((size_t)(b*NG + g0 + scg))*4096 + (size_t)kt*1024 + (t & 127)*8;
        int4 vh = *(const int4*)&f2h[gsrc];
        int4 vl = *(const int4*)&f2l[gsrc];
        *(int4*)&Bh[bDstOff] = vh;
        *(int4*)&Bl[bDstOff] = vl;
      }
      // ---- stage A with in-kernel conversion: 4 float4 -> hi/lo int4 pairs ----
      {
        const float4* s4 = aSrcBase + kt*8 + skh*4;
        float4 v0=s4[0], v1=s4[1], v2=s4[2], v3=s4[3];
#pragma unroll
        for (int h=0; h<2; h++){
          float4 a = h ? v2 : v0;
          float4 c = h ? v3 : v1;
          float hx=__uint_as_float(__float_as_uint(a.x)&0xffff0000u);
          float hy=__uint_as_float(__float_as_uint(a.y)&0xffff0000u);
          float hz=__uint_as_float(__float_as_uint(a.z)&0xffff0000u);
          float hw=__uint_as_float(__float_as_uint(a.w)&0xffff0000u);
          float gx=__uint_as_float(__float_as_uint(c.x)&0xffff0000u);
          float gy=__uint_as_float(__float_as_uint(c.y)&0xffff0000u);
          float gz=__uint_as_float(__float_as_uint(c.z)&0xffff0000u);
          float gw=__uint_as_float(__float_as_uint(c.w)&0xffff0000u);
          int4 hi = make_int4(pack_bf_hi(a.x,a.y), pack_bf_hi(a.z,a.w),
                              pack_bf_hi(c.x,c.y), pack_bf_hi(c.z,c.w));
          int4 lo = make_int4(pack_bf_hi(a.x-hx,a.y-hy), pack_bf_hi(a.z-hz,a.w-hw),
                              pack_bf_hi(c.x-gx,c.y-gy), pack_bf_hi(c.z-gz,c.w-gw));
          *(int4*)&Ah[aDst + h*256] = hi;
          *(int4*)&Al[aDst + h*256] = lo;
        }
      }
      __syncthreads();
      // ---- 12 MFMAs ----
#pragma unroll
      for (int kh=0; kh<2; kh++){
        size_t fo = (size_t)kh*512 + (size_t)half*256 + m32*8;
        v8s b1h = *(const v8s*)&Ah[(size_t)w*1024 + fo];
        v8s b1l = *(const v8s*)&Al[(size_t)w*1024 + fo];
        v8s a0h = *(const v8s*)&Bh[fo];
        v8s a0l = *(const v8s*)&Bl[fo];
        v8s a1h = *(const v8s*)&Bh[1024 + fo];
        v8s a1l = *(const v8s*)&Bl[1024 + fo];
        acc0 = __builtin_amdgcn_mfma_f32_32x32x16_bf16(a0h, b1h, acc0, 0,0,0);
        acc0 = __builtin_amdgcn_mfma_f32_32x32x16_bf16(a0h, b1l, acc0, 0,0,0);
        acc0 = __builtin_amdgcn_mfma_f32_32x32x16_bf16(a0l, b1h, acc0, 0,0,0);
        acc1 = __builtin_amdgcn_mfma_f32_32x32x16_bf16(a1h, b1h, acc1, 0,0,0);
        acc1 = __builtin_amdgcn_mfma_f32_32x32x16_bf16(a1h, b1l, acc1, 0,0,0);
        acc1 = __builtin_amdgcn_mfma_f32_32x32x16_bf16(a1l, b1h, acc1, 0,0,0);
      }
    }

    // ---- epilogue: in-lane online softmax (no shuffles) ----
    float Mt = -INFINITY;
#pragma unroll
    for (int reg=0; reg<16; reg++){
      int cp0 = (reg&3) + 8*(reg>>2) + 4*half;
      float f0 = colq[cp0*4+3];
      float d0 = fmaf(-2.f, acc0[reg], sn) + f0;
      float l0 = (ctBase+cp0 < colEnd) ? (-ALPHA_F*sqrtf(fmaxf(d0,1e-12f))) : -INFINITY;
      acc0[reg] = l0; Mt = fmaxf(Mt, l0);
      int cp1 = cp0 + 32;
      float f1v = colq[cp1*4+3];
      float d1 = fmaf(-2.f, acc1[reg], sn) + f1v;
      float l1 = (ctBase+cp1 < colEnd) ? (-ALPHA_F*sqrtf(fmaxf(d1,1e-12f))) : -INFINITY;
      acc1[reg] = l1; Mt = fmaxf(Mt, l1);
    }
    float mn = fmaxf(mm, Mt);
    float sc = __expf(mm - mn);
    float se=0.f, sx=0.f, sy=0.f, sz=0.f;
#pragma unroll
    for (int reg=0; reg<16; reg++){
      int cp0 = (reg&3) + 8*(reg>>2) + 4*half;
      float4 q0 = *(const float4*)&colq[cp0*4];
      float e0 = __expf(acc0[reg] - mn);
      se += e0; sx=fmaf(e0,q0.x,sx); sy=fmaf(e0,q0.y,sy); sz=fmaf(e0,q0.z,sz);
      float4 q1 = *(const float4*)&colq[(cp0+32)*4];
      float e1 = __expf(acc1[reg] - mn);
      se += e1; sx=fmaf(e1,q1.x,sx); sy=fmaf(e1,q1.y,sy); sz=fmaf(e1,q1.z,sz);
    }
    S  = fmaf(S,  sc, se);
    Vx = fmaf(Vx, sc, sx);
    Vy = fmaf(Vy, sc, sy);
    Vz = fmaf(Vz, sc, sz);
    mm = mn;
  }

  // merge the two half-lanes of each row, write partials
  {
    float m2  = __shfl_xor(mm, 32);
    float S2  = __shfl_xor(S,  32);
    float Vx2 = __shfl_xor(Vx, 32);
    float Vy2 = __shfl_xor(Vy, 32);
    float Vz2 = __shfl_xor(Vz, 32);
    float M = fmaxf(mm, m2);
    float c1 = __expf(mm - M), c2 = __expf(m2 - M);
    float Sf  = S*c1  + S2*c2;
    float Vxf = Vx*c1 + Vx2*c2;
    float Vyf = Vy*c1 + Vy2*c2;
    float Vzf = Vz*c1 + Vz2*c2;
    if (half==0 && nrow < NN){
      float* p = ws + OFF_PART + ((size_t)(b*NN+nrow)*SPLITS + split)*5;
      p[0]=M; p[1]=Sf; p[2]=Vxf; p[3]=Vyf; p[4]=Vzf;
    }
  }
}

// ---------------- combine partials -> verts12 ----------------
__global__ void k_combine(float* __restrict__ ws) {
  int row = blockIdx.x*blockDim.x + threadIdx.x;
  if (row >= BB*NN) return;
  const float* p = ws + OFF_PART + (size_t)row*SPLITS*5;
  float mm = -INFINITY;
#pragma unroll
  for (int s=0;s<SPLITS;s++) mm = fmaxf(mm, p[s*5]);
  float S=0.f,Vx=0.f,Vy=0.f,Vz=0.f;
#pragma unroll
  for (int s=0;s<SPLITS;s++){
    float sc = expf(p[s*5]-mm);
    S  += p[s*5+1]*sc; Vx += p[s*5+2]*sc; Vy += p[s*5+3]*sc; Vz += p[s*5+4]*sc;
  }
  ws[OFF_V12+(size_t)row*3+0]=Vx/S;
  ws[OFF_V12+(size_t)row*3+1]=Vy/S;
  ws[OFF_V12+(size_t)row*3+2]=Vz/S;
}

// ---------------- self-rec: mean over rows of min_m sqdist(verts12, verts2) ----------------
__global__ void k_selfrec(float* __restrict__ ws) {
  int wid = threadIdx.x >> 6;
  int row = blockIdx.x*4 + wid;
  int lane = threadIdx.x & 63;
  if (row >= BB*NN) return;
  int b = row / NN;
  const float* v12 = ws + OFF_V12 + (size_t)row*3;
  float x=v12[0], y=v12[1], z=v12[2];
  float sa = x*x + y*y + z*z;
  const float4* v2q = (const float4*)(ws + OFF_V2Q) + (size_t)b*NN;
  float mn = INFINITY;
  for (int m=lane; m<NN; m+=64) {
    float4 q = v2q[m];
    float d2 = fmaf(-2.0f, x*q.x + y*q.y + z*q.z, sa) + q.w;
    mn = fminf(mn, d2);
  }
  mn = wave_min(mn);
  if (lane==0)
    atomicAdd(((double*)(ws+OFF_ACC)) + (((blockIdx.x & 15)<<2) | wid), (double)mn);
}

// ---------------- top-k via LDS key table + kk rounds of block-argmin ----------------
__global__ __launch_bounds__(256) void k_topk(const float* __restrict__ feat1,
        const int* __restrict__ kptr, float* __restrict__ ws) {
  __shared__ unsigned int keys[NN];
  __shared__ unsigned long long red[4];
  __shared__ float rs[4];
  __shared__ int sel[16];
  int row = blockIdx.x;
  int t = threadIdx.x;
  int lane = t & 63, wid = t >> 6;
  int b = row / NN; int n = row - b*NN;
  int kk = *kptr; if (kk > 16) kk = 16; if (kk < 1) kk = 1;

  const float4* v1q = (const float4*)(ws + OFF_V1Q) + (size_t)b*NN;
  float4 me = v1q[n];
  float x=me.x, y=me.y, z=me.z, sa=me.w;

  for (int m=t; m<NN; m+=256) {
    float4 q = v1q[m];
    float d2 = fmaf(-2.0f, x*q.x + y*q.y + z*q.z, sa) + q.w;
    unsigned int u = __float_as_uint(d2);
    u = ((int)u < 0) ? ~u : (u ^ 0x80000000u);
    keys[m] = u;
  }
  __syncthreads();

  for (int r=0; r<kk; r++){
    unsigned long long best = ~0ull;
    for (int i=t; i<NN; i+=256) {
      unsigned long long kv = ((unsigned long long)keys[i] << 13) | (unsigned int)i;
      best = (kv < best) ? kv : best;
    }
#pragma unroll
    for (int off=32; off; off>>=1){
      unsigned long long o = __shfl_xor(best, off);
      best = (o < best) ? o : best;
    }
    if (lane==0) red[wid] = best;
    __syncthreads();
    if (t==0){
      unsigned long long b0 = red[0] < red[1] ? red[0] : red[1];
      unsigned long long b1 = red[2] < red[3] ? red[2] : red[3];
      unsigned long long bw = b0 < b1 ? b0 : b1;
      int idx = (int)(bw & 8191ull);
      sel[r] = idx;
      keys[idx] = 0xFFFFFFFFu;
    }
    __syncthreads();
  }

  int c = t & 127;
  int rh = t >> 7;
  const float* f1n = feat1 + (size_t)row*CC;
  float e = f1n[c];
  float acc = 0.f;
  for (int r=rh; r<kk; r+=2){
    const float* g = feat1 + ((size_t)b*NN + sel[r])*CC;
    float d = g[c]-e;
    acc = fmaf(d,d,acc);
  }
  acc = wave_sum(acc);
  if (lane==0) rs[wid] = acc;
  __syncthreads();
  if (t==0){
    float s = (rs[0]+rs[1])+(rs[2]+rs[3]);
    atomicAdd(((double*)(ws+OFF_ACC)) + 128 + (blockIdx.x & 63), (double)s);
  }
}

// ---------------- proj2img stats ----------------
__global__ void k_imgstats(const float* __restrict__ verts2, const float* __restrict__ imgoff,
                           float* __restrict__ ws) {
  __shared__ float r0[4], r1[4], r2[4], r3[4];
  __shared__ float sgs, smnx, smny;
  int img = blockIdx.x >> 2, b = blockIdx.x & 3;
  const float* pc = (img==0) ? (ws + OFF_V12 + (size_t)b*NN*3) : (verts2 + (size_t)b*NN*3);
  int lane = threadIdx.x & 63, wid = threadIdx.x >> 6;
  float mnx=INFINITY, mxx=-INFINITY, mny=INFINITY, mxy=-INFINITY;
  for (int n = threadIdx.x; n < NN; n += 256) {
    float x = pc[(size_t)n*3], y = pc[(size_t)n*3+1];
    mnx=fminf(mnx,x); mxx=fmaxf(mxx,x); mny=fminf(mny,y); mxy=fmaxf(mxy,y);
  }
#pragma unroll
  for (int off=32; off; off>>=1) {
    mnx=fminf(mnx,__shfl_xor(mnx,off)); mxx=fmaxf(mxx,__shfl_xor(mxx,off));
    mny=fminf(mny,__shfl_xor(mny,off)); mxy=fmaxf(mxy,__shfl_xor(mxy,off));
  }
  if (lane==0){ r0[wid]=mnx; r1[wid]=mxx; r2[wid]=mny; r3[wid]=mxy; }
  __syncthreads();
  float* st = ws + OFF_STATS + (size_t)(img*4+b)*16;
  if (threadIdx.x==0){
    mnx=fminf(fminf(r0[0],r0[1]),fminf(r0[2],r0[3]));
    mxx=fmaxf(fmaxf(r1[0],r1[1]),fmaxf(r1[2],r1[3]));
    mny=fminf(fminf(r2[0],r2[1]),fminf(r2[2],r2[3]));
    mxy=fmaxf(fmaxf(r3[0],r3[1]),fmaxf(r3[2],r3[3]));
    float gs = fmaxf(mxx-mnx, mxy-mny) / 221.0f;
    sgs=gs; smnx=mnx; smny=mny;
    st[0]=mnx; st[1]=mxx; st[2]=mny; st[3]=mxy; st[4]=gs;
  }
  __syncthreads();
  float gs=sgs, bx=smnx, by=smny;
  float fmnx=INFINITY, fmxx=-INFINITY, fmny=INFINITY, fmxy=-INFINITY;
  for (int n = threadIdx.x; n < NN; n += 256) {
    float fx = floorf((pc[(size_t)n*3]-bx)/gs);
    float fy = floorf((pc[(size_t)n*3+1]-by)/gs);
    fmnx=fminf(fmnx,fx); fmxx=fmaxf(fmxx,fx); fmny=fminf(fmny,fy); fmxy=fmaxf(fmxy,fy);
  }
#pragma unroll
  for (int off=32; off; off>>=1) {
    fmnx=fminf(fmnx,__shfl_xor(fmnx,off)); fmxx=fmaxf(fmxx,__shfl_xor(fmxx,off));
    fmny=fminf(fmny,__shfl_xor(fmny,off)); fmxy=fmaxf(fmxy,__shfl_xor(fmxy,off));
  }
  __syncthreads();
  if (lane==0){ r0[wid]=fmnx; r1[wid]=fmxx; r2[wid]=fmny; r3[wid]=fmxy; }
  __syncthreads();
  if (threadIdx.x==0){
    fmnx=fminf(fminf(r0[0],r0[1]),fminf(r0[2],r0[3]));
    fmxx=fmaxf(fmaxf(r1[0],r1[1]),fmaxf(r1[2],r1[3]));
    fmny=fminf(fminf(r2[0],r2[1]),fminf(r2[2],r2[3]));
    fmxy=fmaxf(fmaxf(r3[0],r3[1]),fmaxf(r3[2],r3[3]));
    float omnx=INFINITY, omxx=-INFINITY, omny=INFINITY, omxy=-INFINITY;
    for (int l=0;l<25;l++){
      float ox=imgoff[l*2], oy=imgoff[l*2+1];
      omnx=fminf(omnx,ox); omxx=fmaxf(omxx,ox); omny=fminf(omny,oy); omxy=fmaxf(omxy,oy);
    }
    float cx = floorf(((fmxx+omxx+1.0f)+(fmnx+omnx+1.0f))*0.5f);
    float cy = floorf(((fmxy+omxy+1.0f)+(fmny+omny+1.0f))*0.5f);
    st[5] = (112.0f - cx) - 1.0f;
    st[6] = (112.0f - cy) - 1.0f;
  }
}

// ---------------- scatter z into both images ----------------
__global__ void k_scatter(const float* __restrict__ verts2, const float* __restrict__ imgoff,
                          float* __restrict__ ws) {
  int t = blockIdx.x*blockDim.x + threadIdx.x;
  if (t >= 2*BB*NN) return;
  int img = t / (BB*NN); int r = t - img*(BB*NN); int b = r / NN;
  const float* pc = (img==0) ? (ws + OFF_V12) : verts2;
  float x = pc[(size_t)r*3], y = pc[(size_t)r*3+1], z = pc[(size_t)r*3+2];
  const float* st = ws + OFF_STATS + (size_t)(img*4+b)*16;
  float mnx=st[0], mny=st[2], gs=st[4], offx=st[5], offy=st[6];
  float bx = floorf((x-mnx)/gs) + 1.0f + offx;
  float by = floorf((y-mny)/gs) + 1.0f + offy;
  float* im = ws + (img==0?OFF_IMG1:OFF_IMG2) + (size_t)b*IMGP;
#pragma unroll
  for (int l=0;l<25;l++){
    float vx = bx + imgoff[l*2], vy = by + imgoff[l*2+1];
    vx += (vx<0.f?1.f:0.f) - (vx>223.f?1.f:0.f);
    vy += (vy<0.f?1.f:0.f) - (vy>223.f?1.f:0.f);
    vx = fminf(fmaxf(vx,0.f),223.f); vy = fminf(fmaxf(vy,0.f),223.f);
    int flat = (int)(vx*224.f + vy);
    atomicAdd(im + flat, z);
  }
}

// ---------------- image loss ----------------
__global__ void k_imgloss(float* __restrict__ ws) {
  int i = blockIdx.x*blockDim.x + threadIdx.x;
  float v = 0.f;
  if (i < BB*IMGP) {
    float a = ws[OFF_IMG1+i], c = ws[OFF_IMG2+i];
    float sa = 1.f/(1.f+expf(-a)), sc = 1.f/(1.f+expf(-c));
    float d = sa - sc; v = d*d;
  }
  v = wave_sum(v);
  if ((threadIdx.x&63)==0)
    atomicAdd(((double*)(ws+OFF_ACC)) + 64 + (blockIdx.x & 63), (double)v);
}

// ---------------- finalize ----------------
__global__ void k_final(const int* __restrict__ kptr, const float* __restrict__ ws, float* __restrict__ out) {
  const double* acc = (const double*)(ws+OFF_ACC);
  int kk = *kptr; if (kk > 16) kk = 16; if (kk < 1) kk = 1;
  double a0=0.0, a1=0.0, a2=0.0;
  for (int j=0;j<64;j++){ a0 += acc[j]; a1 += acc[64+j]; a2 += acc[128+j]; }
  double srl = a0 / (double)(BB*NN);
  double img = a1 / ((double)BB*IMGP);
  double df  = a2 / ((double)BB*NN*kk*CC);
  out[0] = (float)(srl + img + df);
}

extern "C" void kernel_launch(void* const* d_in, const int* in_sizes, int n_in,
                              void* d_out, int out_size, void* d_ws, size_t ws_size,
                              hipStream_t stream) {
  (void)in_sizes; (void)n_in; (void)out_size; (void)ws_size;
  const float* verts1 = (const float*)d_in[0];
  const float* verts2 = (const float*)d_in[1];
  const float* feat1  = (const float*)d_in[2];
  const float* feat2  = (const float*)d_in[3];
  const float* imgoff = (const float*)d_in[4];
  const int*   kptr   = (const int*)d_in[5];
  float* ws  = (float*)d_ws;
  float* out = (float*)d_out;

  hipMemsetAsync(ws + ZERO_START, 0, (size_t)ZERO_FLOATS*sizeof(float), stream);

  k_norms<<<(BB*NN+255)/256, 256, 0, stream>>>(verts1, verts2, feat1, feat2, ws);

  dim3 gC(NG, BB);
  k_conv<<<gC, 256, 0, stream>>>(feat2, ws);

  dim3 gA(RBLK, SPLITS, BB);
  k_stageA<<<gA, 256, 0, stream>>>(feat1, ws);
  k_combine<<<(BB*NN+255)/256, 256, 0, stream>>>(ws);

  k_selfrec<<<(BB*NN+3)/4, 256, 0, stream>>>(ws);
  k_topk<<<BB*NN, 256, 0, stream>>>(feat1, kptr, ws);

  k_imgstats<<<8, 256, 0, stream>>>(verts2, imgoff, ws);
  k_scatter<<<(2*BB*NN+255)/256, 256, 0, stream>>>(verts2, imgoff, ws);
  k_imgloss<<<(BB*IMGP+255)/256, 256, 0, stream>>>(ws);

  k_final<<<1,1,0,stream>>>(kptr, ws, out);
}

// Round 6
// 712.558 us; speedup vs baseline: 2.7915x; 1.0465x over previous
//
#include <hip/hip_runtime.h>
#include <math.h>

#define BB 4
#define NN 4995
#define CC 128
#define IMG 224
#define IMGP (IMG*IMG)
#define ALPHA_F 100.0f
#define SPLITS 8
#define COLS_PER_SPLIT 640   // 32-aligned; 8*640=5120 >= 4995
#define RBLK 40              // ceil(4995/128)
#define NG 158               // col groups of 32 (incl. 1 pad group)
#define TKCAND 512

// ws layout in float units
#define OFF_V12    0            // 59940
#define OFF_FN1    60000        // 19980
#define OFF_V1Q    81000        // 79920 {x,y,z,|v1|^2}
#define OFF_V2Q    161000       // 79920 {x,y,z,|v2|^2}
#define OFF_C2Q    241000       // 79920 {x,y,z,|f2|^2}
#define OFF_PART   321000       // 19980*8*5 = 799200 -> ends 1120200
#define OFF_IMG1   1121000      // 200704
#define OFF_IMG2   1321704      // 200704 -> ends 1522408
#define OFF_ACC    1522408      // 3*64 f64 = 384 floats (byte 6089632, 8-aligned)
#define OFF_STATS  1522792      // 128 -> ends 1522920
#define OFF_F2H    1523000      // 4*158*4096 shorts = 1294336 floats
#define OFF_F2L    2818000      // 1294336 floats -> ends 4112336 (16.45MB)
#define ZERO_START OFF_IMG1
#define ZERO_FLOATS (1522920 - OFF_IMG1)

typedef short v8s  __attribute__((ext_vector_type(8)));
typedef float v16f __attribute__((ext_vector_type(16)));

__device__ __forceinline__ float wave_min(float v){
#pragma unroll
  for (int off=32; off; off>>=1) v = fminf(v, __shfl_xor(v, off));
  return v;
}
__device__ __forceinline__ float wave_sum(float v){
#pragma unroll
  for (int off=32; off; off>>=1) v += __shfl_xor(v, off);
  return v;
}

// pack top-16 bits (bf16 truncation) of two floats: (hi16(b)<<16)|hi16(a)
__device__ __forceinline__ int pack_bf_hi(float a, float b){
  return (int)__builtin_amdgcn_perm(__float_as_uint(b), __float_as_uint(a), 0x07060302u);
}

// ---------------- norms + packed quads ----------------
__global__ void k_norms(const float* __restrict__ verts1, const float* __restrict__ verts2,
                        const float* __restrict__ feat1, const float* __restrict__ feat2,
                        float* __restrict__ ws) {
  int i = blockIdx.x*blockDim.x + threadIdx.x;
  if (i >= BB*NN) return;
  float x=verts1[(size_t)i*3], y=verts1[(size_t)i*3+1], z=verts1[(size_t)i*3+2];
  ((float4*)(ws+OFF_V1Q))[i] = make_float4(x,y,z, x*x+y*y+z*z);
  float x2=verts2[(size_t)i*3], y2=verts2[(size_t)i*3+1], z2=verts2[(size_t)i*3+2];
  ((float4*)(ws+OFF_V2Q))[i] = make_float4(x2,y2,z2, x2*x2+y2*y2+z2*z2);
  {
    const float4* f = (const float4*)(feat2 + (size_t)i*CC);
    float s0=0.f,s1=0.f,s2=0.f,s3=0.f;
#pragma unroll
    for (int k=0;k<CC/4;k++){ float4 t=f[k];
      s0=fmaf(t.x,t.x,s0); s1=fmaf(t.y,t.y,s1); s2=fmaf(t.z,t.z,s2); s3=fmaf(t.w,t.w,s3); }
    ((float4*)(ws+OFF_C2Q))[i] = make_float4(x2,y2,z2, (s0+s1)+(s2+s3));
  }
  {
    const float4* f = (const float4*)(feat1 + (size_t)i*CC);
    float s0=0.f,s1=0.f,s2=0.f,s3=0.f;
#pragma unroll
    for (int k=0;k<CC/4;k++){ float4 t=f[k];
      s0=fmaf(t.x,t.x,s0); s1=fmaf(t.y,t.y,s1); s2=fmaf(t.z,t.z,s2); s3=fmaf(t.w,t.w,s3); }
    ws[OFF_FN1+i] = (s0+s1)+(s2+s3);
  }
}

// ---------------- pre-convert feat2 -> tiled bf16 hi/lo ----------------
// layout [b][g][kt4][kh2][half2][c32][j8], strides (shorts): j=1,c32=8,half=256,kh=512,kt=1024,g=4096
__global__ __launch_bounds__(256) void k_conv(const float* __restrict__ feat2, float* __restrict__ ws) {
  int g = blockIdx.x, b = blockIdx.y;
  int t = threadIdx.x;
  int q = t >> 5, c32 = t & 31;
  int col = g*32 + c32; if (col > NN-1) col = NN-1;
  const float4* src = (const float4*)(feat2 + ((size_t)(b*NN + col))*CC) + q*4;
  float4 v0 = src[0], v1 = src[1], v2 = src[2], v3 = src[3];
  short* f2h = (short*)(ws + OFF_F2H);
  short* f2l = (short*)(ws + OFF_F2L);
  size_t base = ((size_t)(b*NG + g))*4096 + (size_t)q*512 + c32*8;
#pragma unroll
  for (int h=0; h<2; h++){
    float4 a = h ? v2 : v0;
    float4 c = h ? v3 : v1;
    float hx=__uint_as_float(__float_as_uint(a.x)&0xffff0000u);
    float hy=__uint_as_float(__float_as_uint(a.y)&0xffff0000u);
    float hz=__uint_as_float(__float_as_uint(a.z)&0xffff0000u);
    float hw=__uint_as_float(__float_as_uint(a.w)&0xffff0000u);
    float gx=__uint_as_float(__float_as_uint(c.x)&0xffff0000u);
    float gy=__uint_as_float(__float_as_uint(c.y)&0xffff0000u);
    float gz=__uint_as_float(__float_as_uint(c.z)&0xffff0000u);
    float gw=__uint_as_float(__float_as_uint(c.w)&0xffff0000u);
    int4 hi = make_int4(pack_bf_hi(a.x,a.y), pack_bf_hi(a.z,a.w),
                        pack_bf_hi(c.x,c.y), pack_bf_hi(c.z,c.w));
    int4 lo = make_int4(pack_bf_hi(a.x-hx,a.y-hy), pack_bf_hi(a.z-hz,a.w-hw),
                        pack_bf_hi(c.x-gx,c.y-gy), pack_bf_hi(c.z-gz,c.w-gw));
    *(int4*)&f2h[base + h*256] = hi;
    *(int4*)&f2l[base + h*256] = lo;
  }
}

// ---------------- stage A: swapped-operand MFMA GEMM + in-lane online softmax ----------------
__global__ __launch_bounds__(256) void k_stageA(const float* __restrict__ feat1,
      float* __restrict__ ws) {
  __shared__ __align__(16) short Ah[4096], Al[4096];   // feat1: [gg4][kh2][half2][r32][j8]
  __shared__ __align__(16) short Bh[2048], Bl[2048];   // feat2: [cg2][kh2][half2][c32][j8]
  __shared__ __align__(16) float colq[64*4];           // {x,y,z,fn2} per col

  int rblk  = blockIdx.x;
  int split = blockIdx.y;
  int b     = blockIdx.z;
  int rowBase = rblk*128;
  int colBase = split*COLS_PER_SPLIT;
  int colEnd  = colBase + COLS_PER_SPLIT; if (colEnd > NN) colEnd = NN;
  int nct = (colEnd - colBase + 63) >> 6;

  int t    = threadIdx.x;
  int w    = t >> 6;
  int lane = t & 63;
  int half = lane >> 5;
  int m32  = lane & 31;

  const float* f1b = feat1 + (size_t)b*NN*CC;
  const short* f2h = (const short*)(ws + OFF_F2H);
  const short* f2l = (const short*)(ws + OFF_F2L);
  const float4* c2q = (const float4*)(ws + OFF_C2Q) + (size_t)b*NN;

  int nrow = rowBase + w*32 + m32;
  int nclamp = nrow > NN-1 ? NN-1 : nrow;
  float sn = ws[OFF_FN1 + (size_t)b*NN + nclamp];

  int sr = t >> 1, skh = t & 1;
  int srow = rowBase + sr; if (srow > NN-1) srow = NN-1;
  int sgg = sr >> 5, sr32 = sr & 31;
  const float4* aSrcBase = (const float4*)(f1b + (size_t)srow*CC);
  size_t aDst = (size_t)sgg*1024 + (size_t)skh*512 + sr32*8;

  int scg = t >> 7;
  size_t bDstOff = (size_t)scg*1024 + (t & 127)*8;

  float mm = -INFINITY, S = 0.f, Vx = 0.f, Vy = 0.f, Vz = 0.f;

  for (int ci = 0; ci < nct; ci++){
    int ctBase = colBase + ci*64;
    int g0 = ctBase >> 5;
    __syncthreads();
    if (t < 64){
      int c = ctBase + t; if (c > NN-1) c = NN-1;
      *(float4*)&colq[t*4] = c2q[c];
    }
    v16f acc0, acc1;
#pragma unroll
    for (int i=0;i<16;i++){ acc0[i]=0.f; acc1[i]=0.f; }

#pragma unroll 1
    for (int kt = 0; kt < 4; kt++){
      __syncthreads();
      {
        size_t gsrc = ((size_t)(b*NG + g0 + scg))*4096 + (size_t)kt*1024 + (t & 127)*8;
        int4 vh = *(const int4*)&f2h[gsrc];
        int4 vl = *(const int4*)&f2l[gsrc];
        *(int4*)&Bh[bDstOff] = vh;
        *(int4*)&Bl[bDstOff] = vl;
      }
      {
        const float4* s4 = aSrcBase + kt*8 + skh*4;
        float4 v0=s4[0], v1=s4[1], v2=s4[2], v3=s4[3];
#pragma unroll
        for (int h=0; h<2; h++){
          float4 a = h ? v2 : v0;
          float4 c = h ? v3 : v1;
          float hx=__uint_as_float(__float_as_uint(a.x)&0xffff0000u);
          float hy=__uint_as_float(__float_as_uint(a.y)&0xffff0000u);
          float hz=__uint_as_float(__float_as_uint(a.z)&0xffff0000u);
          float hw=__uint_as_float(__float_as_uint(a.w)&0xffff0000u);
          float gx=__uint_as_float(__float_as_uint(c.x)&0xffff0000u);
          float gy=__uint_as_float(__float_as_uint(c.y)&0xffff0000u);
          float gz=__uint_as_float(__float_as_uint(c.z)&0xffff0000u);
          float gw=__uint_as_float(__float_as_uint(c.w)&0xffff0000u);
          int4 hi = make_int4(pack_bf_hi(a.x,a.y), pack_bf_hi(a.z,a.w),
                              pack_bf_hi(c.x,c.y), pack_bf_hi(c.z,c.w));
          int4 lo = make_int4(pack_bf_hi(a.x-hx,a.y-hy), pack_bf_hi(a.z-hz,a.w-hw),
                              pack_bf_hi(c.x-gx,c.y-gy), pack_bf_hi(c.z-gz,c.w-gw));
          *(int4*)&Ah[aDst + h*256] = hi;
          *(int4*)&Al[aDst + h*256] = lo;
        }
      }
      __syncthreads();
#pragma unroll
      for (int kh=0; kh<2; kh++){
        size_t fo = (size_t)kh*512 + (size_t)half*256 + m32*8;
        v8s b1h = *(const v8s*)&Ah[(size_t)w*1024 + fo];
        v8s b1l = *(const v8s*)&Al[(size_t)w*1024 + fo];
        v8s a0h = *(const v8s*)&Bh[fo];
        v8s a0l = *(const v8s*)&Bl[fo];
        v8s a1h = *(const v8s*)&Bh[1024 + fo];
        v8s a1l = *(const v8s*)&Bl[1024 + fo];
        acc0 = __builtin_amdgcn_mfma_f32_32x32x16_bf16(a0h, b1h, acc0, 0,0,0);
        acc0 = __builtin_amdgcn_mfma_f32_32x32x16_bf16(a0h, b1l, acc0, 0,0,0);
        acc0 = __builtin_amdgcn_mfma_f32_32x32x16_bf16(a0l, b1h, acc0, 0,0,0);
        acc1 = __builtin_amdgcn_mfma_f32_32x32x16_bf16(a1h, b1h, acc1, 0,0,0);
        acc1 = __builtin_amdgcn_mfma_f32_32x32x16_bf16(a1h, b1l, acc1, 0,0,0);
        acc1 = __builtin_amdgcn_mfma_f32_32x32x16_bf16(a1l, b1h, acc1, 0,0,0);
      }
    }

    float Mt = -INFINITY;
#pragma unroll
    for (int reg=0; reg<16; reg++){
      int cp0 = (reg&3) + 8*(reg>>2) + 4*half;
      float f0 = colq[cp0*4+3];
      float d0 = fmaf(-2.f, acc0[reg], sn) + f0;
      float l0 = (ctBase+cp0 < colEnd) ? (-ALPHA_F*sqrtf(fmaxf(d0,1e-12f))) : -INFINITY;
      acc0[reg] = l0; Mt = fmaxf(Mt, l0);
      int cp1 = cp0 + 32;
      float f1v = colq[cp1*4+3];
      float d1 = fmaf(-2.f, acc1[reg], sn) + f1v;
      float l1 = (ctBase+cp1 < colEnd) ? (-ALPHA_F*sqrtf(fmaxf(d1,1e-12f))) : -INFINITY;
      acc1[reg] = l1; Mt = fmaxf(Mt, l1);
    }
    float mn = fmaxf(mm, Mt);
    float sc = __expf(mm - mn);
    float se=0.f, sx=0.f, sy=0.f, sz=0.f;
#pragma unroll
    for (int reg=0; reg<16; reg++){
      int cp0 = (reg&3) + 8*(reg>>2) + 4*half;
      float4 q0 = *(const float4*)&colq[cp0*4];
      float e0 = __expf(acc0[reg] - mn);
      se += e0; sx=fmaf(e0,q0.x,sx); sy=fmaf(e0,q0.y,sy); sz=fmaf(e0,q0.z,sz);
      float4 q1 = *(const float4*)&colq[(cp0+32)*4];
      float e1 = __expf(acc1[reg] - mn);
      se += e1; sx=fmaf(e1,q1.x,sx); sy=fmaf(e1,q1.y,sy); sz=fmaf(e1,q1.z,sz);
    }
    S  = fmaf(S,  sc, se);
    Vx = fmaf(Vx, sc, sx);
    Vy = fmaf(Vy, sc, sy);
    Vz = fmaf(Vz, sc, sz);
    mm = mn;
  }

  {
    float m2  = __shfl_xor(mm, 32);
    float S2  = __shfl_xor(S,  32);
    float Vx2 = __shfl_xor(Vx, 32);
    float Vy2 = __shfl_xor(Vy, 32);
    float Vz2 = __shfl_xor(Vz, 32);
    float M = fmaxf(mm, m2);
    float c1 = __expf(mm - M), c2 = __expf(m2 - M);
    float Sf  = S*c1  + S2*c2;
    float Vxf = Vx*c1 + Vx2*c2;
    float Vyf = Vy*c1 + Vy2*c2;
    float Vzf = Vz*c1 + Vz2*c2;
    if (half==0 && nrow < NN){
      float* p = ws + OFF_PART + ((size_t)(b*NN+nrow)*SPLITS + split)*5;
      p[0]=M; p[1]=Sf; p[2]=Vxf; p[3]=Vyf; p[4]=Vzf;
    }
  }
}

// ---------------- combine partials -> verts12 ----------------
__global__ void k_combine(float* __restrict__ ws) {
  int row = blockIdx.x*blockDim.x + threadIdx.x;
  if (row >= BB*NN) return;
  const float* p = ws + OFF_PART + (size_t)row*SPLITS*5;
  float mm = -INFINITY;
#pragma unroll
  for (int s=0;s<SPLITS;s++) mm = fmaxf(mm, p[s*5]);
  float S=0.f,Vx=0.f,Vy=0.f,Vz=0.f;
#pragma unroll
  for (int s=0;s<SPLITS;s++){
    float sc = expf(p[s*5]-mm);
    S  += p[s*5+1]*sc; Vx += p[s*5+2]*sc; Vy += p[s*5+3]*sc; Vz += p[s*5+4]*sc;
  }
  ws[OFF_V12+(size_t)row*3+0]=Vx/S;
  ws[OFF_V12+(size_t)row*3+1]=Vy/S;
  ws[OFF_V12+(size_t)row*3+2]=Vz/S;
}

// ---------------- self-rec: 4 rows/wave, 16 rows/block ----------------
__global__ __launch_bounds__(256) void k_selfrec(float* __restrict__ ws) {
  int rblk = blockIdx.x, b = blockIdx.y;
  int lane = threadIdx.x & 63, w = threadIdx.x >> 6;
  int r0 = rblk*16 + w*4;
  const float4* v2q = (const float4*)(ws + OFF_V2Q) + (size_t)b*NN;
  const float* v12 = ws + OFF_V12 + (size_t)b*NN*3;
  float xr[4], yr[4], zr[4], sar[4]; bool val[4];
#pragma unroll
  for (int j=0;j<4;j++){
    int n = r0+j; val[j] = (n < NN); int nc = val[j] ? n : NN-1;
    xr[j]=v12[(size_t)nc*3]; yr[j]=v12[(size_t)nc*3+1]; zr[j]=v12[(size_t)nc*3+2];
    sar[j]=xr[j]*xr[j]+yr[j]*yr[j]+zr[j]*zr[j];
  }
  float mn0=INFINITY, mn1=INFINITY, mn2=INFINITY, mn3=INFINITY;
  for (int m=lane; m<NN; m+=64) {
    float4 q = v2q[m];
    mn0 = fminf(mn0, fmaf(-2.0f, xr[0]*q.x + yr[0]*q.y + zr[0]*q.z, sar[0]) + q.w);
    mn1 = fminf(mn1, fmaf(-2.0f, xr[1]*q.x + yr[1]*q.y + zr[1]*q.z, sar[1]) + q.w);
    mn2 = fminf(mn2, fmaf(-2.0f, xr[2]*q.x + yr[2]*q.y + zr[2]*q.z, sar[2]) + q.w);
    mn3 = fminf(mn3, fmaf(-2.0f, xr[3]*q.x + yr[3]*q.y + zr[3]*q.z, sar[3]) + q.w);
  }
  mn0 = wave_min(mn0); mn1 = wave_min(mn1); mn2 = wave_min(mn2); mn3 = wave_min(mn3);
  float s = (val[0]?mn0:0.f) + (val[1]?mn1:0.f) + (val[2]?mn2:0.f) + (val[3]?mn3:0.f);
  if (lane==0)
    atomicAdd(((double*)(ws+OFF_ACC)) + ((rblk*4 + w) & 63), (double)s);
}

// ---------------- top-k via register keys + exact threshold + tiny selection ----------------
// kv = (monotonic-u32(d2) << 13) | idx  (unique; order == (d2, idx) lexicographic == lax.top_k).
// tau = kk-th smallest of the 256 per-thread min kvs. All global top-kk kvs <= tau, and only
// threads with min <= tau (exactly kk of them) contribute candidates -> count <= 20*kk <= 320.
__global__ __launch_bounds__(256) void k_topk(const float* __restrict__ feat1,
        const int* __restrict__ kptr, float* __restrict__ ws) {
  __shared__ unsigned long long red[4];
  __shared__ unsigned long long cand[TKCAND];
  __shared__ int scnt;
  __shared__ int sel[16];
  __shared__ float rs[4];
  int row = blockIdx.x;
  int t = threadIdx.x;
  int lane = t & 63, wid = t >> 6;
  int b = row / NN; int n = row - b*NN;
  int kk = *kptr; if (kk > 16) kk = 16; if (kk < 1) kk = 1;

  const float4* v1q = (const float4*)(ws + OFF_V1Q) + (size_t)b*NN;
  float4 me = v1q[n];
  float x=me.x, y=me.y, z=me.z, sa=me.w;

  if (t==0) scnt = 0;
  unsigned long long kv[20];
  unsigned long long my = ~0ull;
#pragma unroll
  for (int i=0;i<20;i++){
    int m = t + 256*i;
    unsigned long long v = ~0ull;
    if (m < NN){
      float4 q = v1q[m];
      float d2 = fmaf(-2.0f, x*q.x + y*q.y + z*q.z, sa) + q.w;
      unsigned int u = __float_as_uint(d2);
      u = ((int)u < 0) ? ~u : (u ^ 0x80000000u);
      v = ((unsigned long long)u << 13) | (unsigned int)m;
    }
    kv[i] = v;
    my = v < my ? v : my;
  }

  // threshold: kk rounds of block-argmin over per-thread minima (no replacement needed)
  unsigned long long cur = my, tau = ~0ull;
  for (int r=0; r<kk; r++){
    unsigned long long v = cur;
#pragma unroll
    for (int off=32; off; off>>=1){
      unsigned long long o = __shfl_xor(v, off);
      v = o < v ? o : v;
    }
    if (lane==0) red[wid] = v;
    __syncthreads();
    unsigned long long w0 = red[0] < red[1] ? red[0] : red[1];
    unsigned long long w1 = red[2] < red[3] ? red[2] : red[3];
    unsigned long long wmin = w0 < w1 ? w0 : w1;
    tau = wmin;
    if (cur == wmin) cur = ~0ull;
    __syncthreads();
  }

  // compaction: only ~kk threads enter the inner writes
  if (my <= tau){
#pragma unroll
    for (int i=0;i<20;i++){
      if (kv[i] <= tau){
        int pos = atomicAdd(&scnt, 1);
        if (pos < TKCAND) cand[pos] = kv[i];
      }
    }
  }
  __syncthreads();
  int cnt = scnt; if (cnt > TKCAND) cnt = TKCAND;

  // exact selection among <=320 candidates: kk rounds of block-argmin with removal
  unsigned long long c0 = (t < cnt) ? cand[t] : ~0ull;
  unsigned long long c1 = (t+256 < cnt) ? cand[t+256] : ~0ull;
  for (int r=0; r<kk; r++){
    unsigned long long v = c0 < c1 ? c0 : c1;
#pragma unroll
    for (int off=32; off; off>>=1){
      unsigned long long o = __shfl_xor(v, off);
      v = o < v ? o : v;
    }
    if (lane==0) red[wid] = v;
    __syncthreads();
    unsigned long long w0 = red[0] < red[1] ? red[0] : red[1];
    unsigned long long w1 = red[2] < red[3] ? red[2] : red[3];
    unsigned long long wmin = w0 < w1 ? w0 : w1;
    if (t==0) sel[r] = (int)(wmin & 8191ull);
    if (c0 == wmin) c0 = ~0ull;
    if (c1 == wmin) c1 = ~0ull;
    __syncthreads();
  }

  // deform feat MSE over selected neighbors
  int c = t & 127;
  int rh = t >> 7;
  const float* f1n = feat1 + (size_t)row*CC;
  float e = f1n[c];
  float acc = 0.f;
  for (int r=rh; r<kk; r+=2){
    const float* g = feat1 + ((size_t)b*NN + sel[r])*CC;
    float d = g[c]-e;
    acc = fmaf(d,d,acc);
  }
  acc = wave_sum(acc);
  if (lane==0) rs[wid] = acc;
  __syncthreads();
  if (t==0){
    float s = (rs[0]+rs[1])+(rs[2]+rs[3]);
    atomicAdd(((double*)(ws+OFF_ACC)) + 128 + (blockIdx.x & 63), (double)s);
  }
}

// ---------------- proj2img stats ----------------
__global__ void k_imgstats(const float* __restrict__ verts2, const float* __restrict__ imgoff,
                           float* __restrict__ ws) {
  __shared__ float r0[4], r1[4], r2[4], r3[4];
  __shared__ float sgs, smnx, smny;
  int img = blockIdx.x >> 2, b = blockIdx.x & 3;
  const float* pc = (img==0) ? (ws + OFF_V12 + (size_t)b*NN*3) : (verts2 + (size_t)b*NN*3);
  int lane = threadIdx.x & 63, wid = threadIdx.x >> 6;
  float mnx=INFINITY, mxx=-INFINITY, mny=INFINITY, mxy=-INFINITY;
  for (int n = threadIdx.x; n < NN; n += 256) {
    float x = pc[(size_t)n*3], y = pc[(size_t)n*3+1];
    mnx=fminf(mnx,x); mxx=fmaxf(mxx,x); mny=fminf(mny,y); mxy=fmaxf(mxy,y);
  }
#pragma unroll
  for (int off=32; off; off>>=1) {
    mnx=fminf(mnx,__shfl_xor(mnx,off)); mxx=fmaxf(mxx,__shfl_xor(mxx,off));
    mny=fminf(mny,__shfl_xor(mny,off)); mxy=fmaxf(mxy,__shfl_xor(mxy,off));
  }
  if (lane==0){ r0[wid]=mnx; r1[wid]=mxx; r2[wid]=mny; r3[wid]=mxy; }
  __syncthreads();
  float* st = ws + OFF_STATS + (size_t)(img*4+b)*16;
  if (threadIdx.x==0){
    mnx=fminf(fminf(r0[0],r0[1]),fminf(r0[2],r0[3]));
    mxx=fmaxf(fmaxf(r1[0],r1[1]),fmaxf(r1[2],r1[3]));
    mny=fminf(fminf(r2[0],r2[1]),fminf(r2[2],r2[3]));
    mxy=fmaxf(fmaxf(r3[0],r3[1]),fmaxf(r3[2],r3[3]));
    float gs = fmaxf(mxx-mnx, mxy-mny) / 221.0f;
    sgs=gs; smnx=mnx; smny=mny;
    st[0]=mnx; st[1]=mxx; st[2]=mny; st[3]=mxy; st[4]=gs;
  }
  __syncthreads();
  float gs=sgs, bx=smnx, by=smny;
  float fmnx=INFINITY, fmxx=-INFINITY, fmny=INFINITY, fmxy=-INFINITY;
  for (int n = threadIdx.x; n < NN; n += 256) {
    float fx = floorf((pc[(size_t)n*3]-bx)/gs);
    float fy = floorf((pc[(size_t)n*3+1]-by)/gs);
    fmnx=fminf(fmnx,fx); fmxx=fmaxf(fmxx,fx); fmny=fminf(fmny,fy); fmxy=fmaxf(fmxy,fy);
  }
#pragma unroll
  for (int off=32; off; off>>=1) {
    fmnx=fminf(fmnx,__shfl_xor(fmnx,off)); fmxx=fmaxf(fmxx,__shfl_xor(fmxx,off));
    fmny=fminf(fmny,__shfl_xor(fmny,off)); fmxy=fmaxf(fmxy,__shfl_xor(fmxy,off));
  }
  __syncthreads();
  if (lane==0){ r0[wid]=fmnx; r1[wid]=fmxx; r2[wid]=fmny; r3[wid]=fmxy; }
  __syncthreads();
  if (threadIdx.x==0){
    fmnx=fminf(fminf(r0[0],r0[1]),fminf(r0[2],r0[3]));
    fmxx=fmaxf(fmaxf(r1[0],r1[1]),fmaxf(r1[2],r1[3]));
    fmny=fminf(fminf(r2[0],r2[1]),fminf(r2[2],r2[3]));
    fmxy=fmaxf(fmaxf(r3[0],r3[1]),fmaxf(r3[2],r3[3]));
    float omnx=INFINITY, omxx=-INFINITY, omny=INFINITY, omxy=-INFINITY;
    for (int l=0;l<25;l++){
      float ox=imgoff[l*2], oy=imgoff[l*2+1];
      omnx=fminf(omnx,ox); omxx=fmaxf(omxx,ox); omny=fminf(omny,oy); omxy=fmaxf(omxy,oy);
    }
    float cx = floorf(((fmxx+omxx+1.0f)+(fmnx+omnx+1.0f))*0.5f);
    float cy = floorf(((fmxy+omxy+1.0f)+(fmny+omny+1.0f))*0.5f);
    st[5] = (112.0f - cx) - 1.0f;
    st[6] = (112.0f - cy) - 1.0f;
  }
}

// ---------------- scatter z into both images ----------------
__global__ void k_scatter(const float* __restrict__ verts2, const float* __restrict__ imgoff,
                          float* __restrict__ ws) {
  int t = blockIdx.x*blockDim.x + threadIdx.x;
  if (t >= 2*BB*NN) return;
  int img = t / (BB*NN); int r = t - img*(BB*NN); int b = r / NN;
  const float* pc = (img==0) ? (ws + OFF_V12) : verts2;
  float x = pc[(size_t)r*3], y = pc[(size_t)r*3+1], z = pc[(size_t)r*3+2];
  const float* st = ws + OFF_STATS + (size_t)(img*4+b)*16;
  float mnx=st[0], mny=st[2], gs=st[4], offx=st[5], offy=st[6];
  float bx = floorf((x-mnx)/gs) + 1.0f + offx;
  float by = floorf((y-mny)/gs) + 1.0f + offy;
  float* im = ws + (img==0?OFF_IMG1:OFF_IMG2) + (size_t)b*IMGP;
#pragma unroll
  for (int l=0;l<25;l++){
    float vx = bx + imgoff[l*2], vy = by + imgoff[l*2+1];
    vx += (vx<0.f?1.f:0.f) - (vx>223.f?1.f:0.f);
    vy += (vy<0.f?1.f:0.f) - (vy>223.f?1.f:0.f);
    vx = fminf(fmaxf(vx,0.f),223.f); vy = fminf(fmaxf(vy,0.f),223.f);
    int flat = (int)(vx*224.f + vy);
    atomicAdd(im + flat, z);
  }
}

// ---------------- image loss ----------------
__global__ void k_imgloss(float* __restrict__ ws) {
  int i = blockIdx.x*blockDim.x + threadIdx.x;
  float v = 0.f;
  if (i < BB*IMGP) {
    float a = ws[OFF_IMG1+i], c = ws[OFF_IMG2+i];
    float sa = 1.f/(1.f+expf(-a)), sc = 1.f/(1.f+expf(-c));
    float d = sa - sc; v = d*d;
  }
  v = wave_sum(v);
  if ((threadIdx.x&63)==0)
    atomicAdd(((double*)(ws+OFF_ACC)) + 64 + (blockIdx.x & 63), (double)v);
}

// ---------------- finalize ----------------
__global__ void k_final(const int* __restrict__ kptr, const float* __restrict__ ws, float* __restrict__ out) {
  const double* acc = (const double*)(ws+OFF_ACC);
  int kk = *kptr; if (kk > 16) kk = 16; if (kk < 1) kk = 1;
  double a0=0.0, a1=0.0, a2=0.0;
  for (int j=0;j<64;j++){ a0 += acc[j]; a1 += acc[64+j]; a2 += acc[128+j]; }
  double srl = a0 / (double)(BB*NN);
  double img = a1 / ((double)BB*IMGP);
  double df  = a2 / ((double)BB*NN*kk*CC);
  out[0] = (float)(srl + img + df);
}

extern "C" void kernel_launch(void* const* d_in, const int* in_sizes, int n_in,
                              void* d_out, int out_size, void* d_ws, size_t ws_size,
                              hipStream_t stream) {
  (void)in_sizes; (void)n_in; (void)out_size; (void)ws_size;
  const float* verts1 = (const float*)d_in[0];
  const float* verts2 = (const float*)d_in[1];
  const float* feat1  = (const float*)d_in[2];
  const float* feat2  = (const float*)d_in[3];
  const float* imgoff = (const float*)d_in[4];
  const int*   kptr   = (const int*)d_in[5];
  float* ws  = (float*)d_ws;
  float* out = (float*)d_out;

  hipMemsetAsync(ws + ZERO_START, 0, (size_t)ZERO_FLOATS*sizeof(float), stream);

  k_norms<<<(BB*NN+255)/256, 256, 0, stream>>>(verts1, verts2, feat1, feat2, ws);

  dim3 gC(NG, BB);
  k_conv<<<gC, 256, 0, stream>>>(feat2, ws);

  dim3 gA(RBLK, SPLITS, BB);
  k_stageA<<<gA, 256, 0, stream>>>(feat1, ws);
  k_combine<<<(BB*NN+255)/256, 256, 0, stream>>>(ws);

  dim3 gS((NN+15)/16, BB);
  k_selfrec<<<gS, 256, 0, stream>>>(ws);
  k_topk<<<BB*NN, 256, 0, stream>>>(feat1, kptr, ws);

  k_imgstats<<<8, 256, 0, stream>>>(verts2, imgoff, ws);
  k_scatter<<<(2*BB*NN+255)/256, 256, 0, stream>>>(verts2, imgoff, ws);
  k_imgloss<<<(BB*IMGP+255)/256, 256, 0, stream>>>(ws);

  k_final<<<1,1,0,stream>>>(kptr, ws, out);
}

// Round 7
// 655.780 us; speedup vs baseline: 3.0332x; 1.0866x over previous
//
#include <hip/hip_runtime.h>
#include <math.h>

#define BB 4
#define NN 4995
#define CC 128
#define IMG 224
#define IMGP (IMG*IMG)
#define ALPHA_F 100.0f
#define SPLITS 8
#define COLS_PER_SPLIT 640   // 32-aligned; 8*640=5120 >= 4995
#define RBLK 40              // ceil(4995/128)
#define NG 158               // col groups of 32 (incl. 1 pad group)
#define TKCAND 512

// ws layout in float units
#define OFF_V12    0            // 59940
#define OFF_FN1    60000        // 19980
#define OFF_V1Q    81000        // 79920 {x,y,z,|v1|^2}
#define OFF_V2Q    161000       // 79920 {x,y,z,|v2|^2}
#define OFF_C2Q    241000       // 79920 {x,y,z,|f2|^2}
#define OFF_PART   321000       // 19980*8*5 = 799200 -> ends 1120200
#define OFF_IMG1   1121000      // 200704
#define OFF_IMG2   1321704      // 200704 -> ends 1522408
#define OFF_ACC    1522408      // 3*64 f64 = 384 floats (byte 6089632, 8-aligned)
#define OFF_STATS  1522792      // 128 -> ends 1522920
#define OFF_F2H    1523000      // 4*158*4096 shorts = 1294336 floats
#define OFF_F2L    2818000      // 1294336 floats -> ends 4112336 (16.45MB)
#define ZERO_START OFF_IMG1
#define ZERO_FLOATS (1522920 - OFF_IMG1)

typedef short v8s  __attribute__((ext_vector_type(8)));
typedef float v16f __attribute__((ext_vector_type(16)));

__device__ __forceinline__ float wave_min(float v){
#pragma unroll
  for (int off=32; off; off>>=1) v = fminf(v, __shfl_xor(v, off));
  return v;
}
__device__ __forceinline__ float wave_sum(float v){
#pragma unroll
  for (int off=32; off; off>>=1) v += __shfl_xor(v, off);
  return v;
}

// pack top-16 bits (bf16 truncation) of two floats: (hi16(b)<<16)|hi16(a)
__device__ __forceinline__ int pack_bf_hi(float a, float b){
  return (int)__builtin_amdgcn_perm(__float_as_uint(b), __float_as_uint(a), 0x07060302u);
}

// ---------------- norms + packed quads ----------------
__global__ void k_norms(const float* __restrict__ verts1, const float* __restrict__ verts2,
                        const float* __restrict__ feat1, const float* __restrict__ feat2,
                        float* __restrict__ ws) {
  int i = blockIdx.x*blockDim.x + threadIdx.x;
  if (i >= BB*NN) return;
  float x=verts1[(size_t)i*3], y=verts1[(size_t)i*3+1], z=verts1[(size_t)i*3+2];
  ((float4*)(ws+OFF_V1Q))[i] = make_float4(x,y,z, x*x+y*y+z*z);
  float x2=verts2[(size_t)i*3], y2=verts2[(size_t)i*3+1], z2=verts2[(size_t)i*3+2];
  ((float4*)(ws+OFF_V2Q))[i] = make_float4(x2,y2,z2, x2*x2+y2*y2+z2*z2);
  {
    const float4* f = (const float4*)(feat2 + (size_t)i*CC);
    float s0=0.f,s1=0.f,s2=0.f,s3=0.f;
#pragma unroll
    for (int k=0;k<CC/4;k++){ float4 t=f[k];
      s0=fmaf(t.x,t.x,s0); s1=fmaf(t.y,t.y,s1); s2=fmaf(t.z,t.z,s2); s3=fmaf(t.w,t.w,s3); }
    ((float4*)(ws+OFF_C2Q))[i] = make_float4(x2,y2,z2, (s0+s1)+(s2+s3));
  }
  {
    const float4* f = (const float4*)(feat1 + (size_t)i*CC);
    float s0=0.f,s1=0.f,s2=0.f,s3=0.f;
#pragma unroll
    for (int k=0;k<CC/4;k++){ float4 t=f[k];
      s0=fmaf(t.x,t.x,s0); s1=fmaf(t.y,t.y,s1); s2=fmaf(t.z,t.z,s2); s3=fmaf(t.w,t.w,s3); }
    ws[OFF_FN1+i] = (s0+s1)+(s2+s3);
  }
}

// ---------------- pre-convert feat2 -> tiled bf16 hi/lo ----------------
// layout [b][g][kt4][kh2][half2][c32][j8], strides (shorts): j=1,c32=8,half=256,kh=512,kt=1024,g=4096
__global__ __launch_bounds__(256) void k_conv(const float* __restrict__ feat2, float* __restrict__ ws) {
  int g = blockIdx.x, b = blockIdx.y;
  int t = threadIdx.x;
  int q = t >> 5, c32 = t & 31;
  int col = g*32 + c32; if (col > NN-1) col = NN-1;
  const float4* src = (const float4*)(feat2 + ((size_t)(b*NN + col))*CC) + q*4;
  float4 v0 = src[0], v1 = src[1], v2 = src[2], v3 = src[3];
  short* f2h = (short*)(ws + OFF_F2H);
  short* f2l = (short*)(ws + OFF_F2L);
  size_t base = ((size_t)(b*NG + g))*4096 + (size_t)q*512 + c32*8;
#pragma unroll
  for (int h=0; h<2; h++){
    float4 a = h ? v2 : v0;
    float4 c = h ? v3 : v1;
    float hx=__uint_as_float(__float_as_uint(a.x)&0xffff0000u);
    float hy=__uint_as_float(__float_as_uint(a.y)&0xffff0000u);
    float hz=__uint_as_float(__float_as_uint(a.z)&0xffff0000u);
    float hw=__uint_as_float(__float_as_uint(a.w)&0xffff0000u);
    float gx=__uint_as_float(__float_as_uint(c.x)&0xffff0000u);
    float gy=__uint_as_float(__float_as_uint(c.y)&0xffff0000u);
    float gz=__uint_as_float(__float_as_uint(c.z)&0xffff0000u);
    float gw=__uint_as_float(__float_as_uint(c.w)&0xffff0000u);
    int4 hi = make_int4(pack_bf_hi(a.x,a.y), pack_bf_hi(a.z,a.w),
                        pack_bf_hi(c.x,c.y), pack_bf_hi(c.z,c.w));
    int4 lo = make_int4(pack_bf_hi(a.x-hx,a.y-hy), pack_bf_hi(a.z-hz,a.w-hw),
                        pack_bf_hi(c.x-gx,c.y-gy), pack_bf_hi(c.z-gz,c.w-gw));
    *(int4*)&f2h[base + h*256] = hi;
    *(int4*)&f2l[base + h*256] = lo;
  }
}

// ---------------- stage A: swapped-operand MFMA GEMM + in-lane online softmax ----------------
__global__ __launch_bounds__(256) void k_stageA(const float* __restrict__ feat1,
      float* __restrict__ ws) {
  __shared__ __align__(16) short Ah[4096], Al[4096];   // feat1: [gg4][kh2][half2][r32][j8]
  __shared__ __align__(16) short Bh[2048], Bl[2048];   // feat2: [cg2][kh2][half2][c32][j8]
  __shared__ __align__(16) float colq[64*4];           // {x,y,z,fn2} per col

  int rblk  = blockIdx.x;
  int split = blockIdx.y;
  int b     = blockIdx.z;
  int rowBase = rblk*128;
  int colBase = split*COLS_PER_SPLIT;
  int colEnd  = colBase + COLS_PER_SPLIT; if (colEnd > NN) colEnd = NN;
  int nct = (colEnd - colBase + 63) >> 6;

  int t    = threadIdx.x;
  int w    = t >> 6;
  int lane = t & 63;
  int half = lane >> 5;
  int m32  = lane & 31;

  const float* f1b = feat1 + (size_t)b*NN*CC;
  const short* f2h = (const short*)(ws + OFF_F2H);
  const short* f2l = (const short*)(ws + OFF_F2L);
  const float4* c2q = (const float4*)(ws + OFF_C2Q) + (size_t)b*NN;

  int nrow = rowBase + w*32 + m32;
  int nclamp = nrow > NN-1 ? NN-1 : nrow;
  float sn = ws[OFF_FN1 + (size_t)b*NN + nclamp];

  int sr = t >> 1, skh = t & 1;
  int srow = rowBase + sr; if (srow > NN-1) srow = NN-1;
  int sgg = sr >> 5, sr32 = sr & 31;
  const float4* aSrcBase = (const float4*)(f1b + (size_t)srow*CC);
  size_t aDst = (size_t)sgg*1024 + (size_t)skh*512 + sr32*8;

  int scg = t >> 7;
  size_t bDstOff = (size_t)scg*1024 + (t & 127)*8;

  float mm = -INFINITY, S = 0.f, Vx = 0.f, Vy = 0.f, Vz = 0.f;

  for (int ci = 0; ci < nct; ci++){
    int ctBase = colBase + ci*64;
    int g0 = ctBase >> 5;
    __syncthreads();
    if (t < 64){
      int c = ctBase + t; if (c > NN-1) c = NN-1;
      *(float4*)&colq[t*4] = c2q[c];
    }
    v16f acc0, acc1;
#pragma unroll
    for (int i=0;i<16;i++){ acc0[i]=0.f; acc1[i]=0.f; }

#pragma unroll 1
    for (int kt = 0; kt < 4; kt++){
      __syncthreads();
      {
        size_t gsrc = ((size_t)(b*NG + g0 + scg))*4096 + (size_t)kt*1024 + (t & 127)*8;
        int4 vh = *(const int4*)&f2h[gsrc];
        int4 vl = *(const int4*)&f2l[gsrc];
        *(int4*)&Bh[bDstOff] = vh;
        *(int4*)&Bl[bDstOff] = vl;
      }
      {
        const float4* s4 = aSrcBase + kt*8 + skh*4;
        float4 v0=s4[0], v1=s4[1], v2=s4[2], v3=s4[3];
#pragma unroll
        for (int h=0; h<2; h++){
          float4 a = h ? v2 : v0;
          float4 c = h ? v3 : v1;
          float hx=__uint_as_float(__float_as_uint(a.x)&0xffff0000u);
          float hy=__uint_as_float(__float_as_uint(a.y)&0xffff0000u);
          float hz=__uint_as_float(__float_as_uint(a.z)&0xffff0000u);
          float hw=__uint_as_float(__float_as_uint(a.w)&0xffff0000u);
          float gx=__uint_as_float(__float_as_uint(c.x)&0xffff0000u);
          float gy=__uint_as_float(__float_as_uint(c.y)&0xffff0000u);
          float gz=__uint_as_float(__float_as_uint(c.z)&0xffff0000u);
          float gw=__uint_as_float(__float_as_uint(c.w)&0xffff0000u);
          int4 hi = make_int4(pack_bf_hi(a.x,a.y), pack_bf_hi(a.z,a.w),
                              pack_bf_hi(c.x,c.y), pack_bf_hi(c.z,c.w));
          int4 lo = make_int4(pack_bf_hi(a.x-hx,a.y-hy), pack_bf_hi(a.z-hz,a.w-hw),
                              pack_bf_hi(c.x-gx,c.y-gy), pack_bf_hi(c.z-gz,c.w-gw));
          *(int4*)&Ah[aDst + h*256] = hi;
          *(int4*)&Al[aDst + h*256] = lo;
        }
      }
      __syncthreads();
#pragma unroll
      for (int kh=0; kh<2; kh++){
        size_t fo = (size_t)kh*512 + (size_t)half*256 + m32*8;
        v8s b1h = *(const v8s*)&Ah[(size_t)w*1024 + fo];
        v8s b1l = *(const v8s*)&Al[(size_t)w*1024 + fo];
        v8s a0h = *(const v8s*)&Bh[fo];
        v8s a0l = *(const v8s*)&Bl[fo];
        v8s a1h = *(const v8s*)&Bh[1024 + fo];
        v8s a1l = *(const v8s*)&Bl[1024 + fo];
        acc0 = __builtin_amdgcn_mfma_f32_32x32x16_bf16(a0h, b1h, acc0, 0,0,0);
        acc0 = __builtin_amdgcn_mfma_f32_32x32x16_bf16(a0h, b1l, acc0, 0,0,0);
        acc0 = __builtin_amdgcn_mfma_f32_32x32x16_bf16(a0l, b1h, acc0, 0,0,0);
        acc1 = __builtin_amdgcn_mfma_f32_32x32x16_bf16(a1h, b1h, acc1, 0,0,0);
        acc1 = __builtin_amdgcn_mfma_f32_32x32x16_bf16(a1h, b1l, acc1, 0,0,0);
        acc1 = __builtin_amdgcn_mfma_f32_32x32x16_bf16(a1l, b1h, acc1, 0,0,0);
      }
    }

    float Mt = -INFINITY;
#pragma unroll
    for (int reg=0; reg<16; reg++){
      int cp0 = (reg&3) + 8*(reg>>2) + 4*half;
      float f0 = colq[cp0*4+3];
      float d0 = fmaf(-2.f, acc0[reg], sn) + f0;
      float l0 = (ctBase+cp0 < colEnd) ? (-ALPHA_F*sqrtf(fmaxf(d0,1e-12f))) : -INFINITY;
      acc0[reg] = l0; Mt = fmaxf(Mt, l0);
      int cp1 = cp0 + 32;
      float f1v = colq[cp1*4+3];
      float d1 = fmaf(-2.f, acc1[reg], sn) + f1v;
      float l1 = (ctBase+cp1 < colEnd) ? (-ALPHA_F*sqrtf(fmaxf(d1,1e-12f))) : -INFINITY;
      acc1[reg] = l1; Mt = fmaxf(Mt, l1);
    }
    float mn = fmaxf(mm, Mt);
    float sc = __expf(mm - mn);
    float se=0.f, sx=0.f, sy=0.f, sz=0.f;
#pragma unroll
    for (int reg=0; reg<16; reg++){
      int cp0 = (reg&3) + 8*(reg>>2) + 4*half;
      float4 q0 = *(const float4*)&colq[cp0*4];
      float e0 = __expf(acc0[reg] - mn);
      se += e0; sx=fmaf(e0,q0.x,sx); sy=fmaf(e0,q0.y,sy); sz=fmaf(e0,q0.z,sz);
      float4 q1 = *(const float4*)&colq[(cp0+32)*4];
      float e1 = __expf(acc1[reg] - mn);
      se += e1; sx=fmaf(e1,q1.x,sx); sy=fmaf(e1,q1.y,sy); sz=fmaf(e1,q1.z,sz);
    }
    S  = fmaf(S,  sc, se);
    Vx = fmaf(Vx, sc, sx);
    Vy = fmaf(Vy, sc, sy);
    Vz = fmaf(Vz, sc, sz);
    mm = mn;
  }

  {
    float m2  = __shfl_xor(mm, 32);
    float S2  = __shfl_xor(S,  32);
    float Vx2 = __shfl_xor(Vx, 32);
    float Vy2 = __shfl_xor(Vy, 32);
    float Vz2 = __shfl_xor(Vz, 32);
    float M = fmaxf(mm, m2);
    float c1 = __expf(mm - M), c2 = __expf(m2 - M);
    float Sf  = S*c1  + S2*c2;
    float Vxf = Vx*c1 + Vx2*c2;
    float Vyf = Vy*c1 + Vy2*c2;
    float Vzf = Vz*c1 + Vz2*c2;
    if (half==0 && nrow < NN){
      float* p = ws + OFF_PART + ((size_t)(b*NN+nrow)*SPLITS + split)*5;
      p[0]=M; p[1]=Sf; p[2]=Vxf; p[3]=Vyf; p[4]=Vzf;
    }
  }
}

// ---------------- combine partials -> verts12 ----------------
__global__ void k_combine(float* __restrict__ ws) {
  int row = blockIdx.x*blockDim.x + threadIdx.x;
  if (row >= BB*NN) return;
  const float* p = ws + OFF_PART + (size_t)row*SPLITS*5;
  float mm = -INFINITY;
#pragma unroll
  for (int s=0;s<SPLITS;s++) mm = fmaxf(mm, p[s*5]);
  float S=0.f,Vx=0.f,Vy=0.f,Vz=0.f;
#pragma unroll
  for (int s=0;s<SPLITS;s++){
    float sc = expf(p[s*5]-mm);
    S  += p[s*5+1]*sc; Vx += p[s*5+2]*sc; Vy += p[s*5+3]*sc; Vz += p[s*5+4]*sc;
  }
  ws[OFF_V12+(size_t)row*3+0]=Vx/S;
  ws[OFF_V12+(size_t)row*3+1]=Vy/S;
  ws[OFF_V12+(size_t)row*3+2]=Vz/S;
}

// ---------------- self-rec: 4 rows/wave, 16 rows/block ----------------
__global__ __launch_bounds__(256) void k_selfrec(float* __restrict__ ws) {
  int rblk = blockIdx.x, b = blockIdx.y;
  int lane = threadIdx.x & 63, w = threadIdx.x >> 6;
  int r0 = rblk*16 + w*4;
  const float4* v2q = (const float4*)(ws + OFF_V2Q) + (size_t)b*NN;
  const float* v12 = ws + OFF_V12 + (size_t)b*NN*3;
  float xr[4], yr[4], zr[4], sar[4]; bool val[4];
#pragma unroll
  for (int j=0;j<4;j++){
    int n = r0+j; val[j] = (n < NN); int nc = val[j] ? n : NN-1;
    xr[j]=v12[(size_t)nc*3]; yr[j]=v12[(size_t)nc*3+1]; zr[j]=v12[(size_t)nc*3+2];
    sar[j]=xr[j]*xr[j]+yr[j]*yr[j]+zr[j]*zr[j];
  }
  float mn0=INFINITY, mn1=INFINITY, mn2=INFINITY, mn3=INFINITY;
  for (int m=lane; m<NN; m+=64) {
    float4 q = v2q[m];
    mn0 = fminf(mn0, fmaf(-2.0f, xr[0]*q.x + yr[0]*q.y + zr[0]*q.z, sar[0]) + q.w);
    mn1 = fminf(mn1, fmaf(-2.0f, xr[1]*q.x + yr[1]*q.y + zr[1]*q.z, sar[1]) + q.w);
    mn2 = fminf(mn2, fmaf(-2.0f, xr[2]*q.x + yr[2]*q.y + zr[2]*q.z, sar[2]) + q.w);
    mn3 = fminf(mn3, fmaf(-2.0f, xr[3]*q.x + yr[3]*q.y + zr[3]*q.z, sar[3]) + q.w);
  }
  mn0 = wave_min(mn0); mn1 = wave_min(mn1); mn2 = wave_min(mn2); mn3 = wave_min(mn3);
  float s = (val[0]?mn0:0.f) + (val[1]?mn1:0.f) + (val[2]?mn2:0.f) + (val[3]?mn3:0.f);
  if (lane==0)
    atomicAdd(((double*)(ws+OFF_ACC)) + ((rblk*4 + w) & 63), (double)s);
}

// ---------------- top-k: spill-free threshold + recompute compaction + tiny selection ----------------
// Phase 1: per-thread min 32-bit monotonic key only (no candidate array -> no spill).
// tau: per-wave kk-th smallest of 64 thread-min-keys (kk rounds of intra-wave u32 min, no barriers),
//      then min over the 4 waves. Guarantees >= kk candidate keys <= tau (see proof in journal).
// Compaction: threads with minkey <= tau RECOMPUTE their 20 d2s, push kv=(key<<13)|idx if key <= tau.
// Selection: exact (key,idx) order over <=512 candidates, kk rounds of block-argmin with removal.
__global__ __launch_bounds__(256) void k_topk(const float* __restrict__ feat1,
        const int* __restrict__ kptr, float* __restrict__ ws) {
  __shared__ unsigned long long red[4];
  __shared__ unsigned long long cand[TKCAND];
  __shared__ unsigned int wtau[4];
  __shared__ int scnt;
  __shared__ int sel[16];
  __shared__ float rs[4];
  int row = blockIdx.x;
  int t = threadIdx.x;
  int lane = t & 63, wid = t >> 6;
  int b = row / NN; int n = row - b*NN;
  int kk = *kptr; if (kk > 16) kk = 16; if (kk < 1) kk = 1;

  const float4* v1q = (const float4*)(ws + OFF_V1Q) + (size_t)b*NN;
  float4 me = v1q[n];
  float x=me.x, y=me.y, z=me.z, sa=me.w;

  if (t==0) scnt = 0;

  // phase 1: per-thread min key
  unsigned int mykey = 0xFFFFFFFFu;
#pragma unroll
  for (int i=0;i<20;i++){
    int m = t + 256*i;
    if (m < NN){
      float4 q = v1q[m];
      float d2 = fmaf(-2.0f, x*q.x + y*q.y + z*q.z, sa) + q.w;
      unsigned int u = __float_as_uint(d2);
      u = ((int)u < 0) ? ~u : (u ^ 0x80000000u);
      mykey = u < mykey ? u : mykey;
    }
  }

  // per-wave kk-th smallest (with removal; duplicate removal only shrinks tau -> still safe)
  {
    unsigned int cur = mykey, tw = 0xFFFFFFFFu;
    for (int r=0; r<kk; r++){
      unsigned int v = cur;
#pragma unroll
      for (int off=32; off; off>>=1){
        unsigned int o = __shfl_xor(v, off);
        v = o < v ? o : v;
      }
      tw = v;
      if (cur == v) cur = 0xFFFFFFFFu;
    }
    if (lane==0) wtau[wid] = tw;
  }
  __syncthreads();
  unsigned int tau;
  {
    unsigned int t0 = wtau[0] < wtau[1] ? wtau[0] : wtau[1];
    unsigned int t1 = wtau[2] < wtau[3] ? wtau[2] : wtau[3];
    tau = t0 < t1 ? t0 : t1;
  }

  // compaction: recompute candidates only on passing threads (~kk of 256)
  if (mykey <= tau){
#pragma unroll
    for (int i=0;i<20;i++){
      int m = t + 256*i;
      if (m < NN){
        float4 q = v1q[m];
        float d2 = fmaf(-2.0f, x*q.x + y*q.y + z*q.z, sa) + q.w;
        unsigned int u = __float_as_uint(d2);
        u = ((int)u < 0) ? ~u : (u ^ 0x80000000u);
        if (u <= tau){
          int pos = atomicAdd(&scnt, 1);
          if (pos < TKCAND)
            cand[pos] = ((unsigned long long)u << 13) | (unsigned int)m;
        }
      }
    }
  }
  __syncthreads();
  int cnt = scnt; if (cnt > TKCAND) cnt = TKCAND;

  // exact selection among candidates: kk rounds of block-argmin with removal
  unsigned long long c0 = (t < cnt) ? cand[t] : ~0ull;
  unsigned long long c1 = (t+256 < cnt) ? cand[t+256] : ~0ull;
  for (int r=0; r<kk; r++){
    unsigned long long v = c0 < c1 ? c0 : c1;
#pragma unroll
    for (int off=32; off; off>>=1){
      unsigned long long o = __shfl_xor(v, off);
      v = o < v ? o : v;
    }
    if (lane==0) red[wid] = v;
    __syncthreads();
    unsigned long long w0 = red[0] < red[1] ? red[0] : red[1];
    unsigned long long w1 = red[2] < red[3] ? red[2] : red[3];
    unsigned long long wmin = w0 < w1 ? w0 : w1;
    if (t==0) sel[r] = (int)(wmin & 8191ull);
    if (c0 == wmin) c0 = ~0ull;
    if (c1 == wmin) c1 = ~0ull;
    __syncthreads();
  }

  // deform feat MSE over selected neighbors
  int c = t & 127;
  int rh = t >> 7;
  const float* f1n = feat1 + (size_t)row*CC;
  float e = f1n[c];
  float acc = 0.f;
  for (int r=rh; r<kk; r+=2){
    const float* g = feat1 + ((size_t)b*NN + sel[r])*CC;
    float d = g[c]-e;
    acc = fmaf(d,d,acc);
  }
  acc = wave_sum(acc);
  if (lane==0) rs[wid] = acc;
  __syncthreads();
  if (t==0){
    float s = (rs[0]+rs[1])+(rs[2]+rs[3]);
    atomicAdd(((double*)(ws+OFF_ACC)) + 128 + (blockIdx.x & 63), (double)s);
  }
}

// ---------------- proj2img stats ----------------
__global__ void k_imgstats(const float* __restrict__ verts2, const float* __restrict__ imgoff,
                           float* __restrict__ ws) {
  __shared__ float r0[4], r1[4], r2[4], r3[4];
  __shared__ float sgs, smnx, smny;
  int img = blockIdx.x >> 2, b = blockIdx.x & 3;
  const float* pc = (img==0) ? (ws + OFF_V12 + (size_t)b*NN*3) : (verts2 + (size_t)b*NN*3);
  int lane = threadIdx.x & 63, wid = threadIdx.x >> 6;
  float mnx=INFINITY, mxx=-INFINITY, mny=INFINITY, mxy=-INFINITY;
  for (int n = threadIdx.x; n < NN; n += 256) {
    float x = pc[(size_t)n*3], y = pc[(size_t)n*3+1];
    mnx=fminf(mnx,x); mxx=fmaxf(mxx,x); mny=fminf(mny,y); mxy=fmaxf(mxy,y);
  }
#pragma unroll
  for (int off=32; off; off>>=1) {
    mnx=fminf(mnx,__shfl_xor(mnx,off)); mxx=fmaxf(mxx,__shfl_xor(mxx,off));
    mny=fminf(mny,__shfl_xor(mny,off)); mxy=fmaxf(mxy,__shfl_xor(mxy,off));
  }
  if (lane==0){ r0[wid]=mnx; r1[wid]=mxx; r2[wid]=mny; r3[wid]=mxy; }
  __syncthreads();
  float* st = ws + OFF_STATS + (size_t)(img*4+b)*16;
  if (threadIdx.x==0){
    mnx=fminf(fminf(r0[0],r0[1]),fminf(r0[2],r0[3]));
    mxx=fmaxf(fmaxf(r1[0],r1[1]),fmaxf(r1[2],r1[3]));
    mny=fminf(fminf(r2[0],r2[1]),fminf(r2[2],r2[3]));
    mxy=fmaxf(fmaxf(r3[0],r3[1]),fmaxf(r3[2],r3[3]));
    float gs = fmaxf(mxx-mnx, mxy-mny) / 221.0f;
    sgs=gs; smnx=mnx; smny=mny;
    st[0]=mnx; st[1]=mxx; st[2]=mny; st[3]=mxy; st[4]=gs;
  }
  __syncthreads();
  float gs=sgs, bx=smnx, by=smny;
  float fmnx=INFINITY, fmxx=-INFINITY, fmny=INFINITY, fmxy=-INFINITY;
  for (int n = threadIdx.x; n < NN; n += 256) {
    float fx = floorf((pc[(size_t)n*3]-bx)/gs);
    float fy = floorf((pc[(size_t)n*3+1]-by)/gs);
    fmnx=fminf(fmnx,fx); fmxx=fmaxf(fmxx,fx); fmny=fminf(fmny,fy); fmxy=fmaxf(fmxy,fy);
  }
#pragma unroll
  for (int off=32; off; off>>=1) {
    fmnx=fminf(fmnx,__shfl_xor(fmnx,off)); fmxx=fmaxf(fmxx,__shfl_xor(fmxx,off));
    fmny=fminf(fmny,__shfl_xor(fmny,off)); fmxy=fmaxf(fmxy,__shfl_xor(fmxy,off));
  }
  __syncthreads();
  if (lane==0){ r0[wid]=fmnx; r1[wid]=fmxx; r2[wid]=fmny; r3[wid]=fmxy; }
  __syncthreads();
  if (threadIdx.x==0){
    fmnx=fminf(fminf(r0[0],r0[1]),fminf(r0[2],r0[3]));
    fmxx=fmaxf(fmaxf(r1[0],r1[1]),fmaxf(r1[2],r1[3]));
    fmny=fminf(fminf(r2[0],r2[1]),fminf(r2[2],r2[3]));
    fmxy=fmaxf(fmaxf(r3[0],r3[1]),fmaxf(r3[2],r3[3]));
    float omnx=INFINITY, omxx=-INFINITY, omny=INFINITY, omxy=-INFINITY;
    for (int l=0;l<25;l++){
      float ox=imgoff[l*2], oy=imgoff[l*2+1];
      omnx=fminf(omnx,ox); omxx=fmaxf(omxx,ox); omny=fminf(omny,oy); omxy=fmaxf(omxy,oy);
    }
    float cx = floorf(((fmxx+omxx+1.0f)+(fmnx+omnx+1.0f))*0.5f);
    float cy = floorf(((fmxy+omxy+1.0f)+(fmny+omny+1.0f))*0.5f);
    st[5] = (112.0f - cx) - 1.0f;
    st[6] = (112.0f - cy) - 1.0f;
  }
}

// ---------------- scatter z into both images ----------------
__global__ void k_scatter(const float* __restrict__ verts2, const float* __restrict__ imgoff,
                          float* __restrict__ ws) {
  int t = blockIdx.x*blockDim.x + threadIdx.x;
  if (t >= 2*BB*NN) return;
  int img = t / (BB*NN); int r = t - img*(BB*NN); int b = r / NN;
  const float* pc = (img==0) ? (ws + OFF_V12) : verts2;
  float x = pc[(size_t)r*3], y = pc[(size_t)r*3+1], z = pc[(size_t)r*3+2];
  const float* st = ws + OFF_STATS + (size_t)(img*4+b)*16;
  float mnx=st[0], mny=st[2], gs=st[4], offx=st[5], offy=st[6];
  float bx = floorf((x-mnx)/gs) + 1.0f + offx;
  float by = floorf((y-mny)/gs) + 1.0f + offy;
  float* im = ws + (img==0?OFF_IMG1:OFF_IMG2) + (size_t)b*IMGP;
#pragma unroll
  for (int l=0;l<25;l++){
    float vx = bx + imgoff[l*2], vy = by + imgoff[l*2+1];
    vx += (vx<0.f?1.f:0.f) - (vx>223.f?1.f:0.f);
    vy += (vy<0.f?1.f:0.f) - (vy>223.f?1.f:0.f);
    vx = fminf(fmaxf(vx,0.f),223.f); vy = fminf(fmaxf(vy,0.f),223.f);
    int flat = (int)(vx*224.f + vy);
    atomicAdd(im + flat, z);
  }
}

// ---------------- image loss ----------------
__global__ void k_imgloss(float* __restrict__ ws) {
  int i = blockIdx.x*blockDim.x + threadIdx.x;
  float v = 0.f;
  if (i < BB*IMGP) {
    float a = ws[OFF_IMG1+i], c = ws[OFF_IMG2+i];
    float sa = 1.f/(1.f+expf(-a)), sc = 1.f/(1.f+expf(-c));
    float d = sa - sc; v = d*d;
  }
  v = wave_sum(v);
  if ((threadIdx.x&63)==0)
    atomicAdd(((double*)(ws+OFF_ACC)) + 64 + (blockIdx.x & 63), (double)v);
}

// ---------------- finalize ----------------
__global__ void k_final(const int* __restrict__ kptr, const float* __restrict__ ws, float* __restrict__ out) {
  const double* acc = (const double*)(ws+OFF_ACC);
  int kk = *kptr; if (kk > 16) kk = 16; if (kk < 1) kk = 1;
  double a0=0.0, a1=0.0, a2=0.0;
  for (int j=0;j<64;j++){ a0 += acc[j]; a1 += acc[64+j]; a2 += acc[128+j]; }
  double srl = a0 / (double)(BB*NN);
  double img = a1 / ((double)BB*IMGP);
  double df  = a2 / ((double)BB*NN*kk*CC);
  out[0] = (float)(srl + img + df);
}

extern "C" void kernel_launch(void* const* d_in, const int* in_sizes, int n_in,
                              void* d_out, int out_size, void* d_ws, size_t ws_size,
                              hipStream_t stream) {
  (void)in_sizes; (void)n_in; (void)out_size; (void)ws_size;
  const float* verts1 = (const float*)d_in[0];
  const float* verts2 = (const float*)d_in[1];
  const float* feat1  = (const float*)d_in[2];
  const float* feat2  = (const float*)d_in[3];
  const float* imgoff = (const float*)d_in[4];
  const int*   kptr   = (const int*)d_in[5];
  float* ws  = (float*)d_ws;
  float* out = (float*)d_out;

  hipMemsetAsync(ws + ZERO_START, 0, (size_t)ZERO_FLOATS*sizeof(float), stream);

  k_norms<<<(BB*NN+255)/256, 256, 0, stream>>>(verts1, verts2, feat1, feat2, ws);

  dim3 gC(NG, BB);
  k_conv<<<gC, 256, 0, stream>>>(feat2, ws);

  dim3 gA(RBLK, SPLITS, BB);
  k_stageA<<<gA, 256, 0, stream>>>(feat1, ws);
  k_combine<<<(BB*NN+255)/256, 256, 0, stream>>>(ws);

  dim3 gS((NN+15)/16, BB);
  k_selfrec<<<gS, 256, 0, stream>>>(ws);
  k_topk<<<BB*NN, 256, 0, stream>>>(feat1, kptr, ws);

  k_imgstats<<<8, 256, 0, stream>>>(verts2, imgoff, ws);
  k_scatter<<<(2*BB*NN+255)/256, 256, 0, stream>>>(verts2, imgoff, ws);
  k_imgloss<<<(BB*IMGP+255)/256, 256, 0, stream>>>(ws);

  k_final<<<1,1,0,stream>>>(kptr, ws, out);
}

// Round 8
// 620.414 us; speedup vs baseline: 3.2061x; 1.0570x over previous
//
#include <hip/hip_runtime.h>
#include <math.h>

#define BB 4
#define NN 4995
#define CC 128
#define IMG 224
#define IMGP (IMG*IMG)
#define ALPHA_F 100.0f
#define SPLITS 8
#define COLS_PER_SPLIT 640   // 32-aligned; 8*640=5120 >= 4995
#define RBLK 40              // ceil(4995/128)
#define NG 158               // col groups of 32 (incl. 1 pad group)
#define TKCAND 512

// ws layout in float units
#define OFF_V12    0            // 59940
#define OFF_FN1    60000        // 19980
#define OFF_V1Q    81000        // 79920 {x,y,z,|v1|^2}
#define OFF_V2Q    161000       // 79920 {x,y,z,|v2|^2}
#define OFF_C2Q    241000       // 79920 {x,y,z,|f2|^2}
#define OFF_PART   321000       // 19980*8*5 = 799200 -> ends 1120200
#define OFF_IMG1   1121000      // 200704
#define OFF_IMG2   1321704      // 200704 -> ends 1522408
#define OFF_ACC    1522408      // 3*64 f64 = 384 floats (byte 6089632, 8-aligned)
#define OFF_STATS  1522792      // 128 -> ends 1522920
#define OFF_F2H    1523000      // 4*158*4096 shorts = 1294336 floats
#define OFF_F2L    2818000      // 1294336 floats -> ends 4112336 (16.45MB)
#define ZERO_START OFF_IMG1
#define ZERO_FLOATS (1522920 - OFF_IMG1)

typedef short v8s  __attribute__((ext_vector_type(8)));
typedef float v16f __attribute__((ext_vector_type(16)));

__device__ __forceinline__ float wave_min(float v){
#pragma unroll
  for (int off=32; off; off>>=1) v = fminf(v, __shfl_xor(v, off));
  return v;
}
__device__ __forceinline__ float wave_sum(float v){
#pragma unroll
  for (int off=32; off; off>>=1) v += __shfl_xor(v, off);
  return v;
}

// pack top-16 bits (bf16 truncation) of two floats: (hi16(b)<<16)|hi16(a)
__device__ __forceinline__ int pack_bf_hi(float a, float b){
  return (int)__builtin_amdgcn_perm(__float_as_uint(b), __float_as_uint(a), 0x07060302u);
}

// ---------------- norms + packed quads ----------------
__global__ void k_norms(const float* __restrict__ verts1, const float* __restrict__ verts2,
                        const float* __restrict__ feat1, const float* __restrict__ feat2,
                        float* __restrict__ ws) {
  int i = blockIdx.x*blockDim.x + threadIdx.x;
  if (i >= BB*NN) return;
  float x=verts1[(size_t)i*3], y=verts1[(size_t)i*3+1], z=verts1[(size_t)i*3+2];
  ((float4*)(ws+OFF_V1Q))[i] = make_float4(x,y,z, x*x+y*y+z*z);
  float x2=verts2[(size_t)i*3], y2=verts2[(size_t)i*3+1], z2=verts2[(size_t)i*3+2];
  ((float4*)(ws+OFF_V2Q))[i] = make_float4(x2,y2,z2, x2*x2+y2*y2+z2*z2);
  {
    const float4* f = (const float4*)(feat2 + (size_t)i*CC);
    float s0=0.f,s1=0.f,s2=0.f,s3=0.f;
#pragma unroll
    for (int k=0;k<CC/4;k++){ float4 t=f[k];
      s0=fmaf(t.x,t.x,s0); s1=fmaf(t.y,t.y,s1); s2=fmaf(t.z,t.z,s2); s3=fmaf(t.w,t.w,s3); }
    ((float4*)(ws+OFF_C2Q))[i] = make_float4(x2,y2,z2, (s0+s1)+(s2+s3));
  }
  {
    const float4* f = (const float4*)(feat1 + (size_t)i*CC);
    float s0=0.f,s1=0.f,s2=0.f,s3=0.f;
#pragma unroll
    for (int k=0;k<CC/4;k++){ float4 t=f[k];
      s0=fmaf(t.x,t.x,s0); s1=fmaf(t.y,t.y,s1); s2=fmaf(t.z,t.z,s2); s3=fmaf(t.w,t.w,s3); }
    ws[OFF_FN1+i] = (s0+s1)+(s2+s3);
  }
}

// ---------------- pre-convert feat2 -> tiled bf16 hi/lo ----------------
// layout [b][g][kt4][kh2][half2][c32][j8], strides (shorts): j=1,c32=8,half=256,kh=512,kt=1024,g=4096
__global__ __launch_bounds__(256) void k_conv(const float* __restrict__ feat2, float* __restrict__ ws) {
  int g = blockIdx.x, b = blockIdx.y;
  int t = threadIdx.x;
  int q = t >> 5, c32 = t & 31;
  int col = g*32 + c32; if (col > NN-1) col = NN-1;
  const float4* src = (const float4*)(feat2 + ((size_t)(b*NN + col))*CC) + q*4;
  float4 v0 = src[0], v1 = src[1], v2 = src[2], v3 = src[3];
  short* f2h = (short*)(ws + OFF_F2H);
  short* f2l = (short*)(ws + OFF_F2L);
  size_t base = ((size_t)(b*NG + g))*4096 + (size_t)q*512 + c32*8;
#pragma unroll
  for (int h=0; h<2; h++){
    float4 a = h ? v2 : v0;
    float4 c = h ? v3 : v1;
    float hx=__uint_as_float(__float_as_uint(a.x)&0xffff0000u);
    float hy=__uint_as_float(__float_as_uint(a.y)&0xffff0000u);
    float hz=__uint_as_float(__float_as_uint(a.z)&0xffff0000u);
    float hw=__uint_as_float(__float_as_uint(a.w)&0xffff0000u);
    float gx=__uint_as_float(__float_as_uint(c.x)&0xffff0000u);
    float gy=__uint_as_float(__float_as_uint(c.y)&0xffff0000u);
    float gz=__uint_as_float(__float_as_uint(c.z)&0xffff0000u);
    float gw=__uint_as_float(__float_as_uint(c.w)&0xffff0000u);
    int4 hi = make_int4(pack_bf_hi(a.x,a.y), pack_bf_hi(a.z,a.w),
                        pack_bf_hi(c.x,c.y), pack_bf_hi(c.z,c.w));
    int4 lo = make_int4(pack_bf_hi(a.x-hx,a.y-hy), pack_bf_hi(a.z-hz,a.w-hw),
                        pack_bf_hi(c.x-gx,c.y-gy), pack_bf_hi(c.z-gz,c.w-gw));
    *(int4*)&f2h[base + h*256] = hi;
    *(int4*)&f2l[base + h*256] = lo;
  }
}

// ---------------- stage A: swapped-operand MFMA GEMM + in-lane online softmax ----------------
__global__ __launch_bounds__(256) void k_stageA(const float* __restrict__ feat1,
      float* __restrict__ ws) {
  __shared__ __align__(16) short Ah[4096], Al[4096];   // feat1: [gg4][kh2][half2][r32][j8]
  __shared__ __align__(16) short Bh[2048], Bl[2048];   // feat2: [cg2][kh2][half2][c32][j8]
  __shared__ __align__(16) float colq[64*4];           // {x,y,z,fn2} per col

  int rblk  = blockIdx.x;
  int split = blockIdx.y;
  int b     = blockIdx.z;
  int rowBase = rblk*128;
  int colBase = split*COLS_PER_SPLIT;
  int colEnd  = colBase + COLS_PER_SPLIT; if (colEnd > NN) colEnd = NN;
  int nct = (colEnd - colBase + 63) >> 6;

  int t    = threadIdx.x;
  int w    = t >> 6;
  int lane = t & 63;
  int half = lane >> 5;
  int m32  = lane & 31;

  const float* f1b = feat1 + (size_t)b*NN*CC;
  const short* f2h = (const short*)(ws + OFF_F2H);
  const short* f2l = (const short*)(ws + OFF_F2L);
  const float4* c2q = (const float4*)(ws + OFF_C2Q) + (size_t)b*NN;

  int nrow = rowBase + w*32 + m32;
  int nclamp = nrow > NN-1 ? NN-1 : nrow;
  float sn = ws[OFF_FN1 + (size_t)b*NN + nclamp];

  int sr = t >> 1, skh = t & 1;
  int srow = rowBase + sr; if (srow > NN-1) srow = NN-1;
  int sgg = sr >> 5, sr32 = sr & 31;
  const float4* aSrcBase = (const float4*)(f1b + (size_t)srow*CC);
  size_t aDst = (size_t)sgg*1024 + (size_t)skh*512 + sr32*8;

  int scg = t >> 7;
  size_t bDstOff = (size_t)scg*1024 + (t & 127)*8;

  float mm = -INFINITY, S = 0.f, Vx = 0.f, Vy = 0.f, Vz = 0.f;

  for (int ci = 0; ci < nct; ci++){
    int ctBase = colBase + ci*64;
    int g0 = ctBase >> 5;
    __syncthreads();
    if (t < 64){
      int c = ctBase + t; if (c > NN-1) c = NN-1;
      *(float4*)&colq[t*4] = c2q[c];
    }
    v16f acc0, acc1;
#pragma unroll
    for (int i=0;i<16;i++){ acc0[i]=0.f; acc1[i]=0.f; }

#pragma unroll 1
    for (int kt = 0; kt < 4; kt++){
      __syncthreads();
      {
        size_t gsrc = ((size_t)(b*NG + g0 + scg))*4096 + (size_t)kt*1024 + (t & 127)*8;
        int4 vh = *(const int4*)&f2h[gsrc];
        int4 vl = *(const int4*)&f2l[gsrc];
        *(int4*)&Bh[bDstOff] = vh;
        *(int4*)&Bl[bDstOff] = vl;
      }
      {
        const float4* s4 = aSrcBase + kt*8 + skh*4;
        float4 v0=s4[0], v1=s4[1], v2=s4[2], v3=s4[3];
#pragma unroll
        for (int h=0; h<2; h++){
          float4 a = h ? v2 : v0;
          float4 c = h ? v3 : v1;
          float hx=__uint_as_float(__float_as_uint(a.x)&0xffff0000u);
          float hy=__uint_as_float(__float_as_uint(a.y)&0xffff0000u);
          float hz=__uint_as_float(__float_as_uint(a.z)&0xffff0000u);
          float hw=__uint_as_float(__float_as_uint(a.w)&0xffff0000u);
          float gx=__uint_as_float(__float_as_uint(c.x)&0xffff0000u);
          float gy=__uint_as_float(__float_as_uint(c.y)&0xffff0000u);
          float gz=__uint_as_float(__float_as_uint(c.z)&0xffff0000u);
          float gw=__uint_as_float(__float_as_uint(c.w)&0xffff0000u);
          int4 hi = make_int4(pack_bf_hi(a.x,a.y), pack_bf_hi(a.z,a.w),
                              pack_bf_hi(c.x,c.y), pack_bf_hi(c.z,c.w));
          int4 lo = make_int4(pack_bf_hi(a.x-hx,a.y-hy), pack_bf_hi(a.z-hz,a.w-hw),
                              pack_bf_hi(c.x-gx,c.y-gy), pack_bf_hi(c.z-gz,c.w-gw));
          *(int4*)&Ah[aDst + h*256] = hi;
          *(int4*)&Al[aDst + h*256] = lo;
        }
      }
      __syncthreads();
#pragma unroll
      for (int kh=0; kh<2; kh++){
        size_t fo = (size_t)kh*512 + (size_t)half*256 + m32*8;
        v8s b1h = *(const v8s*)&Ah[(size_t)w*1024 + fo];
        v8s b1l = *(const v8s*)&Al[(size_t)w*1024 + fo];
        v8s a0h = *(const v8s*)&Bh[fo];
        v8s a0l = *(const v8s*)&Bl[fo];
        v8s a1h = *(const v8s*)&Bh[1024 + fo];
        v8s a1l = *(const v8s*)&Bl[1024 + fo];
        acc0 = __builtin_amdgcn_mfma_f32_32x32x16_bf16(a0h, b1h, acc0, 0,0,0);
        acc0 = __builtin_amdgcn_mfma_f32_32x32x16_bf16(a0h, b1l, acc0, 0,0,0);
        acc0 = __builtin_amdgcn_mfma_f32_32x32x16_bf16(a0l, b1h, acc0, 0,0,0);
        acc1 = __builtin_amdgcn_mfma_f32_32x32x16_bf16(a1h, b1h, acc1, 0,0,0);
        acc1 = __builtin_amdgcn_mfma_f32_32x32x16_bf16(a1h, b1l, acc1, 0,0,0);
        acc1 = __builtin_amdgcn_mfma_f32_32x32x16_bf16(a1l, b1h, acc1, 0,0,0);
      }
    }

    float Mt = -INFINITY;
#pragma unroll
    for (int reg=0; reg<16; reg++){
      int cp0 = (reg&3) + 8*(reg>>2) + 4*half;
      float f0 = colq[cp0*4+3];
      float d0 = fmaf(-2.f, acc0[reg], sn) + f0;
      float l0 = (ctBase+cp0 < colEnd) ? (-ALPHA_F*sqrtf(fmaxf(d0,1e-12f))) : -INFINITY;
      acc0[reg] = l0; Mt = fmaxf(Mt, l0);
      int cp1 = cp0 + 32;
      float f1v = colq[cp1*4+3];
      float d1 = fmaf(-2.f, acc1[reg], sn) + f1v;
      float l1 = (ctBase+cp1 < colEnd) ? (-ALPHA_F*sqrtf(fmaxf(d1,1e-12f))) : -INFINITY;
      acc1[reg] = l1; Mt = fmaxf(Mt, l1);
    }
    float mn = fmaxf(mm, Mt);
    float sc = __expf(mm - mn);
    float se=0.f, sx=0.f, sy=0.f, sz=0.f;
#pragma unroll
    for (int reg=0; reg<16; reg++){
      int cp0 = (reg&3) + 8*(reg>>2) + 4*half;
      float4 q0 = *(const float4*)&colq[cp0*4];
      float e0 = __expf(acc0[reg] - mn);
      se += e0; sx=fmaf(e0,q0.x,sx); sy=fmaf(e0,q0.y,sy); sz=fmaf(e0,q0.z,sz);
      float4 q1 = *(const float4*)&colq[(cp0+32)*4];
      float e1 = __expf(acc1[reg] - mn);
      se += e1; sx=fmaf(e1,q1.x,sx); sy=fmaf(e1,q1.y,sy); sz=fmaf(e1,q1.z,sz);
    }
    S  = fmaf(S,  sc, se);
    Vx = fmaf(Vx, sc, sx);
    Vy = fmaf(Vy, sc, sy);
    Vz = fmaf(Vz, sc, sz);
    mm = mn;
  }

  {
    float m2  = __shfl_xor(mm, 32);
    float S2  = __shfl_xor(S,  32);
    float Vx2 = __shfl_xor(Vx, 32);
    float Vy2 = __shfl_xor(Vy, 32);
    float Vz2 = __shfl_xor(Vz, 32);
    float M = fmaxf(mm, m2);
    float c1 = __expf(mm - M), c2 = __expf(m2 - M);
    float Sf  = S*c1  + S2*c2;
    float Vxf = Vx*c1 + Vx2*c2;
    float Vyf = Vy*c1 + Vy2*c2;
    float Vzf = Vz*c1 + Vz2*c2;
    if (half==0 && nrow < NN){
      float* p = ws + OFF_PART + ((size_t)(b*NN+nrow)*SPLITS + split)*5;
      p[0]=M; p[1]=Sf; p[2]=Vxf; p[3]=Vyf; p[4]=Vzf;
    }
  }
}

// ---------------- combine partials -> verts12 ----------------
__global__ void k_combine(float* __restrict__ ws) {
  int row = blockIdx.x*blockDim.x + threadIdx.x;
  if (row >= BB*NN) return;
  const float* p = ws + OFF_PART + (size_t)row*SPLITS*5;
  float mm = -INFINITY;
#pragma unroll
  for (int s=0;s<SPLITS;s++) mm = fmaxf(mm, p[s*5]);
  float S=0.f,Vx=0.f,Vy=0.f,Vz=0.f;
#pragma unroll
  for (int s=0;s<SPLITS;s++){
    float sc = expf(p[s*5]-mm);
    S  += p[s*5+1]*sc; Vx += p[s*5+2]*sc; Vy += p[s*5+3]*sc; Vz += p[s*5+4]*sc;
  }
  ws[OFF_V12+(size_t)row*3+0]=Vx/S;
  ws[OFF_V12+(size_t)row*3+1]=Vy/S;
  ws[OFF_V12+(size_t)row*3+2]=Vz/S;
}

// ---------------- self-rec: 4 rows/wave, 16 rows/block ----------------
__global__ __launch_bounds__(256) void k_selfrec(float* __restrict__ ws) {
  int rblk = blockIdx.x, b = blockIdx.y;
  int lane = threadIdx.x & 63, w = threadIdx.x >> 6;
  int r0 = rblk*16 + w*4;
  const float4* v2q = (const float4*)(ws + OFF_V2Q) + (size_t)b*NN;
  const float* v12 = ws + OFF_V12 + (size_t)b*NN*3;
  float xr[4], yr[4], zr[4], sar[4]; bool val[4];
#pragma unroll
  for (int j=0;j<4;j++){
    int n = r0+j; val[j] = (n < NN); int nc = val[j] ? n : NN-1;
    xr[j]=v12[(size_t)nc*3]; yr[j]=v12[(size_t)nc*3+1]; zr[j]=v12[(size_t)nc*3+2];
    sar[j]=xr[j]*xr[j]+yr[j]*yr[j]+zr[j]*zr[j];
  }
  float mn0=INFINITY, mn1=INFINITY, mn2=INFINITY, mn3=INFINITY;
  for (int m=lane; m<NN; m+=64) {
    float4 q = v2q[m];
    mn0 = fminf(mn0, fmaf(-2.0f, xr[0]*q.x + yr[0]*q.y + zr[0]*q.z, sar[0]) + q.w);
    mn1 = fminf(mn1, fmaf(-2.0f, xr[1]*q.x + yr[1]*q.y + zr[1]*q.z, sar[1]) + q.w);
    mn2 = fminf(mn2, fmaf(-2.0f, xr[2]*q.x + yr[2]*q.y + zr[2]*q.z, sar[2]) + q.w);
    mn3 = fminf(mn3, fmaf(-2.0f, xr[3]*q.x + yr[3]*q.y + zr[3]*q.z, sar[3]) + q.w);
  }
  mn0 = wave_min(mn0); mn1 = wave_min(mn1); mn2 = wave_min(mn2); mn3 = wave_min(mn3);
  float s = (val[0]?mn0:0.f) + (val[1]?mn1:0.f) + (val[2]?mn2:0.f) + (val[3]?mn3:0.f);
  if (lane==0)
    atomicAdd(((double*)(ws+OFF_ACC)) + ((rblk*4 + w) & 63), (double)s);
}

// ---------------- top-k: ballot-radix threshold + recompute compaction + rank-count selection ----------------
// Phase 1: per-thread min 32-bit monotonic key (no candidate array -> no spill).
// tau: EXACT kk-th smallest of the 256 thread-min keys via 32-step ballot radix-select
//      (each wave computes it redundantly from LDS keybuf -> no cross-wave reduction, no shuffles).
// Compaction: threads with minkey <= tau recompute their 20 d2s, push kv=(key<<13)|idx if key <= tau.
// Selection: rank-counting over <=TKCAND candidates (rank = #kvs smaller); rank<kk writes sel[rank].
__global__ __launch_bounds__(256) void k_topk(const float* __restrict__ feat1,
        const int* __restrict__ kptr, float* __restrict__ ws) {
  __shared__ unsigned int keybuf[256];
  __shared__ unsigned long long cand[TKCAND];
  __shared__ int scnt;
  __shared__ int sel[16];
  __shared__ float rs[4];
  int row = blockIdx.x;
  int t = threadIdx.x;
  int lane = t & 63, wid = t >> 6;
  int b = row / NN; int n = row - b*NN;
  int kk = *kptr; if (kk > 16) kk = 16; if (kk < 1) kk = 1;

  const float4* v1q = (const float4*)(ws + OFF_V1Q) + (size_t)b*NN;
  float4 me = v1q[n];
  float mx=-2.0f*me.x, my2=-2.0f*me.y, mz=-2.0f*me.z, sa=me.w;

  if (t==0) scnt = 0;

  // phase 1: per-thread min key
  unsigned int mykey = 0xFFFFFFFFu;
#pragma unroll
  for (int i=0;i<20;i++){
    int m = t + 256*i;
    if (m < NN){
      float4 q = v1q[m];
      float d2 = fmaf(mx, q.x, fmaf(my2, q.y, fmaf(mz, q.z, sa + q.w)));
      unsigned int u = __float_as_uint(d2);
      u = ((int)u < 0) ? ~u : (u ^ 0x80000000u);
      mykey = u < mykey ? u : mykey;
    }
  }
  keybuf[t] = mykey;
  __syncthreads();

  // tau: exact kk-th smallest of 256 keys, ballot radix-select (each wave redundant)
  unsigned int tau;
  {
    unsigned int k0 = keybuf[lane];
    unsigned int k1 = keybuf[64+lane];
    unsigned int k2 = keybuf[128+lane];
    unsigned int k3 = keybuf[192+lane];
    unsigned int prefix = 0;
    for (int bit=31; bit>=0; --bit){
      unsigned int piv = prefix | (1u<<bit);
      int c = __popcll(__ballot(k0 < piv)) + __popcll(__ballot(k1 < piv))
            + __popcll(__ballot(k2 < piv)) + __popcll(__ballot(k3 < piv));
      if (c < kk) prefix = piv;
    }
    tau = prefix;   // == kk-th smallest key value
  }

  // compaction: recompute candidates only on passing threads (~kk of 256)
  if (mykey <= tau){
#pragma unroll
    for (int i=0;i<20;i++){
      int m = t + 256*i;
      if (m < NN){
        float4 q = v1q[m];
        float d2 = fmaf(mx, q.x, fmaf(my2, q.y, fmaf(mz, q.z, sa + q.w)));
        unsigned int u = __float_as_uint(d2);
        u = ((int)u < 0) ? ~u : (u ^ 0x80000000u);
        if (u <= tau){
          int pos = atomicAdd(&scnt, 1);
          if (pos < TKCAND)
            cand[pos] = ((unsigned long long)u << 13) | (unsigned int)m;
        }
      }
    }
  }
  __syncthreads();
  int cnt = scnt; if (cnt > TKCAND) cnt = TKCAND;

  // selection by rank-counting (exact; kvs unique). Broadcast LDS reads, no shuffles.
  {
    unsigned long long kv0 = (t < cnt) ? cand[t] : ~0ull;
    unsigned long long kv1 = (t+256 < cnt) ? cand[t+256] : ~0ull;
    int r0 = 0, r1 = 0;
    for (int j=0; j<cnt; ++j){
      unsigned long long cj = cand[j];
      r0 += (cj < kv0);
      r1 += (cj < kv1);
    }
    if (t < cnt && r0 < kk)      sel[r0] = (int)(kv0 & 8191ull);
    if (t+256 < cnt && r1 < kk)  sel[r1] = (int)(kv1 & 8191ull);
  }
  __syncthreads();

  // deform feat MSE over selected neighbors
  int c = t & 127;
  int rh = t >> 7;
  const float* f1n = feat1 + (size_t)row*CC;
  float e = f1n[c];
  float acc = 0.f;
  for (int r=rh; r<kk; r+=2){
    const float* g = feat1 + ((size_t)b*NN + sel[r])*CC;
    float d = g[c]-e;
    acc = fmaf(d,d,acc);
  }
  acc = wave_sum(acc);
  if (lane==0) rs[wid] = acc;
  __syncthreads();
  if (t==0){
    float s = (rs[0]+rs[1])+(rs[2]+rs[3]);
    atomicAdd(((double*)(ws+OFF_ACC)) + 128 + (blockIdx.x & 63), (double)s);
  }
}

// ---------------- proj2img stats ----------------
__global__ void k_imgstats(const float* __restrict__ verts2, const float* __restrict__ imgoff,
                           float* __restrict__ ws) {
  __shared__ float r0[4], r1[4], r2[4], r3[4];
  __shared__ float sgs, smnx, smny;
  int img = blockIdx.x >> 2, b = blockIdx.x & 3;
  const float* pc = (img==0) ? (ws + OFF_V12 + (size_t)b*NN*3) : (verts2 + (size_t)b*NN*3);
  int lane = threadIdx.x & 63, wid = threadIdx.x >> 6;
  float mnx=INFINITY, mxx=-INFINITY, mny=INFINITY, mxy=-INFINITY;
  for (int n = threadIdx.x; n < NN; n += 256) {
    float x = pc[(size_t)n*3], y = pc[(size_t)n*3+1];
    mnx=fminf(mnx,x); mxx=fmaxf(mxx,x); mny=fminf(mny,y); mxy=fmaxf(mxy,y);
  }
#pragma unroll
  for (int off=32; off; off>>=1) {
    mnx=fminf(mnx,__shfl_xor(mnx,off)); mxx=fmaxf(mxx,__shfl_xor(mxx,off));
    mny=fminf(mny,__shfl_xor(mny,off)); mxy=fmaxf(mxy,__shfl_xor(mxy,off));
  }
  if (lane==0){ r0[wid]=mnx; r1[wid]=mxx; r2[wid]=mny; r3[wid]=mxy; }
  __syncthreads();
  float* st = ws + OFF_STATS + (size_t)(img*4+b)*16;
  if (threadIdx.x==0){
    mnx=fminf(fminf(r0[0],r0[1]),fminf(r0[2],r0[3]));
    mxx=fmaxf(fmaxf(r1[0],r1[1]),fmaxf(r1[2],r1[3]));
    mny=fminf(fminf(r2[0],r2[1]),fminf(r2[2],r2[3]));
    mxy=fmaxf(fmaxf(r3[0],r3[1]),fmaxf(r3[2],r3[3]));
    float gs = fmaxf(mxx-mnx, mxy-mny) / 221.0f;
    sgs=gs; smnx=mnx; smny=mny;
    st[0]=mnx; st[1]=mxx; st[2]=mny; st[3]=mxy; st[4]=gs;
  }
  __syncthreads();
  float gs=sgs, bx=smnx, by=smny;
  float fmnx=INFINITY, fmxx=-INFINITY, fmny=INFINITY, fmxy=-INFINITY;
  for (int n = threadIdx.x; n < NN; n += 256) {
    float fx = floorf((pc[(size_t)n*3]-bx)/gs);
    float fy = floorf((pc[(size_t)n*3+1]-by)/gs);
    fmnx=fminf(fmnx,fx); fmxx=fmaxf(fmxx,fx); fmny=fminf(fmny,fy); fmxy=fmaxf(fmxy,fy);
  }
#pragma unroll
  for (int off=32; off; off>>=1) {
    fmnx=fminf(fmnx,__shfl_xor(fmnx,off)); fmxx=fmaxf(fmxx,__shfl_xor(fmxx,off));
    fmny=fminf(fmny,__shfl_xor(fmny,off)); fmxy=fmaxf(fmxy,__shfl_xor(fmxy,off));
  }
  __syncthreads();
  if (lane==0){ r0[wid]=fmnx; r1[wid]=fmxx; r2[wid]=fmny; r3[wid]=fmxy; }
  __syncthreads();
  if (threadIdx.x==0){
    fmnx=fminf(fminf(r0[0],r0[1]),fminf(r0[2],r0[3]));
    fmxx=fmaxf(fmaxf(r1[0],r1[1]),fmaxf(r1[2],r1[3]));
    fmny=fminf(fminf(r2[0],r2[1]),fminf(r2[2],r2[3]));
    fmxy=fmaxf(fmaxf(r3[0],r3[1]),fmaxf(r3[2],r3[3]));
    float omnx=INFINITY, omxx=-INFINITY, omny=INFINITY, omxy=-INFINITY;
    for (int l=0;l<25;l++){
      float ox=imgoff[l*2], oy=imgoff[l*2+1];
      omnx=fminf(omnx,ox); omxx=fmaxf(omxx,ox); omny=fminf(omny,oy); omxy=fmaxf(omxy,oy);
    }
    float cx = floorf(((fmxx+omxx+1.0f)+(fmnx+omnx+1.0f))*0.5f);
    float cy = floorf(((fmxy+omxy+1.0f)+(fmny+omny+1.0f))*0.5f);
    st[5] = (112.0f - cx) - 1.0f;
    st[6] = (112.0f - cy) - 1.0f;
  }
}

// ---------------- scatter z into both images ----------------
__global__ void k_scatter(const float* __restrict__ verts2, const float* __restrict__ imgoff,
                          float* __restrict__ ws) {
  int t = blockIdx.x*blockDim.x + threadIdx.x;
  if (t >= 2*BB*NN) return;
  int img = t / (BB*NN); int r = t - img*(BB*NN); int b = r / NN;
  const float* pc = (img==0) ? (ws + OFF_V12) : verts2;
  float x = pc[(size_t)r*3], y = pc[(size_t)r*3+1], z = pc[(size_t)r*3+2];
  const float* st = ws + OFF_STATS + (size_t)(img*4+b)*16;
  float mnx=st[0], mny=st[2], gs=st[4], offx=st[5], offy=st[6];
  float bx = floorf((x-mnx)/gs) + 1.0f + offx;
  float by = floorf((y-mny)/gs) + 1.0f + offy;
  float* im = ws + (img==0?OFF_IMG1:OFF_IMG2) + (size_t)b*IMGP;
#pragma unroll
  for (int l=0;l<25;l++){
    float vx = bx + imgoff[l*2], vy = by + imgoff[l*2+1];
    vx += (vx<0.f?1.f:0.f) - (vx>223.f?1.f:0.f);
    vy += (vy<0.f?1.f:0.f) - (vy>223.f?1.f:0.f);
    vx = fminf(fmaxf(vx,0.f),223.f); vy = fminf(fmaxf(vy,0.f),223.f);
    int flat = (int)(vx*224.f + vy);
    atomicAdd(im + flat, z);
  }
}

// ---------------- image loss ----------------
__global__ void k_imgloss(float* __restrict__ ws) {
  int i = blockIdx.x*blockDim.x + threadIdx.x;
  float v = 0.f;
  if (i < BB*IMGP) {
    float a = ws[OFF_IMG1+i], c = ws[OFF_IMG2+i];
    float sa = 1.f/(1.f+expf(-a)), sc = 1.f/(1.f+expf(-c));
    float d = sa - sc; v = d*d;
  }
  v = wave_sum(v);
  if ((threadIdx.x&63)==0)
    atomicAdd(((double*)(ws+OFF_ACC)) + 64 + (blockIdx.x & 63), (double)v);
}

// ---------------- finalize ----------------
__global__ void k_final(const int* __restrict__ kptr, const float* __restrict__ ws, float* __restrict__ out) {
  const double* acc = (const double*)(ws+OFF_ACC);
  int kk = *kptr; if (kk > 16) kk = 16; if (kk < 1) kk = 1;
  double a0=0.0, a1=0.0, a2=0.0;
  for (int j=0;j<64;j++){ a0 += acc[j]; a1 += acc[64+j]; a2 += acc[128+j]; }
  double srl = a0 / (double)(BB*NN);
  double img = a1 / ((double)BB*IMGP);
  double df  = a2 / ((double)BB*NN*kk*CC);
  out[0] = (float)(srl + img + df);
}

extern "C" void kernel_launch(void* const* d_in, const int* in_sizes, int n_in,
                              void* d_out, int out_size, void* d_ws, size_t ws_size,
                              hipStream_t stream) {
  (void)in_sizes; (void)n_in; (void)out_size; (void)ws_size;
  const float* verts1 = (const float*)d_in[0];
  const float* verts2 = (const float*)d_in[1];
  const float* feat1  = (const float*)d_in[2];
  const float* feat2  = (const float*)d_in[3];
  const float* imgoff = (const float*)d_in[4];
  const int*   kptr   = (const int*)d_in[5];
  float* ws  = (float*)d_ws;
  float* out = (float*)d_out;

  hipMemsetAsync(ws + ZERO_START, 0, (size_t)ZERO_FLOATS*sizeof(float), stream);

  k_norms<<<(BB*NN+255)/256, 256, 0, stream>>>(verts1, verts2, feat1, feat2, ws);

  dim3 gC(NG, BB);
  k_conv<<<gC, 256, 0, stream>>>(feat2, ws);

  dim3 gA(RBLK, SPLITS, BB);
  k_stageA<<<gA, 256, 0, stream>>>(feat1, ws);
  k_combine<<<(BB*NN+255)/256, 256, 0, stream>>>(ws);

  dim3 gS((NN+15)/16, BB);
  k_selfrec<<<gS, 256, 0, stream>>>(ws);
  k_topk<<<BB*NN, 256, 0, stream>>>(feat1, kptr, ws);

  k_imgstats<<<8, 256, 0, stream>>>(verts2, imgoff, ws);
  k_scatter<<<(2*BB*NN+255)/256, 256, 0, stream>>>(verts2, imgoff, ws);
  k_imgloss<<<(BB*IMGP+255)/256, 256, 0, stream>>>(ws);

  k_final<<<1,1,0,stream>>>(kptr, ws, out);
}